// Round 5
// baseline (885.611 us; speedup 1.0000x reference)
//
#include <hip/hip_runtime.h>
#include <hip/hip_bf16.h>
#include <math.h>

#define S_ORIG 4095
#define LPAD   4096
#define NHEADS 16
#define DH     64
#define NLM    128
#define BHT    32        // B * NHEADS
#define HIDDEN 1024
#define QKSCALE 0.35355339059327373f   // 1 / 64^0.25

typedef unsigned short u16;
typedef short s16x8 __attribute__((ext_vector_type(8)));
typedef float f32x4 __attribute__((ext_vector_type(4)));

// swizzled LDS index for 128x128 u16 tiles (kills 256B-row-stride bank conflicts)
#define IDXS(r, c) ((r) * 128 + ((c) ^ (((r) & 7) << 3)))

// ---------------------------------------------------------------------------
// fp32 -> (hi, lo) bf16 split
// ---------------------------------------------------------------------------
__device__ inline void split2(float x, u16& h, u16& l) {
    __hip_bfloat16 bh = __float2bfloat16(x);
    float fh = __bfloat162float(bh);
    __hip_bfloat16 bl = __float2bfloat16(x - fh);
    h = *(u16*)&bh;
    l = *(u16*)&bl;
}

__device__ inline float bf16f(u16 b) {
    unsigned u = ((unsigned)b) << 16;
    return *(float*)&u;
}

// X (B,4095,1024) fp32 -> XH, XL (8192,1024) bf16-bits, pad row (l==4095) zero.
__global__ __launch_bounds__(256) void k_split_x(const float* __restrict__ X,
                                                 u16* __restrict__ XH,
                                                 u16* __restrict__ XL) {
    int idx = blockIdx.x * 256 + threadIdx.x;      // one thread = 4 elems
    int gr = idx >> 8;                             // row 0..8191
    int c4 = (idx & 255) * 4;
    int b = gr >> 12, l = gr & (LPAD - 1);
    float4 v = make_float4(0.f, 0.f, 0.f, 0.f);
    if (l < S_ORIG) v = *(const float4*)(X + ((size_t)b * S_ORIG + l) * HIDDEN + c4);
    ushort4 h4, l4;
    split2(v.x, h4.x, l4.x); split2(v.y, h4.y, l4.y);
    split2(v.z, h4.z, l4.z); split2(v.w, h4.w, l4.w);
    size_t o = (size_t)gr * HIDDEN + c4;
    *(ushort4*)(XH + o) = h4;
    *(ushort4*)(XL + o) = l4;
}

// W (1024,1024) fp32 -> WH, WL bf16-bits (native [n][k] layout).
__global__ __launch_bounds__(256) void k_split_w(const float* __restrict__ W,
                                                 u16* __restrict__ WH,
                                                 u16* __restrict__ WL) {
    int idx = blockIdx.x * 256 + threadIdx.x;
    size_t o = (size_t)idx * 4;
    float4 v = *(const float4*)(W + o);
    ushort4 h4, l4;
    split2(v.x, h4.x, l4.x); split2(v.y, h4.y, l4.y);
    split2(v.z, h4.z, l4.z); split2(v.w, h4.w, l4.w);
    *(ushort4*)(WH + o) = h4;
    *(ushort4*)(WL + o) = l4;
}

// ---------------------------------------------------------------------------
// Split-bf16 MFMA GEMM:  C = A @ B^T + bias, A 8192x1024 (hi/lo), B 1024x1024
// [n][k] (hi/lo). Logical K = 3072: seg0 = AH*BH, seg1 = AH*BL, seg2 = AL*BH.
// 128x128 tile, BK=32, 256 threads (4 waves), 4x4 16x16x32 fragments/wave.
// mode 0: out[b][h][l][d] (+ optional mask*QKSCALE);  mode 1: out rows l<4095.
// ---------------------------------------------------------------------------
__global__ __launch_bounds__(256) void k_gemm_bf16(
    const u16* __restrict__ AH, const u16* __restrict__ AL,
    const u16* __restrict__ BH, const u16* __restrict__ BL,
    const float* __restrict__ bias, const float* __restrict__ mask,
    float* __restrict__ out, int mode)
{
    __shared__ u16 Alds[128 * 32];
    __shared__ u16 Blds[128 * 32];
    int tid = threadIdx.x;
    int row0 = blockIdx.x * 128, col0 = blockIdx.y * 128;
    int lane = tid & 63, wv = tid >> 6;
    int wr = (wv >> 1) * 64, wc = (wv & 1) * 64;
    int lr = lane & 15, lk = lane >> 4;
    int sr = tid >> 2, sseg = (tid & 3) * 8;       // staging row / k-elem offset

    f32x4 acc[4][4] = {};

    for (int kt = 0; kt < 3072; kt += 32) {
        int s = kt >> 10;
        const u16* Asrc = (s < 2) ? AH : AL;
        const u16* Bsrc = (s == 1) ? BL : BH;
        int ka = kt & 1023;
        #pragma unroll
        for (int h = 0; h < 2; ++h) {
            int r = sr + h * 64;
            __builtin_amdgcn_global_load_lds(
                (const __attribute__((address_space(1))) void*)(Asrc + (size_t)(row0 + r) * HIDDEN + ka + sseg),
                (__attribute__((address_space(3))) void*)(&Alds[r * 32 + sseg]), 16, 0, 0);
            __builtin_amdgcn_global_load_lds(
                (const __attribute__((address_space(1))) void*)(Bsrc + (size_t)(col0 + r) * HIDDEN + ka + sseg),
                (__attribute__((address_space(3))) void*)(&Blds[r * 32 + sseg]), 16, 0, 0);
        }
        __syncthreads();
        s16x8 a[4], b[4];
        #pragma unroll
        for (int i = 0; i < 4; ++i) {
            a[i] = *(const s16x8*)&Alds[(wr + i * 16 + lr) * 32 + lk * 8];
            b[i] = *(const s16x8*)&Blds[(wc + i * 16 + lr) * 32 + lk * 8];
        }
        #pragma unroll
        for (int i = 0; i < 4; ++i)
            #pragma unroll
            for (int j = 0; j < 4; ++j)
                acc[i][j] = __builtin_amdgcn_mfma_f32_16x16x32_bf16(a[i], b[j], acc[i][j], 0, 0, 0);
        __syncthreads();
    }

    #pragma unroll
    for (int i = 0; i < 4; ++i) {
        #pragma unroll
        for (int j = 0; j < 4; ++j) {
            int cc = col0 + wc + j * 16 + lr;
            float bval = bias[cc];
            #pragma unroll
            for (int q = 0; q < 4; ++q) {
                int rr = row0 + wr + i * 16 + lk * 4 + q;
                int bb = rr >> 12, l = rr & (LPAD - 1);
                float val = acc[i][j][q] + bval;
                if (mode == 0) {
                    if (mask) val *= mask[(size_t)bb * LPAD + l] * QKSCALE;
                    out[(((size_t)bb * NHEADS + (cc >> 6)) * LPAD + l) * DH + (cc & 63)] = val;
                } else {
                    if (l < S_ORIG)
                        out[((size_t)bb * S_ORIG + l) * HIDDEN + cc] = val;
                }
            }
        }
    }
}

// ---------------------------------------------------------------------------
// Landmarks: mean over 32 consecutive rows of Q and K. grid (128, 32), 64 thr.
// ---------------------------------------------------------------------------
__global__ void k_landmarks(const float* __restrict__ Q, const float* __restrict__ K,
                            float* __restrict__ QL, float* __restrict__ KL) {
    int n = blockIdx.x, bh = blockIdx.y, d = threadIdx.x;
    size_t base = ((size_t)bh * LPAD + n * 32) * DH + d;
    float sq = 0.f, sk = 0.f;
    #pragma unroll
    for (int s = 0; s < 32; ++s) {
        sq += Q[base + (size_t)s * DH];
        sk += K[base + (size_t)s * DH];
    }
    QL[((size_t)bh * NLM + n) * DH + d] = sq * (1.f / 32.f);
    KL[((size_t)bh * NLM + n) * DH + d] = sk * (1.f / 32.f);
}

// ---------------------------------------------------------------------------
// S = QL @ B^T  (128 x 128, inner 64).
// mode 0: B = KL (128 rows), row-softmax, out K2 (ld 128).
// mode 1: B = K tile (128 rows at n0), out raw scores - 1e9*(1-mask) (ld 4096).
// ---------------------------------------------------------------------------
__global__ __launch_bounds__(256) void k_qlk(const float* __restrict__ QLb,
                                             const float* __restrict__ Bsrc,
                                             const float* __restrict__ mask,
                                             float* __restrict__ out,
                                             int ld_out, int mode) {
    __shared__ float Qt[64][132];
    __shared__ float Bt[64][132];
    int tid = threadIdx.x;
    int tx = tid & 15, ty = tid >> 4;
    int bh = blockIdx.y;
    int n0 = blockIdx.x * 128;
    const float* QLp = QLb + (size_t)bh * NLM * DH;
    const float* Bp = Bsrc + ((mode == 0) ? (size_t)bh * NLM * DH
                                          : (size_t)bh * LPAD * DH + (size_t)n0 * DH);

    #pragma unroll
    for (int q = 0; q < 8; ++q) {
        int idx = tid + q * 256;
        int r = idx >> 4, d4 = idx & 15;
        float4 v = *(const float4*)(QLp + (size_t)r * DH + d4 * 4);
        Qt[d4 * 4 + 0][r] = v.x; Qt[d4 * 4 + 1][r] = v.y;
        Qt[d4 * 4 + 2][r] = v.z; Qt[d4 * 4 + 3][r] = v.w;
        float4 w = *(const float4*)(Bp + (size_t)r * DH + d4 * 4);
        Bt[d4 * 4 + 0][r] = w.x; Bt[d4 * 4 + 1][r] = w.y;
        Bt[d4 * 4 + 2][r] = w.z; Bt[d4 * 4 + 3][r] = w.w;
    }
    __syncthreads();

    float acc[8][8];
    #pragma unroll
    for (int i = 0; i < 8; ++i)
        #pragma unroll
        for (int j = 0; j < 8; ++j) acc[i][j] = 0.f;

    #pragma unroll
    for (int k = 0; k < 64; ++k) {
        float av[8], bv[8];
        float4 t0 = *(const float4*)&Qt[k][ty * 4];
        float4 t1 = *(const float4*)&Qt[k][64 + ty * 4];
        float4 t2 = *(const float4*)&Bt[k][tx * 4];
        float4 t3 = *(const float4*)&Bt[k][64 + tx * 4];
        av[0]=t0.x; av[1]=t0.y; av[2]=t0.z; av[3]=t0.w;
        av[4]=t1.x; av[5]=t1.y; av[6]=t1.z; av[7]=t1.w;
        bv[0]=t2.x; bv[1]=t2.y; bv[2]=t2.z; bv[3]=t2.w;
        bv[4]=t3.x; bv[5]=t3.y; bv[6]=t3.z; bv[7]=t3.w;
        #pragma unroll
        for (int i = 0; i < 8; ++i)
            #pragma unroll
            for (int j = 0; j < 8; ++j)
                acc[i][j] = fmaf(av[i], bv[j], acc[i][j]);
    }

    if (mode == 1) {
        int b = bh >> 4;
        #pragma unroll
        for (int i = 0; i < 8; ++i) {
            int r = (i >> 2) * 64 + ty * 4 + (i & 3);
            #pragma unroll
            for (int jh = 0; jh < 2; ++jh) {
                int c = n0 + jh * 64 + tx * 4;
                float4 m4 = *(const float4*)(mask + (size_t)b * LPAD + c);
                float4 res;
                res.x = acc[i][jh * 4 + 0] - 1e9f * (1.f - m4.x);
                res.y = acc[i][jh * 4 + 1] - 1e9f * (1.f - m4.y);
                res.z = acc[i][jh * 4 + 2] - 1e9f * (1.f - m4.z);
                res.w = acc[i][jh * 4 + 3] - 1e9f * (1.f - m4.w);
                *(float4*)(out + ((size_t)bh * NLM + r) * ld_out + c) = res;
            }
        }
    } else {
        float m[8], s[8];
        #pragma unroll
        for (int i = 0; i < 8; ++i) {
            m[i] = acc[i][0];
            #pragma unroll
            for (int j = 1; j < 8; ++j) m[i] = fmaxf(m[i], acc[i][j]);
        }
        #pragma unroll
        for (int o = 8; o >= 1; o >>= 1)
            #pragma unroll
            for (int i = 0; i < 8; ++i) m[i] = fmaxf(m[i], __shfl_xor(m[i], o));
        #pragma unroll
        for (int i = 0; i < 8; ++i) {
            s[i] = 0.f;
            #pragma unroll
            for (int j = 0; j < 8; ++j) {
                acc[i][j] = expf(acc[i][j] - m[i]);
                s[i] += acc[i][j];
            }
        }
        #pragma unroll
        for (int o = 8; o >= 1; o >>= 1)
            #pragma unroll
            for (int i = 0; i < 8; ++i) s[i] += __shfl_xor(s[i], o);
        #pragma unroll
        for (int i = 0; i < 8; ++i) {
            int r = (i >> 2) * 64 + ty * 4 + (i & 3);
            float inv = 1.f / s[i];
            #pragma unroll
            for (int jh = 0; jh < 2; ++jh) {
                int c = jh * 64 + tx * 4;
                float4 res;
                res.x = acc[i][jh * 4 + 0] * inv;
                res.y = acc[i][jh * 4 + 1] * inv;
                res.z = acc[i][jh * 4 + 2] * inv;
                res.w = acc[i][jh * 4 + 3] * inv;
                *(float4*)(out + ((size_t)bh * NLM + r) * ld_out + c) = res;
            }
        }
    }
}

// ---------------------------------------------------------------------------
// Fused Newton-Schulz pseudo-inverse. One workgroup per bh, 256 threads.
// Same algorithm as R4 (correctness-proven) but spill-free: the fv[64]
// register cache is replaced by an LDS fp32 staging tile F overlaying the
// A-pair region (exactly 64 KB). Peak regs ~190 -> no scratch traffic.
// ---------------------------------------------------------------------------
__device__ inline void matmulP(f32x4 (&acc)[4][4], const u16* X_h, const u16* X_l,
                               const u16* Y_h, const u16* Y_l,
                               int wr, int wc, int lr, int lk) {
    #pragma unroll
    for (int i = 0; i < 4; ++i)
        #pragma unroll
        for (int j = 0; j < 4; ++j) acc[i][j] = (f32x4){0.f, 0.f, 0.f, 0.f};
    #pragma unroll
    for (int t = 0; t < 3; ++t) {
        const u16* X = (t == 2) ? X_l : X_h;
        const u16* Y = (t == 1) ? Y_l : Y_h;
        #pragma unroll
        for (int kc = 0; kc < 4; ++kc) {
            s16x8 a[4], b[4];
            #pragma unroll
            for (int i = 0; i < 4; ++i)
                a[i] = *(const s16x8*)&X[IDXS(wr + i * 16 + lr, kc * 32 + lk * 8)];
            #pragma unroll
            for (int j = 0; j < 4; ++j)
                b[j] = *(const s16x8*)&Y[IDXS(wc + j * 16 + lr, kc * 32 + lk * 8)];
            #pragma unroll
            for (int i = 0; i < 4; ++i)
                #pragma unroll
                for (int j = 0; j < 4; ++j)
                    acc[i][j] = __builtin_amdgcn_mfma_f32_16x16x32_bf16(a[i], b[j], acc[i][j], 0, 0, 0);
        }
    }
}

__global__ __launch_bounds__(256) void k_newton(const float* __restrict__ K2g,
                                                u16* __restrict__ K2Hs,
                                                u16* __restrict__ K2Ls,
                                                float* __restrict__ Vout) {
    __shared__ u16 lds[65536];          // Ah | Al | Bh | Bl (each 128x128)
    __shared__ float red[256];
    u16* Ah = lds;
    u16* Al = lds + 16384;
    u16* Bh = lds + 32768;
    u16* Bl = lds + 49152;
    float* F = (float*)lds;             // fp32 K2 staging, overlays A-pair (64KB)

    int tid = threadIdx.x;
    int bh = blockIdx.x;
    int lane = tid & 63, wv = tid >> 6;
    int wr = (wv >> 1) * 64, wc = (wv & 1) * 64;
    int lr = lane & 15, lk = lane >> 4;
    int r = tid >> 1, c0 = (tid & 1) * 64;

    const float* K2p = K2g + (size_t)bh * NLM * NLM;
    size_t so = (size_t)bh * NLM * NLM;

    // ---- prologue: K2 -> F (LDS fp32, A-region), row-sum partials ----
    float rs = 0.f;
    #pragma unroll
    for (int k = 0; k < 16; ++k) {
        float4 v = *(const float4*)(K2p + r * NLM + c0 + k * 4);
        *(float4*)&F[r * NLM + c0 + k * 4] = v;
        rs += fabsf(v.x) + fabsf(v.y) + fabsf(v.z) + fabsf(v.w);
    }
    rs += __shfl_xor(rs, 1);            // full row sum (pair of threads per row)
    red[tid] = rs;
    __syncthreads();
    for (int s = 128; s > 0; s >>= 1) {
        if (tid < s) red[tid] = fmaxf(red[tid], red[tid + s]);
        __syncthreads();
    }
    float maxrow = red[0];
    __syncthreads();
    // col sums (read F)
    {
        int c = tid >> 1;
        int rbase = (tid & 1) * 64;
        float cs = 0.f;
        for (int rr = 0; rr < 64; ++rr) cs += fabsf(F[(rbase + rr) * NLM + c]);
        cs += __shfl_xor(cs, 1);
        red[tid] = cs;
    }
    __syncthreads();
    for (int s = 128; s > 0; s >>= 1) {
        if (tid < s) red[tid] = fmaxf(red[tid], red[tid + s]);
        __syncthreads();
    }
    float invden = 1.f / (maxrow * red[0]);
    __syncthreads();

    // ---- split phase (reads F, writes B-pair + K2 pair to global) ----
    #pragma unroll
    for (int k = 0; k < 8; ++k) {
        float4 va = *(const float4*)&F[r * NLM + c0 + k * 8];
        float4 vb = *(const float4*)&F[r * NLM + c0 + k * 8 + 4];
        float xs0 = va.x, xs1 = va.y, xs2 = va.z, xs3 = va.w;
        float xs4 = vb.x, xs5 = vb.y, xs6 = vb.z, xs7 = vb.w;
        s16x8 h8, l8, sh8, sl8;
        u16 hh, ll;
        split2(xs0 * invden, hh, ll); h8[0] = (short)hh; l8[0] = (short)ll;
        split2(xs1 * invden, hh, ll); h8[1] = (short)hh; l8[1] = (short)ll;
        split2(xs2 * invden, hh, ll); h8[2] = (short)hh; l8[2] = (short)ll;
        split2(xs3 * invden, hh, ll); h8[3] = (short)hh; l8[3] = (short)ll;
        split2(xs4 * invden, hh, ll); h8[4] = (short)hh; l8[4] = (short)ll;
        split2(xs5 * invden, hh, ll); h8[5] = (short)hh; l8[5] = (short)ll;
        split2(xs6 * invden, hh, ll); h8[6] = (short)hh; l8[6] = (short)ll;
        split2(xs7 * invden, hh, ll); h8[7] = (short)hh; l8[7] = (short)ll;
        split2(xs0, hh, ll); sh8[0] = (short)hh; sl8[0] = (short)ll;
        split2(xs1, hh, ll); sh8[1] = (short)hh; sl8[1] = (short)ll;
        split2(xs2, hh, ll); sh8[2] = (short)hh; sl8[2] = (short)ll;
        split2(xs3, hh, ll); sh8[3] = (short)hh; sl8[3] = (short)ll;
        split2(xs4, hh, ll); sh8[4] = (short)hh; sl8[4] = (short)ll;
        split2(xs5, hh, ll); sh8[5] = (short)hh; sl8[5] = (short)ll;
        split2(xs6, hh, ll); sh8[6] = (short)hh; sl8[6] = (short)ll;
        split2(xs7, hh, ll); sh8[7] = (short)hh; sl8[7] = (short)ll;
        *(s16x8*)&Bh[IDXS(r, c0 + k * 8)] = h8;          // B = V0^T = K2*invden
        *(s16x8*)&Bl[IDXS(r, c0 + k * 8)] = l8;
        *(s16x8*)&K2Hs[so + r * NLM + c0 + k * 8] = sh8; // K2 pair -> global
        *(s16x8*)&K2Ls[so + r * NLM + c0 + k * 8] = sl8;
    }
    __syncthreads();    // F reads done; A-region free for iteration use

    f32x4 t4[4][4], acc[4][4];

    for (int it = 0; it < 6; ++it) {
        // A <- K2 pair (linear global -> swizzled LDS)
        #pragma unroll
        for (int k = 0; k < 8; ++k) {
            s16x8 h8 = *(const s16x8*)&K2Hs[so + r * NLM + c0 + k * 8];
            s16x8 l8 = *(const s16x8*)&K2Ls[so + r * NLM + c0 + k * 8];
            *(s16x8*)&Ah[IDXS(r, c0 + k * 8)] = h8;
            *(s16x8*)&Al[IDXS(r, c0 + k * 8)] = l8;
        }
        __syncthreads();
        // KV = P(K2, Vt) = K2 @ V
        matmulP(t4, Ah, Al, Bh, Bl, wr, wc, lr, lk);
        __syncthreads();                          // A reads done before overwrite
        // A <- KVt (transposed write: row n, 4 contiguous cols -> vectorized)
        #pragma unroll
        for (int i = 0; i < 4; ++i)
            #pragma unroll
            for (int j = 0; j < 4; ++j) {
                int n = wc + j * 16 + lr;
                int m0 = wr + i * 16 + lk * 4;
                ushort4 h4, l4;
                split2(t4[i][j][0], h4.x, l4.x); split2(t4[i][j][1], h4.y, l4.y);
                split2(t4[i][j][2], h4.z, l4.z); split2(t4[i][j][3], h4.w, l4.w);
                *(ushort4*)&Ah[IDXS(n, m0)] = h4;
                *(ushort4*)&Al[IDXS(n, m0)] = l4;
            }
        __syncthreads();
        // transpose B in place: Vt -> V
        {
            s16x8 th[8], tl[8];
            #pragma unroll
            for (int k = 0; k < 8; ++k) {
                th[k] = *(const s16x8*)&Bh[IDXS(r, c0 + k * 8)];
                tl[k] = *(const s16x8*)&Bl[IDXS(r, c0 + k * 8)];
            }
            __syncthreads();
            #pragma unroll
            for (int k = 0; k < 8; ++k)
                #pragma unroll
                for (int e = 0; e < 8; ++e) {
                    int cc = c0 + k * 8 + e;
                    Bh[IDXS(cc, r)] = (u16)th[k][e];
                    Bl[IDXS(cc, r)] = (u16)tl[k][e];
                }
            __syncthreads();
        }
        // W1 = P(V, KVt) = V @ KV ; acc = 13V - 15W1
        matmulP(t4, Bh, Bl, Ah, Al, wr, wc, lr, lk);
        #pragma unroll
        for (int i = 0; i < 4; ++i)
            #pragma unroll
            for (int j = 0; j < 4; ++j) {
                int n = wc + j * 16 + lr;
                int m0 = wr + i * 16 + lk * 4;
                #pragma unroll
                for (int q = 0; q < 4; ++q) {
                    float vv = bf16f(Bh[IDXS(m0 + q, n)]) + bf16f(Bl[IDXS(m0 + q, n)]);
                    acc[i][j][q] = 13.f * vv - 15.f * t4[i][j][q];
                }
            }
        __syncthreads();
        // B <- W1 row-major (scalar writes)
        #pragma unroll
        for (int i = 0; i < 4; ++i)
            #pragma unroll
            for (int j = 0; j < 4; ++j) {
                int n = wc + j * 16 + lr;
                int m0 = wr + i * 16 + lk * 4;
                #pragma unroll
                for (int q = 0; q < 4; ++q) {
                    u16 hh, ll;
                    split2(t4[i][j][q], hh, ll);
                    Bh[IDXS(m0 + q, n)] = hh;
                    Bl[IDXS(m0 + q, n)] = ll;
                }
            }
        __syncthreads();
        // W2 = P(W1, KVt); acc += 7 W2
        matmulP(t4, Bh, Bl, Ah, Al, wr, wc, lr, lk);
        #pragma unroll
        for (int i = 0; i < 4; ++i)
            #pragma unroll
            for (int j = 0; j < 4; ++j)
                #pragma unroll
                for (int q = 0; q < 4; ++q)
                    acc[i][j][q] += 7.f * t4[i][j][q];
        __syncthreads();
        #pragma unroll
        for (int i = 0; i < 4; ++i)
            #pragma unroll
            for (int j = 0; j < 4; ++j) {
                int n = wc + j * 16 + lr;
                int m0 = wr + i * 16 + lk * 4;
                #pragma unroll
                for (int q = 0; q < 4; ++q) {
                    u16 hh, ll;
                    split2(t4[i][j][q], hh, ll);
                    Bh[IDXS(m0 + q, n)] = hh;
                    Bl[IDXS(m0 + q, n)] = ll;
                }
            }
        __syncthreads();
        // W3 = P(W2, KVt); acc = 0.25 (acc - W3) = Vnew
        matmulP(t4, Bh, Bl, Ah, Al, wr, wc, lr, lk);
        #pragma unroll
        for (int i = 0; i < 4; ++i)
            #pragma unroll
            for (int j = 0; j < 4; ++j)
                #pragma unroll
                for (int q = 0; q < 4; ++q)
                    acc[i][j][q] = 0.25f * (acc[i][j][q] - t4[i][j][q]);
        __syncthreads();
        if (it < 5) {
            // B <- Vnew transposed (invariant: B = Vt)
            #pragma unroll
            for (int i = 0; i < 4; ++i)
                #pragma unroll
                for (int j = 0; j < 4; ++j) {
                    int n = wc + j * 16 + lr;
                    int m0 = wr + i * 16 + lk * 4;
                    ushort4 h4, l4;
                    split2(acc[i][j][0], h4.x, l4.x); split2(acc[i][j][1], h4.y, l4.y);
                    split2(acc[i][j][2], h4.z, l4.z); split2(acc[i][j][3], h4.w, l4.w);
                    *(ushort4*)&Bh[IDXS(n, m0)] = h4;
                    *(ushort4*)&Bl[IDXS(n, m0)] = l4;
                }
        } else {
            // final: fp32 V to global
            #pragma unroll
            for (int i = 0; i < 4; ++i)
                #pragma unroll
                for (int j = 0; j < 4; ++j) {
                    int n = wc + j * 16 + lr;
                    int m0 = wr + i * 16 + lk * 4;
                    #pragma unroll
                    for (int q = 0; q < 4; ++q)
                        Vout[so + (size_t)(m0 + q) * NLM + n] = acc[i][j][q];
                }
        }
        __syncthreads();
    }
}

// ---------------------------------------------------------------------------
// Batched matmul: C = alpha*(A@B) + sI  (A 128x128, B 128xN). fp32 VALU.
// grid (N/64, 2, 32), 256 threads, 4x4 per thread, full K=128 staged.
// ---------------------------------------------------------------------------
__global__ __launch_bounds__(256) void k_bmm(const float* __restrict__ Ab,
                                             const float* __restrict__ Bb,
                                             float* __restrict__ Cb,
                                             float* __restrict__ C2b,
                                             int N, float alpha, float sI,
                                             float alpha2, float sI2) {
    __shared__ float At[128][68];
    __shared__ float Bs[128][68];
    int tid = threadIdx.x;
    int tx = tid & 15, ty = tid >> 4;
    int bh = blockIdx.z;
    int r0 = blockIdx.y * 64, c0 = blockIdx.x * 64;
    const float* A = Ab + (size_t)bh * NLM * NLM;
    const float* Bm = Bb + (size_t)bh * NLM * N;

    #pragma unroll
    for (int q = 0; q < 8; ++q) {
        int idx = tid + q * 256;
        int r = idx >> 5, k4 = idx & 31;
        float4 v = *(const float4*)(A + (size_t)(r0 + r) * NLM + k4 * 4);
        At[k4 * 4 + 0][r] = v.x; At[k4 * 4 + 1][r] = v.y;
        At[k4 * 4 + 2][r] = v.z; At[k4 * 4 + 3][r] = v.w;
        int bk = idx >> 4, c4 = idx & 15;
        float4 w = *(const float4*)(Bm + (size_t)bk * N + c0 + c4 * 4);
        *(float4*)&Bs[bk][c4 * 4] = w;
    }
    __syncthreads();

    float acc[4][4];
    #pragma unroll
    for (int i = 0; i < 4; ++i)
        #pragma unroll
        for (int j = 0; j < 4; ++j) acc[i][j] = 0.f;

    #pragma unroll 4
    for (int k = 0; k < 128; ++k) {
        float4 a = *(const float4*)&At[k][ty * 4];
        float4 b = *(const float4*)&Bs[k][tx * 4];
        float av[4] = {a.x, a.y, a.z, a.w};
        float bv[4] = {b.x, b.y, b.z, b.w};
        #pragma unroll
        for (int i = 0; i < 4; ++i)
            #pragma unroll
            for (int j = 0; j < 4; ++j)
                acc[i][j] = fmaf(av[i], bv[j], acc[i][j]);
    }

    float* C = Cb + (size_t)bh * NLM * N;
    float* C2 = C2b ? (C2b + (size_t)bh * NLM * N) : nullptr;
    #pragma unroll
    for (int i = 0; i < 4; ++i) {
        int gr = r0 + ty * 4 + i;
        int gc0 = c0 + tx * 4;
        float4 res, res2;
        float* rp = &res.x; float* rp2 = &res2.x;
        #pragma unroll
        for (int j = 0; j < 4; ++j) {
            float idadd = (gr == gc0 + j) ? 1.f : 0.f;
            rp[j] = alpha * acc[i][j] + sI * idadd;
            rp2[j] = alpha2 * acc[i][j] + sI2 * idadd;
        }
        *(float4*)(C + (size_t)gr * N + gc0) = res;
        if (C2) *(float4*)(C2 + (size_t)gr * N + gc0) = res2;
    }
}

// ---------------------------------------------------------------------------
// Row softmax over 4096-long rows of SC (in place). grid 4096, 256 threads.
// ---------------------------------------------------------------------------
__global__ __launch_bounds__(256) void k_softmax4096(float* __restrict__ SC) {
    float* p = SC + (size_t)blockIdx.x * LPAD;
    int tid = threadIdx.x;
    float4 v[4];
    #pragma unroll
    for (int q = 0; q < 4; ++q) v[q] = *(float4*)(p + tid * 16 + q * 4);

    float m = -1e30f;
    #pragma unroll
    for (int q = 0; q < 4; ++q) {
        m = fmaxf(m, fmaxf(fmaxf(v[q].x, v[q].y), fmaxf(v[q].z, v[q].w)));
    }
    __shared__ float red[4], red2[4];
    for (int o = 32; o >= 1; o >>= 1) m = fmaxf(m, __shfl_xor(m, o));
    int wid = tid >> 6;
    if ((tid & 63) == 0) red[wid] = m;
    __syncthreads();
    m = fmaxf(fmaxf(red[0], red[1]), fmaxf(red[2], red[3]));

    float s = 0.f;
    #pragma unroll
    for (int q = 0; q < 4; ++q) {
        v[q].x = expf(v[q].x - m); v[q].y = expf(v[q].y - m);
        v[q].z = expf(v[q].z - m); v[q].w = expf(v[q].w - m);
        s += v[q].x + v[q].y + v[q].z + v[q].w;
    }
    for (int o = 32; o >= 1; o >>= 1) s += __shfl_xor(s, o);
    if ((tid & 63) == 0) red2[wid] = s;
    __syncthreads();
    s = red2[0] + red2[1] + red2[2] + red2[3];
    float inv = 1.f / s;
    #pragma unroll
    for (int q = 0; q < 4; ++q) {
        v[q].x *= inv; v[q].y *= inv; v[q].z *= inv; v[q].w *= inv;
        *(float4*)(p + tid * 16 + q * 4) = v[q];
    }
}

// ---------------------------------------------------------------------------
// Partial kernel_3 @ V over a 256-wide n chunk. grid (16, 32), 256 threads.
// ---------------------------------------------------------------------------
__global__ __launch_bounds__(256) void k_k3v_partial(const float* __restrict__ SC,
                                                     const float* __restrict__ V,
                                                     float* __restrict__ P) {
    __shared__ float Pt[64][132];
    __shared__ float Vs[64][68];
    int tid = threadIdx.x;
    int tx = tid & 7, ty = tid >> 3;
    int sp = blockIdx.x, bh = blockIdx.y;
    int n0 = sp * 256;

    float acc[4][8];
    #pragma unroll
    for (int i = 0; i < 4; ++i)
        #pragma unroll
        for (int j = 0; j < 8; ++j) acc[i][j] = 0.f;

    for (int ns = 0; ns < 4; ++ns) {
        int nb = n0 + ns * 64;
        #pragma unroll
        for (int q = 0; q < 8; ++q) {
            int idx = tid + q * 256;
            int r = idx >> 4, n4 = idx & 15;
            float4 v = *(const float4*)(SC + ((size_t)bh * NLM + r) * LPAD + nb + n4 * 4);
            Pt[n4 * 4 + 0][r] = v.x; Pt[n4 * 4 + 1][r] = v.y;
            Pt[n4 * 4 + 2][r] = v.z; Pt[n4 * 4 + 3][r] = v.w;
        }
        #pragma unroll
        for (int q = 0; q < 4; ++q) {
            int idx = tid + q * 256;
            int vr = idx >> 4, d4 = idx & 15;
            float4 w = *(const float4*)(V + ((size_t)bh * LPAD + nb + vr) * DH + d4 * 4);
            *(float4*)&Vs[vr][d4 * 4] = w;
        }
        __syncthreads();
        #pragma unroll 4
        for (int nn = 0; nn < 64; ++nn) {
            float4 a4 = *(const float4*)&Pt[nn][ty * 4];
            float4 b0 = *(const float4*)&Vs[nn][tx * 8];
            float4 b1 = *(const float4*)&Vs[nn][tx * 8 + 4];
            float a[4] = {a4.x, a4.y, a4.z, a4.w};
            float b[8] = {b0.x, b0.y, b0.z, b0.w, b1.x, b1.y, b1.z, b1.w};
            #pragma unroll
            for (int i = 0; i < 4; ++i)
                #pragma unroll
                for (int j = 0; j < 8; ++j)
                    acc[i][j] = fmaf(a[i], b[j], acc[i][j]);
        }
        __syncthreads();
    }
    #pragma unroll
    for (int i = 0; i < 4; ++i) {
        int r = ty * 4 + i, d = tx * 8;
        *(float4*)(P + (((size_t)bh * 16 + sp) * NLM + r) * DH + d) =
            make_float4(acc[i][0], acc[i][1], acc[i][2], acc[i][3]);
        *(float4*)(P + (((size_t)bh * 16 + sp) * NLM + r) * DH + d + 4) =
            make_float4(acc[i][4], acc[i][5], acc[i][6], acc[i][7]);
    }
}

__global__ void k_k3v_combine(const float* __restrict__ P, float* __restrict__ O) {
    int idx = blockIdx.x * 256 + threadIdx.x;
    int bh = idx >> 13, rem = idx & 8191;
    float s = 0.f;
    for (int sp = 0; sp < 16; ++sp)
        s += P[((size_t)bh * 16 + sp) * 8192 + rem];
    O[idx] = s;
}

// ---------------------------------------------------------------------------
// kernel_1 stage fused: softmax(Q_tile @ KL^T) @ M  -> ATTN hi/lo bf16
// grid (32 l-tiles, 32 bh), 256 threads.
// ---------------------------------------------------------------------------
__global__ __launch_bounds__(256) void k_attn(const float* __restrict__ Q,
                                              const float* __restrict__ KLb,
                                              const float* __restrict__ MMb,
                                              u16* __restrict__ ATH,
                                              u16* __restrict__ ATL) {
    __shared__ float buf[2 * 64 * 132];     // Qt(64x132) | KLt(64x132); later P(128x132)
    __shared__ float Ms[128 * 68];
    int tid = threadIdx.x;
    int tx = tid & 15, ty = tid >> 4;
    int l0 = blockIdx.x * 128, bh = blockIdx.y;
    int b = bh >> 4, hh = bh & 15;
    float* Qt = buf;
    float* KLt = buf + 64 * 132;

    #pragma unroll
    for (int q = 0; q < 8; ++q) {
        int idx = tid + q * 256;
        int r = idx >> 4, d4 = idx & 15;
        float4 v = *(const float4*)(Q + ((size_t)bh * LPAD + l0 + r) * DH + d4 * 4);
        Qt[(d4 * 4 + 0) * 132 + r] = v.x; Qt[(d4 * 4 + 1) * 132 + r] = v.y;
        Qt[(d4 * 4 + 2) * 132 + r] = v.z; Qt[(d4 * 4 + 3) * 132 + r] = v.w;
        float4 w = *(const float4*)(KLb + ((size_t)bh * NLM + r) * DH + d4 * 4);
        KLt[(d4 * 4 + 0) * 132 + r] = w.x; KLt[(d4 * 4 + 1) * 132 + r] = w.y;
        KLt[(d4 * 4 + 2) * 132 + r] = w.z; KLt[(d4 * 4 + 3) * 132 + r] = w.w;
        float4 u = *(const float4*)(MMb + ((size_t)bh * NLM + r) * DH + d4 * 4);
        *(float4*)&Ms[r * 68 + d4 * 4] = u;
    }
    __syncthreads();

    float acc[8][8];
    #pragma unroll
    for (int i = 0; i < 8; ++i)
        #pragma unroll
        for (int j = 0; j < 8; ++j) acc[i][j] = 0.f;

    #pragma unroll
    for (int k = 0; k < 64; ++k) {
        float av[8], bv[8];
        float4 t0 = *(const float4*)&Qt[k * 132 + ty * 4];
        float4 t1 = *(const float4*)&Qt[k * 132 + 64 + ty * 4];
        float4 t2 = *(const float4*)&KLt[k * 132 + tx * 4];
        float4 t3 = *(const float4*)&KLt[k * 132 + 64 + tx * 4];
        av[0]=t0.x; av[1]=t0.y; av[2]=t0.z; av[3]=t0.w;
        av[4]=t1.x; av[5]=t1.y; av[6]=t1.z; av[7]=t1.w;
        bv[0]=t2.x; bv[1]=t2.y; bv[2]=t2.z; bv[3]=t2.w;
        bv[4]=t3.x; bv[5]=t3.y; bv[6]=t3.z; bv[7]=t3.w;
        #pragma unroll
        for (int i = 0; i < 8; ++i)
            #pragma unroll
            for (int j = 0; j < 8; ++j)
                acc[i][j] = fmaf(av[i], bv[j], acc[i][j]);
    }

    // row softmax over 128 cols
    float m[8], s[8];
    #pragma unroll
    for (int i = 0; i < 8; ++i) {
        m[i] = acc[i][0];
        #pragma unroll
        for (int j = 1; j < 8; ++j) m[i] = fmaxf(m[i], acc[i][j]);
    }
    #pragma unroll
    for (int o = 8; o >= 1; o >>= 1)
        #pragma unroll
        for (int i = 0; i < 8; ++i) m[i] = fmaxf(m[i], __shfl_xor(m[i], o));
    #pragma unroll
    for (int i = 0; i < 8; ++i) {
        s[i] = 0.f;
        #pragma unroll
        for (int j = 0; j < 8; ++j) {
            acc[i][j] = expf(acc[i][j] - m[i]);
            s[i] += acc[i][j];
        }
    }
    #pragma unroll
    for (int o = 8; o >= 1; o >>= 1)
        #pragma unroll
        for (int i = 0; i < 8; ++i) s[i] += __shfl_xor(s[i], o);

    __syncthreads();   // all Qt/KLt reads done; safe to overwrite with P
    #pragma unroll
    for (int i = 0; i < 8; ++i) {
        int r = (i >> 2) * 64 + ty * 4 + (i & 3);
        float inv = 1.f / s[i];
        #pragma unroll
        for (int j = 0; j < 8; ++j) {
            int c = (j >> 2) * 64 + tx * 4 + (j & 3);
            buf[r * 132 + c] = acc[i][j] * inv;
        }
    }
    __syncthreads();

    // out = P @ Ms : each thread 8 rows x 4 cols (d = tx*4..)
    float o2[8][4];
    #pragma unroll
    for (int i = 0; i < 8; ++i)
        #pragma unroll
        for (int j = 0; j < 4; ++j) o2[i][j] = 0.f;
    #pragma unroll 4
    for (int n = 0; n < 128; ++n) {
        float4 b4 = *(const float4*)&Ms[n * 68 + tx * 4];
        float bv[4] = {b4.x, b4.y, b4.z, b4.w};
        #pragma unroll
        for (int i = 0; i < 8; ++i) {
            int r = (i >> 2) * 64 + ty * 4 + (i & 3);
            float a = buf[r * 132 + n];
            #pragma unroll
            for (int j = 0; j < 4; ++j)
                o2[i][j] = fmaf(a, bv[j], o2[i][j]);
        }
    }
    #pragma unroll
    for (int i = 0; i < 8; ++i) {
        int l = l0 + (i >> 2) * 64 + ty * 4 + (i & 3);
        size_t base = ((size_t)b * LPAD + l) * HIDDEN + hh * DH + tx * 4;
        ushort4 h4, l4;
        split2(o2[i][0], h4.x, l4.x); split2(o2[i][1], h4.y, l4.y);
        split2(o2[i][2], h4.z, l4.z); split2(o2[i][3], h4.w, l4.w);
        *(ushort4*)(ATH + base) = h4;
        *(ushort4*)(ATL + base) = l4;
    }
}

// ---------------------------------------------------------------------------
extern "C" void kernel_launch(void* const* d_in, const int* in_sizes, int n_in,
                              void* d_out, int out_size, void* d_ws, size_t ws_size,
                              hipStream_t stream) {
    (void)in_sizes; (void)n_in; (void)out_size; (void)ws_size;
    const float* X    = (const float*)d_in[0];
    const float* mask = (const float*)d_in[1];
    const float* Wq   = (const float*)d_in[2];
    const float* bq   = (const float*)d_in[3];
    const float* Wk   = (const float*)d_in[4];
    const float* bk   = (const float*)d_in[5];
    const float* Wv   = (const float*)d_in[6];
    const float* bv   = (const float*)d_in[7];
    const float* Wo   = (const float*)d_in[8];
    const float* bo   = (const float*)d_in[9];
    float* out = (float*)d_out;
    float* w = (float*)d_ws;

    size_t o = 0;
    u16* WQH = (u16*)(w + o); o += (size_t)HIDDEN * HIDDEN / 2;
    u16* WQL = (u16*)(w + o); o += (size_t)HIDDEN * HIDDEN / 2;
    u16* WKH = (u16*)(w + o); o += (size_t)HIDDEN * HIDDEN / 2;
    u16* WKL = (u16*)(w + o); o += (size_t)HIDDEN * HIDDEN / 2;
    u16* WVH = (u16*)(w + o); o += (size_t)HIDDEN * HIDDEN / 2;
    u16* WVL = (u16*)(w + o); o += (size_t)HIDDEN * HIDDEN / 2;
    u16* WOH = (u16*)(w + o); o += (size_t)HIDDEN * HIDDEN / 2;
    u16* WOL = (u16*)(w + o); o += (size_t)HIDDEN * HIDDEN / 2;
    float* Q   = w + o; o += (size_t)BHT * LPAD * DH;
    float* K   = w + o; o += (size_t)BHT * LPAD * DH;
    float* V   = w + o; o += (size_t)BHT * LPAD * DH;
    float* QL  = w + o; o += (size_t)BHT * NLM * DH;
    float* KL  = w + o; o += (size_t)BHT * NLM * DH;
    float* K2  = w + o; o += (size_t)BHT * NLM * NLM;
    float* VA  = w + o; o += (size_t)BHT * NLM * NLM;
    float* VB  = w + o; o += (size_t)BHT * NLM * NLM;   // reused as K2 pair scratch
    float* KV  = w + o; o += (size_t)BHT * NLM * NLM;   // unused (kept for layout)
    float* P1  = w + o; o += (size_t)BHT * NLM * NLM;   // unused
    float* T3  = w + o; o += (size_t)BHT * NLM * NLM;   // unused
    float* PK  = w + o; o += (size_t)BHT * 16 * NLM * DH;
    float* K3V = w + o; o += (size_t)BHT * NLM * DH;
    float* MM  = w + o; o += (size_t)BHT * NLM * DH;
    float* SC  = w + o; o += (size_t)BHT * NLM * LPAD;
    (void)KV; (void)P1; (void)T3;

    u16* K2Hs = (u16*)VB;
    u16* K2Ls = K2Hs + (size_t)BHT * NLM * NLM;

    // Time-shared aliases of the SC region (disjoint live windows):
    u16* XH  = (u16*)SC;
    u16* XL  = XH + (size_t)2 * LPAD * HIDDEN;
    u16* ATH = (u16*)SC;
    u16* ATL = ATH + (size_t)2 * LPAD * HIDDEN;

    k_split_x<<<8192, 256, 0, stream>>>(X, XH, XL);
    k_split_w<<<1024, 256, 0, stream>>>(Wq, WQH, WQL);
    k_split_w<<<1024, 256, 0, stream>>>(Wk, WKH, WKL);
    k_split_w<<<1024, 256, 0, stream>>>(Wv, WVH, WVL);
    k_split_w<<<1024, 256, 0, stream>>>(Wo, WOH, WOL);

    dim3 gg(64, 8);
    k_gemm_bf16<<<gg, 256, 0, stream>>>(XH, XL, WQH, WQL, bq, mask, Q, 0);
    k_gemm_bf16<<<gg, 256, 0, stream>>>(XH, XL, WKH, WKL, bk, mask, K, 0);
    k_gemm_bf16<<<gg, 256, 0, stream>>>(XH, XL, WVH, WVL, bv, nullptr, V, 0);

    k_landmarks<<<dim3(NLM, BHT), 64, 0, stream>>>(Q, K, QL, KL);

    k_qlk<<<dim3(1, BHT), 256, 0, stream>>>(QL, KL, nullptr, K2, NLM, 0);
    k_qlk<<<dim3(32, BHT), 256, 0, stream>>>(QL, K, mask, SC, LPAD, 1);

    k_newton<<<BHT, 256, 0, stream>>>(K2, K2Hs, K2Ls, VA);

    k_softmax4096<<<BHT * NLM, 256, 0, stream>>>(SC);
    k_k3v_partial<<<dim3(16, BHT), 256, 0, stream>>>(SC, V, PK);
    k_k3v_combine<<<(BHT * NLM * DH) / 256, 256, 0, stream>>>(PK, K3V);
    k_bmm<<<dim3(1, 2, BHT), 256, 0, stream>>>(VA, K3V, MM, nullptr, DH, 1.f, 0.f, 0.f, 0.f);

    k_attn<<<dim3(32, BHT), 256, 0, stream>>>(Q, KL, MM, ATH, ATL);
    k_gemm_bf16<<<gg, 256, 0, stream>>>(ATH, ATL, WOH, WOL, bo, nullptr, out, 1);
}

// Round 6
// 841.919 us; speedup vs baseline: 1.0519x; 1.0519x over previous
//
#include <hip/hip_runtime.h>
#include <hip/hip_bf16.h>
#include <math.h>

#define S_ORIG 4095
#define LPAD   4096
#define NHEADS 16
#define DH     64
#define NLM    128
#define BHT    32        // B * NHEADS
#define HIDDEN 1024
#define QKSCALE 0.35355339059327373f   // 1 / 64^0.25

typedef unsigned short u16;
typedef short s16x8 __attribute__((ext_vector_type(8)));
typedef float f32x4 __attribute__((ext_vector_type(4)));

// swizzled LDS index for 128x128 u16 tiles (kills 256B-row-stride bank conflicts)
#define IDXS(r, c) ((r) * 128 + ((c) ^ (((r) & 7) << 3)))

// ---------------------------------------------------------------------------
// fp32 -> (hi, lo) bf16 split
// ---------------------------------------------------------------------------
__device__ inline void split2(float x, u16& h, u16& l) {
    __hip_bfloat16 bh = __float2bfloat16(x);
    float fh = __bfloat162float(bh);
    __hip_bfloat16 bl = __float2bfloat16(x - fh);
    h = *(u16*)&bh;
    l = *(u16*)&bl;
}

// X (B,4095,1024) fp32 -> XH, XL (8192,1024) bf16-bits, pad row (l==4095) zero.
__global__ __launch_bounds__(256) void k_split_x(const float* __restrict__ X,
                                                 u16* __restrict__ XH,
                                                 u16* __restrict__ XL) {
    int idx = blockIdx.x * 256 + threadIdx.x;      // one thread = 4 elems
    int gr = idx >> 8;                             // row 0..8191
    int c4 = (idx & 255) * 4;
    int b = gr >> 12, l = gr & (LPAD - 1);
    float4 v = make_float4(0.f, 0.f, 0.f, 0.f);
    if (l < S_ORIG) v = *(const float4*)(X + ((size_t)b * S_ORIG + l) * HIDDEN + c4);
    ushort4 h4, l4;
    split2(v.x, h4.x, l4.x); split2(v.y, h4.y, l4.y);
    split2(v.z, h4.z, l4.z); split2(v.w, h4.w, l4.w);
    size_t o = (size_t)gr * HIDDEN + c4;
    *(ushort4*)(XH + o) = h4;
    *(ushort4*)(XL + o) = l4;
}

// W (1024,1024) fp32 -> WH, WL bf16-bits (native [n][k] layout).
__global__ __launch_bounds__(256) void k_split_w(const float* __restrict__ W,
                                                 u16* __restrict__ WH,
                                                 u16* __restrict__ WL) {
    int idx = blockIdx.x * 256 + threadIdx.x;
    size_t o = (size_t)idx * 4;
    float4 v = *(const float4*)(W + o);
    ushort4 h4, l4;
    split2(v.x, h4.x, l4.x); split2(v.y, h4.y, l4.y);
    split2(v.z, h4.z, l4.z); split2(v.w, h4.w, l4.w);
    *(ushort4*)(WH + o) = h4;
    *(ushort4*)(WL + o) = l4;
}

// ---------------------------------------------------------------------------
// Split-bf16 MFMA GEMM:  C = A @ B^T + bias, A 8192x1024 (hi/lo), B 1024x1024
// [n][k] (hi/lo). Logical K = 3072: seg0 = AH*BH, seg1 = AH*BL, seg2 = AL*BH.
// ---------------------------------------------------------------------------
__global__ __launch_bounds__(256) void k_gemm_bf16(
    const u16* __restrict__ AH, const u16* __restrict__ AL,
    const u16* __restrict__ BH, const u16* __restrict__ BL,
    const float* __restrict__ bias, const float* __restrict__ mask,
    float* __restrict__ out, int mode)
{
    __shared__ u16 Alds[128 * 32];
    __shared__ u16 Blds[128 * 32];
    int tid = threadIdx.x;
    int row0 = blockIdx.x * 128, col0 = blockIdx.y * 128;
    int lane = tid & 63, wv = tid >> 6;
    int wr = (wv >> 1) * 64, wc = (wv & 1) * 64;
    int lr = lane & 15, lk = lane >> 4;
    int sr = tid >> 2, sseg = (tid & 3) * 8;       // staging row / k-elem offset

    f32x4 acc[4][4] = {};

    for (int kt = 0; kt < 3072; kt += 32) {
        int s = kt >> 10;
        const u16* Asrc = (s < 2) ? AH : AL;
        const u16* Bsrc = (s == 1) ? BL : BH;
        int ka = kt & 1023;
        #pragma unroll
        for (int h = 0; h < 2; ++h) {
            int r = sr + h * 64;
            __builtin_amdgcn_global_load_lds(
                (const __attribute__((address_space(1))) void*)(Asrc + (size_t)(row0 + r) * HIDDEN + ka + sseg),
                (__attribute__((address_space(3))) void*)(&Alds[r * 32 + sseg]), 16, 0, 0);
            __builtin_amdgcn_global_load_lds(
                (const __attribute__((address_space(1))) void*)(Bsrc + (size_t)(col0 + r) * HIDDEN + ka + sseg),
                (__attribute__((address_space(3))) void*)(&Blds[r * 32 + sseg]), 16, 0, 0);
        }
        __syncthreads();
        s16x8 a[4], b[4];
        #pragma unroll
        for (int i = 0; i < 4; ++i) {
            a[i] = *(const s16x8*)&Alds[(wr + i * 16 + lr) * 32 + lk * 8];
            b[i] = *(const s16x8*)&Blds[(wc + i * 16 + lr) * 32 + lk * 8];
        }
        #pragma unroll
        for (int i = 0; i < 4; ++i)
            #pragma unroll
            for (int j = 0; j < 4; ++j)
                acc[i][j] = __builtin_amdgcn_mfma_f32_16x16x32_bf16(a[i], b[j], acc[i][j], 0, 0, 0);
        __syncthreads();
    }

    #pragma unroll
    for (int i = 0; i < 4; ++i) {
        #pragma unroll
        for (int j = 0; j < 4; ++j) {
            int cc = col0 + wc + j * 16 + lr;
            float bval = bias[cc];
            #pragma unroll
            for (int q = 0; q < 4; ++q) {
                int rr = row0 + wr + i * 16 + lk * 4 + q;
                int bb = rr >> 12, l = rr & (LPAD - 1);
                float val = acc[i][j][q] + bval;
                if (mode == 0) {
                    if (mask) val *= mask[(size_t)bb * LPAD + l] * QKSCALE;
                    out[(((size_t)bb * NHEADS + (cc >> 6)) * LPAD + l) * DH + (cc & 63)] = val;
                } else {
                    if (l < S_ORIG)
                        out[((size_t)bb * S_ORIG + l) * HIDDEN + cc] = val;
                }
            }
        }
    }
}

// ---------------------------------------------------------------------------
// Landmarks: mean over 32 consecutive rows of Q and K. grid (128, 32), 64 thr.
// ---------------------------------------------------------------------------
__global__ void k_landmarks(const float* __restrict__ Q, const float* __restrict__ K,
                            float* __restrict__ QL, float* __restrict__ KL) {
    int n = blockIdx.x, bh = blockIdx.y, d = threadIdx.x;
    size_t base = ((size_t)bh * LPAD + n * 32) * DH + d;
    float sq = 0.f, sk = 0.f;
    #pragma unroll
    for (int s = 0; s < 32; ++s) {
        sq += Q[base + (size_t)s * DH];
        sk += K[base + (size_t)s * DH];
    }
    QL[((size_t)bh * NLM + n) * DH + d] = sq * (1.f / 32.f);
    KL[((size_t)bh * NLM + n) * DH + d] = sk * (1.f / 32.f);
}

// ---------------------------------------------------------------------------
// S = QL @ B^T  (128 x 128, inner 64).
// mode 0: B = KL (128 rows), row-softmax, out K2 (ld 128).
// mode 1: B = K tile (128 rows at n0), out raw scores - 1e9*(1-mask) (ld 4096).
// ---------------------------------------------------------------------------
__global__ __launch_bounds__(256) void k_qlk(const float* __restrict__ QLb,
                                             const float* __restrict__ Bsrc,
                                             const float* __restrict__ mask,
                                             float* __restrict__ out,
                                             int ld_out, int mode) {
    __shared__ float Qt[64][132];
    __shared__ float Bt[64][132];
    int tid = threadIdx.x;
    int tx = tid & 15, ty = tid >> 4;
    int bh = blockIdx.y;
    int n0 = blockIdx.x * 128;
    const float* QLp = QLb + (size_t)bh * NLM * DH;
    const float* Bp = Bsrc + ((mode == 0) ? (size_t)bh * NLM * DH
                                          : (size_t)bh * LPAD * DH + (size_t)n0 * DH);

    #pragma unroll
    for (int q = 0; q < 8; ++q) {
        int idx = tid + q * 256;
        int r = idx >> 4, d4 = idx & 15;
        float4 v = *(const float4*)(QLp + (size_t)r * DH + d4 * 4);
        Qt[d4 * 4 + 0][r] = v.x; Qt[d4 * 4 + 1][r] = v.y;
        Qt[d4 * 4 + 2][r] = v.z; Qt[d4 * 4 + 3][r] = v.w;
        float4 w = *(const float4*)(Bp + (size_t)r * DH + d4 * 4);
        Bt[d4 * 4 + 0][r] = w.x; Bt[d4 * 4 + 1][r] = w.y;
        Bt[d4 * 4 + 2][r] = w.z; Bt[d4 * 4 + 3][r] = w.w;
    }
    __syncthreads();

    float acc[8][8];
    #pragma unroll
    for (int i = 0; i < 8; ++i)
        #pragma unroll
        for (int j = 0; j < 8; ++j) acc[i][j] = 0.f;

    #pragma unroll
    for (int k = 0; k < 64; ++k) {
        float av[8], bv[8];
        float4 t0 = *(const float4*)&Qt[k][ty * 4];
        float4 t1 = *(const float4*)&Qt[k][64 + ty * 4];
        float4 t2 = *(const float4*)&Bt[k][tx * 4];
        float4 t3 = *(const float4*)&Bt[k][64 + tx * 4];
        av[0]=t0.x; av[1]=t0.y; av[2]=t0.z; av[3]=t0.w;
        av[4]=t1.x; av[5]=t1.y; av[6]=t1.z; av[7]=t1.w;
        bv[0]=t2.x; bv[1]=t2.y; bv[2]=t2.z; bv[3]=t2.w;
        bv[4]=t3.x; bv[5]=t3.y; bv[6]=t3.z; bv[7]=t3.w;
        #pragma unroll
        for (int i = 0; i < 8; ++i)
            #pragma unroll
            for (int j = 0; j < 8; ++j)
                acc[i][j] = fmaf(av[i], bv[j], acc[i][j]);
    }

    if (mode == 1) {
        int b = bh >> 4;
        #pragma unroll
        for (int i = 0; i < 8; ++i) {
            int r = (i >> 2) * 64 + ty * 4 + (i & 3);
            #pragma unroll
            for (int jh = 0; jh < 2; ++jh) {
                int c = n0 + jh * 64 + tx * 4;
                float4 m4 = *(const float4*)(mask + (size_t)b * LPAD + c);
                float4 res;
                res.x = acc[i][jh * 4 + 0] - 1e9f * (1.f - m4.x);
                res.y = acc[i][jh * 4 + 1] - 1e9f * (1.f - m4.y);
                res.z = acc[i][jh * 4 + 2] - 1e9f * (1.f - m4.z);
                res.w = acc[i][jh * 4 + 3] - 1e9f * (1.f - m4.w);
                *(float4*)(out + ((size_t)bh * NLM + r) * ld_out + c) = res;
            }
        }
    } else {
        float m[8], s[8];
        #pragma unroll
        for (int i = 0; i < 8; ++i) {
            m[i] = acc[i][0];
            #pragma unroll
            for (int j = 1; j < 8; ++j) m[i] = fmaxf(m[i], acc[i][j]);
        }
        #pragma unroll
        for (int o = 8; o >= 1; o >>= 1)
            #pragma unroll
            for (int i = 0; i < 8; ++i) m[i] = fmaxf(m[i], __shfl_xor(m[i], o));
        #pragma unroll
        for (int i = 0; i < 8; ++i) {
            s[i] = 0.f;
            #pragma unroll
            for (int j = 0; j < 8; ++j) {
                acc[i][j] = expf(acc[i][j] - m[i]);
                s[i] += acc[i][j];
            }
        }
        #pragma unroll
        for (int o = 8; o >= 1; o >>= 1)
            #pragma unroll
            for (int i = 0; i < 8; ++i) s[i] += __shfl_xor(s[i], o);
        #pragma unroll
        for (int i = 0; i < 8; ++i) {
            int r = (i >> 2) * 64 + ty * 4 + (i & 3);
            float inv = 1.f / s[i];
            #pragma unroll
            for (int jh = 0; jh < 2; ++jh) {
                int c = jh * 64 + tx * 4;
                float4 res;
                res.x = acc[i][jh * 4 + 0] * inv;
                res.y = acc[i][jh * 4 + 1] * inv;
                res.z = acc[i][jh * 4 + 2] * inv;
                res.w = acc[i][jh * 4 + 3] * inv;
                *(float4*)(out + ((size_t)bh * NLM + r) * ld_out + c) = res;
            }
        }
    }
}

// ---------------------------------------------------------------------------
// Fused Newton-Schulz via Horner:  V' = 0.25 V (13I - KV(15I - KV(7I - KV))).
// Transposed chain: N1 = 7I - KVt; N2 = 15I - N1@KVt; N3 = 13I - N2@KVt;
// Vnew = 0.25 P(V, N3)  (N3^T = M3).  Only ONE live fragment array t4 ->
// peak ~140 VGPR, no spills. 2 LDS pair slots (X,Y); Vt round-trips via
// global pair GVt (same-block write->barrier->read, L2-resident, the
// pattern already proven by the K2-pair staging in R4).
// ---------------------------------------------------------------------------
__device__ inline void matmulP(f32x4 (&acc)[4][4], const u16* X_h, const u16* X_l,
                               const u16* Y_h, const u16* Y_l,
                               int wr, int wc, int lr, int lk) {
    #pragma unroll
    for (int i = 0; i < 4; ++i)
        #pragma unroll
        for (int j = 0; j < 4; ++j) acc[i][j] = (f32x4){0.f, 0.f, 0.f, 0.f};
    #pragma unroll
    for (int t = 0; t < 3; ++t) {
        const u16* X = (t == 2) ? X_l : X_h;
        const u16* Y = (t == 1) ? Y_l : Y_h;
        #pragma unroll
        for (int kc = 0; kc < 4; ++kc) {
            s16x8 a[4], b[4];
            #pragma unroll
            for (int i = 0; i < 4; ++i)
                a[i] = *(const s16x8*)&X[IDXS(wr + i * 16 + lr, kc * 32 + lk * 8)];
            #pragma unroll
            for (int j = 0; j < 4; ++j)
                b[j] = *(const s16x8*)&Y[IDXS(wc + j * 16 + lr, kc * 32 + lk * 8)];
            #pragma unroll
            for (int i = 0; i < 4; ++i)
                #pragma unroll
                for (int j = 0; j < 4; ++j)
                    acc[i][j] = __builtin_amdgcn_mfma_f32_16x16x32_bf16(a[i], b[j], acc[i][j], 0, 0, 0);
        }
    }
}

__global__ __launch_bounds__(256, 1) void k_newton(const float* __restrict__ K2g,
                                                   u16* __restrict__ K2Hs,
                                                   u16* __restrict__ K2Ls,
                                                   u16* __restrict__ GVth,
                                                   u16* __restrict__ GVtl,
                                                   float* __restrict__ Vout) {
    __shared__ u16 lds[65536];          // Xh | Xl | Yh | Yl (each 128x128)
    __shared__ float red[256];
    u16* Xh = lds;
    u16* Xl = lds + 16384;
    u16* Yh = lds + 32768;
    u16* Yl = lds + 49152;
    float* F = (float*)lds;             // fp32 K2 staging, overlays X-pair (64KB)

    int tid = threadIdx.x;
    int bh = blockIdx.x;
    int lane = tid & 63, wv = tid >> 6;
    int wr = (wv >> 1) * 64, wc = (wv & 1) * 64;
    int lr = lane & 15, lk = lane >> 4;
    int r = tid >> 1, c0 = (tid & 1) * 64;

    const float* K2p = K2g + (size_t)bh * NLM * NLM;
    size_t so = (size_t)bh * NLM * NLM;

    // ---- prologue: K2 -> F, denom reduction ----
    float rs = 0.f;
    #pragma unroll
    for (int k = 0; k < 16; ++k) {
        float4 v = *(const float4*)(K2p + r * NLM + c0 + k * 4);
        *(float4*)&F[r * NLM + c0 + k * 4] = v;
        rs += fabsf(v.x) + fabsf(v.y) + fabsf(v.z) + fabsf(v.w);
    }
    rs += __shfl_xor(rs, 1);
    red[tid] = rs;
    __syncthreads();
    for (int s = 128; s > 0; s >>= 1) {
        if (tid < s) red[tid] = fmaxf(red[tid], red[tid + s]);
        __syncthreads();
    }
    float maxrow = red[0];
    __syncthreads();
    {
        int c = tid >> 1;
        int rbase = (tid & 1) * 64;
        float cs = 0.f;
        for (int rr = 0; rr < 64; ++rr) cs += fabsf(F[(rbase + rr) * NLM + c]);
        cs += __shfl_xor(cs, 1);
        red[tid] = cs;
    }
    __syncthreads();
    for (int s = 128; s > 0; s >>= 1) {
        if (tid < s) red[tid] = fmaxf(red[tid], red[tid + s]);
        __syncthreads();
    }
    float invden = 1.f / (maxrow * red[0]);
    __syncthreads();

    // ---- split: GVt = V0^T = K2*invden (pair); K2 pair -> global scratch ----
    #pragma unroll
    for (int k = 0; k < 8; ++k) {
        float4 va = *(const float4*)&F[r * NLM + c0 + k * 8];
        float4 vb = *(const float4*)&F[r * NLM + c0 + k * 8 + 4];
        float xs[8] = {va.x, va.y, va.z, va.w, vb.x, vb.y, vb.z, vb.w};
        s16x8 h8, l8, sh8, sl8;
        #pragma unroll
        for (int e = 0; e < 8; ++e) {
            u16 hh, ll;
            split2(xs[e] * invden, hh, ll);
            h8[e] = (short)hh; l8[e] = (short)ll;
            split2(xs[e], hh, ll);
            sh8[e] = (short)hh; sl8[e] = (short)ll;
        }
        *(s16x8*)&GVth[so + r * NLM + c0 + k * 8] = h8;
        *(s16x8*)&GVtl[so + r * NLM + c0 + k * 8] = l8;
        *(s16x8*)&K2Hs[so + r * NLM + c0 + k * 8] = sh8;
        *(s16x8*)&K2Ls[so + r * NLM + c0 + k * 8] = sl8;
    }
    __syncthreads();

    f32x4 t4[4][4];

    for (int it = 0; it < 6; ++it) {
        // --- 1. X <- K2 pair, Y <- Vt pair (global -> swizzled LDS) ---
        #pragma unroll
        for (int k = 0; k < 8; ++k) {
            *(s16x8*)&Xh[IDXS(r, c0 + k * 8)] = *(const s16x8*)&K2Hs[so + r * NLM + c0 + k * 8];
            *(s16x8*)&Xl[IDXS(r, c0 + k * 8)] = *(const s16x8*)&K2Ls[so + r * NLM + c0 + k * 8];
            *(s16x8*)&Yh[IDXS(r, c0 + k * 8)] = *(const s16x8*)&GVth[so + r * NLM + c0 + k * 8];
            *(s16x8*)&Yl[IDXS(r, c0 + k * 8)] = *(const s16x8*)&GVtl[so + r * NLM + c0 + k * 8];
        }
        __syncthreads();
        matmulP(t4, Xh, Xl, Yh, Yl, wr, wc, lr, lk);     // t4 = K2@V = KV
        __syncthreads();
        // --- 2. Y <- KV row-major (scalar); X <- N1 = 7I - KVt (transposed, vec) ---
        #pragma unroll
        for (int i = 0; i < 4; ++i)
            #pragma unroll
            for (int j = 0; j < 4; ++j) {
                int n = wc + j * 16 + lr;
                int m0 = wr + i * 16 + lk * 4;
                ushort4 h4, l4;
                #pragma unroll
                for (int q = 0; q < 4; ++q) {
                    u16 hh, ll;
                    split2(t4[i][j][q], hh, ll);
                    Yh[IDXS(m0 + q, n)] = hh;
                    Yl[IDXS(m0 + q, n)] = ll;
                    float nv = ((n == m0 + q) ? 7.f : 0.f) - t4[i][j][q];
                    split2(nv, hh, ll);
                    (&h4.x)[q] = hh; (&l4.x)[q] = ll;
                }
                *(ushort4*)&Xh[IDXS(n, m0)] = h4;
                *(ushort4*)&Xl[IDXS(n, m0)] = l4;
            }
        __syncthreads();
        matmulP(t4, Xh, Xl, Yh, Yl, wr, wc, lr, lk);     // t4 = N1@KVt
        __syncthreads();
        // --- 3. X <- N2 = 15I - t4 (row-major, scalar) ---
        #pragma unroll
        for (int i = 0; i < 4; ++i)
            #pragma unroll
            for (int j = 0; j < 4; ++j) {
                int n = wc + j * 16 + lr;
                int m0 = wr + i * 16 + lk * 4;
                #pragma unroll
                for (int q = 0; q < 4; ++q) {
                    u16 hh, ll;
                    split2(((m0 + q == n) ? 15.f : 0.f) - t4[i][j][q], hh, ll);
                    Xh[IDXS(m0 + q, n)] = hh;
                    Xl[IDXS(m0 + q, n)] = ll;
                }
            }
        __syncthreads();
        matmulP(t4, Xh, Xl, Yh, Yl, wr, wc, lr, lk);     // t4 = N2@KVt
        __syncthreads();
        // --- 4. Y <- N3 = 13I - t4 (row-major); X <- Vt pair (global) ---
        #pragma unroll
        for (int i = 0; i < 4; ++i)
            #pragma unroll
            for (int j = 0; j < 4; ++j) {
                int n = wc + j * 16 + lr;
                int m0 = wr + i * 16 + lk * 4;
                #pragma unroll
                for (int q = 0; q < 4; ++q) {
                    u16 hh, ll;
                    split2(((m0 + q == n) ? 13.f : 0.f) - t4[i][j][q], hh, ll);
                    Yh[IDXS(m0 + q, n)] = hh;
                    Yl[IDXS(m0 + q, n)] = ll;
                }
            }
        #pragma unroll
        for (int k = 0; k < 8; ++k) {
            *(s16x8*)&Xh[IDXS(r, c0 + k * 8)] = *(const s16x8*)&GVth[so + r * NLM + c0 + k * 8];
            *(s16x8*)&Xl[IDXS(r, c0 + k * 8)] = *(const s16x8*)&GVtl[so + r * NLM + c0 + k * 8];
        }
        __syncthreads();
        // --- 5. transpose X in place: Vt -> V ---
        {
            s16x8 th[8], tl[8];
            #pragma unroll
            for (int k = 0; k < 8; ++k) {
                th[k] = *(const s16x8*)&Xh[IDXS(r, c0 + k * 8)];
                tl[k] = *(const s16x8*)&Xl[IDXS(r, c0 + k * 8)];
            }
            __syncthreads();
            #pragma unroll
            for (int k = 0; k < 8; ++k)
                #pragma unroll
                for (int e = 0; e < 8; ++e) {
                    int cc = c0 + k * 8 + e;
                    Xh[IDXS(cc, r)] = (u16)th[k][e];
                    Xl[IDXS(cc, r)] = (u16)tl[k][e];
                }
            __syncthreads();
        }
        matmulP(t4, Xh, Xl, Yh, Yl, wr, wc, lr, lk);     // t4 = V@N3^T = V@M3 = 4*Vnew
        __syncthreads();
        // --- 6. emit: GVt <- 0.25*t4 transposed (vec global), or final Vout ---
        if (it < 5) {
            #pragma unroll
            for (int i = 0; i < 4; ++i)
                #pragma unroll
                for (int j = 0; j < 4; ++j) {
                    int n = wc + j * 16 + lr;
                    int m0 = wr + i * 16 + lk * 4;
                    ushort4 h4, l4;
                    #pragma unroll
                    for (int q = 0; q < 4; ++q) {
                        u16 hh, ll;
                        split2(0.25f * t4[i][j][q], hh, ll);
                        (&h4.x)[q] = hh; (&l4.x)[q] = ll;
                    }
                    *(ushort4*)&GVth[so + (size_t)n * NLM + m0] = h4;
                    *(ushort4*)&GVtl[so + (size_t)n * NLM + m0] = l4;
                }
        } else {
            #pragma unroll
            for (int i = 0; i < 4; ++i)
                #pragma unroll
                for (int j = 0; j < 4; ++j) {
                    int n = wc + j * 16 + lr;
                    int m0 = wr + i * 16 + lk * 4;
                    #pragma unroll
                    for (int q = 0; q < 4; ++q)
                        Vout[so + (size_t)(m0 + q) * NLM + n] = 0.25f * t4[i][j][q];
                }
        }
        __syncthreads();
    }
}

// ---------------------------------------------------------------------------
// Batched matmul: C = alpha*(A@B) + sI  (A 128x128, B 128xN). fp32 VALU.
// ---------------------------------------------------------------------------
__global__ __launch_bounds__(256) void k_bmm(const float* __restrict__ Ab,
                                             const float* __restrict__ Bb,
                                             float* __restrict__ Cb,
                                             float* __restrict__ C2b,
                                             int N, float alpha, float sI,
                                             float alpha2, float sI2) {
    __shared__ float At[128][68];
    __shared__ float Bs[128][68];
    int tid = threadIdx.x;
    int tx = tid & 15, ty = tid >> 4;
    int bh = blockIdx.z;
    int r0 = blockIdx.y * 64, c0 = blockIdx.x * 64;
    const float* A = Ab + (size_t)bh * NLM * NLM;
    const float* Bm = Bb + (size_t)bh * NLM * N;

    #pragma unroll
    for (int q = 0; q < 8; ++q) {
        int idx = tid + q * 256;
        int r = idx >> 5, k4 = idx & 31;
        float4 v = *(const float4*)(A + (size_t)(r0 + r) * NLM + k4 * 4);
        At[k4 * 4 + 0][r] = v.x; At[k4 * 4 + 1][r] = v.y;
        At[k4 * 4 + 2][r] = v.z; At[k4 * 4 + 3][r] = v.w;
        int bk = idx >> 4, c4 = idx & 15;
        float4 w = *(const float4*)(Bm + (size_t)bk * N + c0 + c4 * 4);
        *(float4*)&Bs[bk][c4 * 4] = w;
    }
    __syncthreads();

    float acc[4][4];
    #pragma unroll
    for (int i = 0; i < 4; ++i)
        #pragma unroll
        for (int j = 0; j < 4; ++j) acc[i][j] = 0.f;

    #pragma unroll 4
    for (int k = 0; k < 128; ++k) {
        float4 a = *(const float4*)&At[k][ty * 4];
        float4 b = *(const float4*)&Bs[k][tx * 4];
        float av[4] = {a.x, a.y, a.z, a.w};
        float bv[4] = {b.x, b.y, b.z, b.w};
        #pragma unroll
        for (int i = 0; i < 4; ++i)
            #pragma unroll
            for (int j = 0; j < 4; ++j)
                acc[i][j] = fmaf(av[i], bv[j], acc[i][j]);
    }

    float* C = Cb + (size_t)bh * NLM * N;
    float* C2 = C2b ? (C2b + (size_t)bh * NLM * N) : nullptr;
    #pragma unroll
    for (int i = 0; i < 4; ++i) {
        int gr = r0 + ty * 4 + i;
        int gc0 = c0 + tx * 4;
        float4 res, res2;
        float* rp = &res.x; float* rp2 = &res2.x;
        #pragma unroll
        for (int j = 0; j < 4; ++j) {
            float idadd = (gr == gc0 + j) ? 1.f : 0.f;
            rp[j] = alpha * acc[i][j] + sI * idadd;
            rp2[j] = alpha2 * acc[i][j] + sI2 * idadd;
        }
        *(float4*)(C + (size_t)gr * N + gc0) = res;
        if (C2) *(float4*)(C2 + (size_t)gr * N + gc0) = res2;
    }
}

// ---------------------------------------------------------------------------
// Row softmax over 4096-long rows of SC (in place). grid 4096, 256 threads.
// ---------------------------------------------------------------------------
__global__ __launch_bounds__(256) void k_softmax4096(float* __restrict__ SC) {
    float* p = SC + (size_t)blockIdx.x * LPAD;
    int tid = threadIdx.x;
    float4 v[4];
    #pragma unroll
    for (int q = 0; q < 4; ++q) v[q] = *(float4*)(p + tid * 16 + q * 4);

    float m = -1e30f;
    #pragma unroll
    for (int q = 0; q < 4; ++q) {
        m = fmaxf(m, fmaxf(fmaxf(v[q].x, v[q].y), fmaxf(v[q].z, v[q].w)));
    }
    __shared__ float red[4], red2[4];
    for (int o = 32; o >= 1; o >>= 1) m = fmaxf(m, __shfl_xor(m, o));
    int wid = tid >> 6;
    if ((tid & 63) == 0) red[wid] = m;
    __syncthreads();
    m = fmaxf(fmaxf(red[0], red[1]), fmaxf(red[2], red[3]));

    float s = 0.f;
    #pragma unroll
    for (int q = 0; q < 4; ++q) {
        v[q].x = expf(v[q].x - m); v[q].y = expf(v[q].y - m);
        v[q].z = expf(v[q].z - m); v[q].w = expf(v[q].w - m);
        s += v[q].x + v[q].y + v[q].z + v[q].w;
    }
    for (int o = 32; o >= 1; o >>= 1) s += __shfl_xor(s, o);
    if ((tid & 63) == 0) red2[wid] = s;
    __syncthreads();
    s = red2[0] + red2[1] + red2[2] + red2[3];
    float inv = 1.f / s;
    #pragma unroll
    for (int q = 0; q < 4; ++q) {
        v[q].x *= inv; v[q].y *= inv; v[q].z *= inv; v[q].w *= inv;
        *(float4*)(p + tid * 16 + q * 4) = v[q];
    }
}

// ---------------------------------------------------------------------------
// Partial kernel_3 @ V over a 256-wide n chunk. grid (16, 32), 256 threads.
// ---------------------------------------------------------------------------
__global__ __launch_bounds__(256) void k_k3v_partial(const float* __restrict__ SC,
                                                     const float* __restrict__ V,
                                                     float* __restrict__ P) {
    __shared__ float Pt[64][132];
    __shared__ float Vs[64][68];
    int tid = threadIdx.x;
    int tx = tid & 7, ty = tid >> 3;
    int sp = blockIdx.x, bh = blockIdx.y;
    int n0 = sp * 256;

    float acc[4][8];
    #pragma unroll
    for (int i = 0; i < 4; ++i)
        #pragma unroll
        for (int j = 0; j < 8; ++j) acc[i][j] = 0.f;

    for (int ns = 0; ns < 4; ++ns) {
        int nb = n0 + ns * 64;
        #pragma unroll
        for (int q = 0; q < 8; ++q) {
            int idx = tid + q * 256;
            int r = idx >> 4, n4 = idx & 15;
            float4 v = *(const float4*)(SC + ((size_t)bh * NLM + r) * LPAD + nb + n4 * 4);
            Pt[n4 * 4 + 0][r] = v.x; Pt[n4 * 4 + 1][r] = v.y;
            Pt[n4 * 4 + 2][r] = v.z; Pt[n4 * 4 + 3][r] = v.w;
        }
        #pragma unroll
        for (int q = 0; q < 4; ++q) {
            int idx = tid + q * 256;
            int vr = idx >> 4, d4 = idx & 15;
            float4 w = *(const float4*)(V + ((size_t)bh * LPAD + nb + vr) * DH + d4 * 4);
            *(float4*)&Vs[vr][d4 * 4] = w;
        }
        __syncthreads();
        #pragma unroll 4
        for (int nn = 0; nn < 64; ++nn) {
            float4 a4 = *(const float4*)&Pt[nn][ty * 4];
            float4 b0 = *(const float4*)&Vs[nn][tx * 8];
            float4 b1 = *(const float4*)&Vs[nn][tx * 8 + 4];
            float a[4] = {a4.x, a4.y, a4.z, a4.w};
            float b[8] = {b0.x, b0.y, b0.z, b0.w, b1.x, b1.y, b1.z, b1.w};
            #pragma unroll
            for (int i = 0; i < 4; ++i)
                #pragma unroll
                for (int j = 0; j < 8; ++j)
                    acc[i][j] = fmaf(a[i], b[j], acc[i][j]);
        }
        __syncthreads();
    }
    #pragma unroll
    for (int i = 0; i < 4; ++i) {
        int r = ty * 4 + i, d = tx * 8;
        *(float4*)(P + (((size_t)bh * 16 + sp) * NLM + r) * DH + d) =
            make_float4(acc[i][0], acc[i][1], acc[i][2], acc[i][3]);
        *(float4*)(P + (((size_t)bh * 16 + sp) * NLM + r) * DH + d + 4) =
            make_float4(acc[i][4], acc[i][5], acc[i][6], acc[i][7]);
    }
}

__global__ void k_k3v_combine(const float* __restrict__ P, float* __restrict__ O) {
    int idx = blockIdx.x * 256 + threadIdx.x;
    int bh = idx >> 13, rem = idx & 8191;
    float s = 0.f;
    for (int sp = 0; sp < 16; ++sp)
        s += P[((size_t)bh * 16 + sp) * 8192 + rem];
    O[idx] = s;
}

// ---------------------------------------------------------------------------
// kernel_1 stage fused: softmax(Q_tile @ KL^T) @ M  -> ATTN hi/lo bf16
// grid (32 l-tiles, 32 bh), 256 threads.
// ---------------------------------------------------------------------------
__global__ __launch_bounds__(256) void k_attn(const float* __restrict__ Q,
                                              const float* __restrict__ KLb,
                                              const float* __restrict__ MMb,
                                              u16* __restrict__ ATH,
                                              u16* __restrict__ ATL) {
    __shared__ float buf[2 * 64 * 132];     // Qt(64x132) | KLt(64x132); later P(128x132)
    __shared__ float Ms[128 * 68];
    int tid = threadIdx.x;
    int tx = tid & 15, ty = tid >> 4;
    int l0 = blockIdx.x * 128, bh = blockIdx.y;
    int b = bh >> 4, hh = bh & 15;
    float* Qt = buf;
    float* KLt = buf + 64 * 132;

    #pragma unroll
    for (int q = 0; q < 8; ++q) {
        int idx = tid + q * 256;
        int r = idx >> 4, d4 = idx & 15;
        float4 v = *(const float4*)(Q + ((size_t)bh * LPAD + l0 + r) * DH + d4 * 4);
        Qt[(d4 * 4 + 0) * 132 + r] = v.x; Qt[(d4 * 4 + 1) * 132 + r] = v.y;
        Qt[(d4 * 4 + 2) * 132 + r] = v.z; Qt[(d4 * 4 + 3) * 132 + r] = v.w;
        float4 w = *(const float4*)(KLb + ((size_t)bh * NLM + r) * DH + d4 * 4);
        KLt[(d4 * 4 + 0) * 132 + r] = w.x; KLt[(d4 * 4 + 1) * 132 + r] = w.y;
        KLt[(d4 * 4 + 2) * 132 + r] = w.z; KLt[(d4 * 4 + 3) * 132 + r] = w.w;
        float4 u = *(const float4*)(MMb + ((size_t)bh * NLM + r) * DH + d4 * 4);
        *(float4*)&Ms[r * 68 + d4 * 4] = u;
    }
    __syncthreads();

    float acc[8][8];
    #pragma unroll
    for (int i = 0; i < 8; ++i)
        #pragma unroll
        for (int j = 0; j < 8; ++j) acc[i][j] = 0.f;

    #pragma unroll
    for (int k = 0; k < 64; ++k) {
        float av[8], bv[8];
        float4 t0 = *(const float4*)&Qt[k * 132 + ty * 4];
        float4 t1 = *(const float4*)&Qt[k * 132 + 64 + ty * 4];
        float4 t2 = *(const float4*)&KLt[k * 132 + tx * 4];
        float4 t3 = *(const float4*)&KLt[k * 132 + 64 + tx * 4];
        av[0]=t0.x; av[1]=t0.y; av[2]=t0.z; av[3]=t0.w;
        av[4]=t1.x; av[5]=t1.y; av[6]=t1.z; av[7]=t1.w;
        bv[0]=t2.x; bv[1]=t2.y; bv[2]=t2.z; bv[3]=t2.w;
        bv[4]=t3.x; bv[5]=t3.y; bv[6]=t3.z; bv[7]=t3.w;
        #pragma unroll
        for (int i = 0; i < 8; ++i)
            #pragma unroll
            for (int j = 0; j < 8; ++j)
                acc[i][j] = fmaf(av[i], bv[j], acc[i][j]);
    }

    // row softmax over 128 cols
    float m[8], s[8];
    #pragma unroll
    for (int i = 0; i < 8; ++i) {
        m[i] = acc[i][0];
        #pragma unroll
        for (int j = 1; j < 8; ++j) m[i] = fmaxf(m[i], acc[i][j]);
    }
    #pragma unroll
    for (int o = 8; o >= 1; o >>= 1)
        #pragma unroll
        for (int i = 0; i < 8; ++i) m[i] = fmaxf(m[i], __shfl_xor(m[i], o));
    #pragma unroll
    for (int i = 0; i < 8; ++i) {
        s[i] = 0.f;
        #pragma unroll
        for (int j = 0; j < 8; ++j) {
            acc[i][j] = expf(acc[i][j] - m[i]);
            s[i] += acc[i][j];
        }
    }
    #pragma unroll
    for (int o = 8; o >= 1; o >>= 1)
        #pragma unroll
        for (int i = 0; i < 8; ++i) s[i] += __shfl_xor(s[i], o);

    __syncthreads();   // all Qt/KLt reads done; safe to overwrite with P
    #pragma unroll
    for (int i = 0; i < 8; ++i) {
        int r = (i >> 2) * 64 + ty * 4 + (i & 3);
        float inv = 1.f / s[i];
        #pragma unroll
        for (int j = 0; j < 8; ++j) {
            int c = (j >> 2) * 64 + tx * 4 + (j & 3);
            buf[r * 132 + c] = acc[i][j] * inv;
        }
    }
    __syncthreads();

    // out = P @ Ms : each thread 8 rows x 4 cols (d = tx*4..)
    float o2[8][4];
    #pragma unroll
    for (int i = 0; i < 8; ++i)
        #pragma unroll
        for (int j = 0; j < 4; ++j) o2[i][j] = 0.f;
    #pragma unroll 4
    for (int n = 0; n < 128; ++n) {
        float4 b4 = *(const float4*)&Ms[n * 68 + tx * 4];
        float bv[4] = {b4.x, b4.y, b4.z, b4.w};
        #pragma unroll
        for (int i = 0; i < 8; ++i) {
            int r = (i >> 2) * 64 + ty * 4 + (i & 3);
            float a = buf[r * 132 + n];
            #pragma unroll
            for (int j = 0; j < 4; ++j)
                o2[i][j] = fmaf(a, bv[j], o2[i][j]);
        }
    }
    #pragma unroll
    for (int i = 0; i < 8; ++i) {
        int l = l0 + (i >> 2) * 64 + ty * 4 + (i & 3);
        size_t base = ((size_t)b * LPAD + l) * HIDDEN + hh * DH + tx * 4;
        ushort4 h4, l4;
        split2(o2[i][0], h4.x, l4.x); split2(o2[i][1], h4.y, l4.y);
        split2(o2[i][2], h4.z, l4.z); split2(o2[i][3], h4.w, l4.w);
        *(ushort4*)(ATH + base) = h4;
        *(ushort4*)(ATL + base) = l4;
    }
}

// ---------------------------------------------------------------------------
extern "C" void kernel_launch(void* const* d_in, const int* in_sizes, int n_in,
                              void* d_out, int out_size, void* d_ws, size_t ws_size,
                              hipStream_t stream) {
    (void)in_sizes; (void)n_in; (void)out_size; (void)ws_size;
    const float* X    = (const float*)d_in[0];
    const float* mask = (const float*)d_in[1];
    const float* Wq   = (const float*)d_in[2];
    const float* bq   = (const float*)d_in[3];
    const float* Wk   = (const float*)d_in[4];
    const float* bk   = (const float*)d_in[5];
    const float* Wv   = (const float*)d_in[6];
    const float* bv   = (const float*)d_in[7];
    const float* Wo   = (const float*)d_in[8];
    const float* bo   = (const float*)d_in[9];
    float* out = (float*)d_out;
    float* w = (float*)d_ws;

    size_t o = 0;
    u16* WQH = (u16*)(w + o); o += (size_t)HIDDEN * HIDDEN / 2;
    u16* WQL = (u16*)(w + o); o += (size_t)HIDDEN * HIDDEN / 2;
    u16* WKH = (u16*)(w + o); o += (size_t)HIDDEN * HIDDEN / 2;
    u16* WKL = (u16*)(w + o); o += (size_t)HIDDEN * HIDDEN / 2;
    u16* WVH = (u16*)(w + o); o += (size_t)HIDDEN * HIDDEN / 2;
    u16* WVL = (u16*)(w + o); o += (size_t)HIDDEN * HIDDEN / 2;
    u16* WOH = (u16*)(w + o); o += (size_t)HIDDEN * HIDDEN / 2;
    u16* WOL = (u16*)(w + o); o += (size_t)HIDDEN * HIDDEN / 2;
    float* Q   = w + o; o += (size_t)BHT * LPAD * DH;
    float* K   = w + o; o += (size_t)BHT * LPAD * DH;
    float* V   = w + o; o += (size_t)BHT * LPAD * DH;
    float* QL  = w + o; o += (size_t)BHT * NLM * DH;
    float* KL  = w + o; o += (size_t)BHT * NLM * DH;
    float* K2  = w + o; o += (size_t)BHT * NLM * NLM;
    float* VA  = w + o; o += (size_t)BHT * NLM * NLM;
    float* VB  = w + o; o += (size_t)BHT * NLM * NLM;   // K2 pair scratch
    float* KV  = w + o; o += (size_t)BHT * NLM * NLM;   // GVt pair scratch
    float* P1  = w + o; o += (size_t)BHT * NLM * NLM;   // unused
    float* T3  = w + o; o += (size_t)BHT * NLM * NLM;   // unused
    float* PK  = w + o; o += (size_t)BHT * 16 * NLM * DH;
    float* K3V = w + o; o += (size_t)BHT * NLM * DH;
    float* MM  = w + o; o += (size_t)BHT * NLM * DH;
    float* SC  = w + o; o += (size_t)BHT * NLM * LPAD;
    (void)P1; (void)T3;

    u16* K2Hs = (u16*)VB;
    u16* K2Ls = K2Hs + (size_t)BHT * NLM * NLM;
    u16* GVth = (u16*)KV;
    u16* GVtl = GVth + (size_t)BHT * NLM * NLM;

    // Time-shared aliases of the SC region (disjoint live windows):
    u16* XH  = (u16*)SC;
    u16* XL  = XH + (size_t)2 * LPAD * HIDDEN;
    u16* ATH = (u16*)SC;
    u16* ATL = ATH + (size_t)2 * LPAD * HIDDEN;

    k_split_x<<<8192, 256, 0, stream>>>(X, XH, XL);
    k_split_w<<<1024, 256, 0, stream>>>(Wq, WQH, WQL);
    k_split_w<<<1024, 256, 0, stream>>>(Wk, WKH, WKL);
    k_split_w<<<1024, 256, 0, stream>>>(Wv, WVH, WVL);
    k_split_w<<<1024, 256, 0, stream>>>(Wo, WOH, WOL);

    dim3 gg(64, 8);
    k_gemm_bf16<<<gg, 256, 0, stream>>>(XH, XL, WQH, WQL, bq, mask, Q, 0);
    k_gemm_bf16<<<gg, 256, 0, stream>>>(XH, XL, WKH, WKL, bk, mask, K, 0);
    k_gemm_bf16<<<gg, 256, 0, stream>>>(XH, XL, WVH, WVL, bv, nullptr, V, 0);

    k_landmarks<<<dim3(NLM, BHT), 64, 0, stream>>>(Q, K, QL, KL);

    k_qlk<<<dim3(1, BHT), 256, 0, stream>>>(QL, KL, nullptr, K2, NLM, 0);
    k_qlk<<<dim3(32, BHT), 256, 0, stream>>>(QL, K, mask, SC, LPAD, 1);

    k_newton<<<BHT, 256, 0, stream>>>(K2, K2Hs, K2Ls, GVth, GVtl, VA);

    k_softmax4096<<<BHT * NLM, 256, 0, stream>>>(SC);
    k_k3v_partial<<<dim3(16, BHT), 256, 0, stream>>>(SC, V, PK);
    k_k3v_combine<<<(BHT * NLM * DH) / 256, 256, 0, stream>>>(PK, K3V);
    k_bmm<<<dim3(1, 2, BHT), 256, 0, stream>>>(VA, K3V, MM, nullptr, DH, 1.f, 0.f, 0.f, 0.f);

    k_attn<<<dim3(32, BHT), 256, 0, stream>>>(Q, KL, MM, ATH, ATL);
    k_gemm_bf16<<<gg, 256, 0, stream>>>(ATH, ATL, WOH, WOL, bo, nullptr, out, 1);
}

// Round 8
// 756.064 us; speedup vs baseline: 1.1713x; 1.1136x over previous
//
#include <hip/hip_runtime.h>
#include <hip/hip_bf16.h>
#include <math.h>

#define S_ORIG 4095
#define LPAD   4096
#define NHEADS 16
#define DH     64
#define NLM    128
#define BHT    32        // B * NHEADS
#define HIDDEN 1024
#define QKSCALE 0.35355339059327373f   // 1 / 64^0.25

typedef unsigned short u16;
typedef short s16x8 __attribute__((ext_vector_type(8)));
typedef float f32x4 __attribute__((ext_vector_type(4)));

// XOR-swizzled LDS indices (spread row-stride power-of-2 across banks)
#define IDX64(r, c)  ((r) * 64 + ((c) ^ (((r) & 7) << 3)))
#define IDX128(r, c) ((r) * 128 + ((c) ^ (((r) & 7) << 3)))

// ---------------------------------------------------------------------------
// fp32 -> (hi, lo) bf16 split
// ---------------------------------------------------------------------------
__device__ inline void split2(float x, u16& h, u16& l) {
    __hip_bfloat16 bh = __float2bfloat16(x);
    float fh = __bfloat162float(bh);
    __hip_bfloat16 bl = __float2bfloat16(x - fh);
    h = *(u16*)&bh;
    l = *(u16*)&bl;
}

// X (B,4095,1024) fp32 -> XH, XL (8192,1024) bf16-bits, pad row (l==4095) zero.
__global__ __launch_bounds__(256) void k_split_x(const float* __restrict__ X,
                                                 u16* __restrict__ XH,
                                                 u16* __restrict__ XL) {
    int idx = blockIdx.x * 256 + threadIdx.x;      // one thread = 4 elems
    int gr = idx >> 8;                             // row 0..8191
    int c4 = (idx & 255) * 4;
    int b = gr >> 12, l = gr & (LPAD - 1);
    float4 v = make_float4(0.f, 0.f, 0.f, 0.f);
    if (l < S_ORIG) v = *(const float4*)(X + ((size_t)b * S_ORIG + l) * HIDDEN + c4);
    ushort4 h4, l4;
    split2(v.x, h4.x, l4.x); split2(v.y, h4.y, l4.y);
    split2(v.z, h4.z, l4.z); split2(v.w, h4.w, l4.w);
    size_t o = (size_t)gr * HIDDEN + c4;
    *(ushort4*)(XH + o) = h4;
    *(ushort4*)(XL + o) = l4;
}

// W (1024,1024) fp32 -> WH, WL bf16-bits (native [n][k] layout).
__global__ __launch_bounds__(256) void k_split_w(const float* __restrict__ W,
                                                 u16* __restrict__ WH,
                                                 u16* __restrict__ WL) {
    int idx = blockIdx.x * 256 + threadIdx.x;
    size_t o = (size_t)idx * 4;
    float4 v = *(const float4*)(W + o);
    ushort4 h4, l4;
    split2(v.x, h4.x, l4.x); split2(v.y, h4.y, l4.y);
    split2(v.z, h4.z, l4.z); split2(v.w, h4.w, l4.w);
    *(ushort4*)(WH + o) = h4;
    *(ushort4*)(WL + o) = l4;
}

// ---------------------------------------------------------------------------
// Split-bf16 MFMA GEMM:  C = A @ B^T + bias, A 8192x1024 (hi/lo), B 1024x1024
// [n][k] (hi/lo). Logical K = 3072: seg0 = AH*BH, seg1 = AH*BL, seg2 = AL*BH.
// ---------------------------------------------------------------------------
__global__ __launch_bounds__(256) void k_gemm_bf16(
    const u16* __restrict__ AH, const u16* __restrict__ AL,
    const u16* __restrict__ BH, const u16* __restrict__ BL,
    const float* __restrict__ bias, const float* __restrict__ mask,
    float* __restrict__ out, int mode)
{
    __shared__ u16 Alds[128 * 32];
    __shared__ u16 Blds[128 * 32];
    int tid = threadIdx.x;
    int row0 = blockIdx.x * 128, col0 = blockIdx.y * 128;
    int lane = tid & 63, wv = tid >> 6;
    int wr = (wv >> 1) * 64, wc = (wv & 1) * 64;
    int lr = lane & 15, lk = lane >> 4;
    int sr = tid >> 2, sseg = (tid & 3) * 8;       // staging row / k-elem offset

    f32x4 acc[4][4] = {};

    for (int kt = 0; kt < 3072; kt += 32) {
        int s = kt >> 10;
        const u16* Asrc = (s < 2) ? AH : AL;
        const u16* Bsrc = (s == 1) ? BL : BH;
        int ka = kt & 1023;
        #pragma unroll
        for (int h = 0; h < 2; ++h) {
            int r = sr + h * 64;
            __builtin_amdgcn_global_load_lds(
                (const __attribute__((address_space(1))) void*)(Asrc + (size_t)(row0 + r) * HIDDEN + ka + sseg),
                (__attribute__((address_space(3))) void*)(&Alds[r * 32 + sseg]), 16, 0, 0);
            __builtin_amdgcn_global_load_lds(
                (const __attribute__((address_space(1))) void*)(Bsrc + (size_t)(col0 + r) * HIDDEN + ka + sseg),
                (__attribute__((address_space(3))) void*)(&Blds[r * 32 + sseg]), 16, 0, 0);
        }
        __syncthreads();
        s16x8 a[4], b[4];
        #pragma unroll
        for (int i = 0; i < 4; ++i) {
            a[i] = *(const s16x8*)&Alds[(wr + i * 16 + lr) * 32 + lk * 8];
            b[i] = *(const s16x8*)&Blds[(wc + i * 16 + lr) * 32 + lk * 8];
        }
        #pragma unroll
        for (int i = 0; i < 4; ++i)
            #pragma unroll
            for (int j = 0; j < 4; ++j)
                acc[i][j] = __builtin_amdgcn_mfma_f32_16x16x32_bf16(a[i], b[j], acc[i][j], 0, 0, 0);
        __syncthreads();
    }

    #pragma unroll
    for (int i = 0; i < 4; ++i) {
        #pragma unroll
        for (int j = 0; j < 4; ++j) {
            int cc = col0 + wc + j * 16 + lr;
            float bval = bias[cc];
            #pragma unroll
            for (int q = 0; q < 4; ++q) {
                int rr = row0 + wr + i * 16 + lk * 4 + q;
                int bb = rr >> 12, l = rr & (LPAD - 1);
                float val = acc[i][j][q] + bval;
                if (mode == 0) {
                    if (mask) val *= mask[(size_t)bb * LPAD + l] * QKSCALE;
                    out[(((size_t)bb * NHEADS + (cc >> 6)) * LPAD + l) * DH + (cc & 63)] = val;
                } else {
                    if (l < S_ORIG)
                        out[((size_t)bb * S_ORIG + l) * HIDDEN + cc] = val;
                }
            }
        }
    }
}

// ---------------------------------------------------------------------------
// Landmarks: mean over 32 consecutive rows of Q and K. grid (128, 32), 64 thr.
// ---------------------------------------------------------------------------
__global__ void k_landmarks(const float* __restrict__ Q, const float* __restrict__ K,
                            float* __restrict__ QL, float* __restrict__ KL) {
    int n = blockIdx.x, bh = blockIdx.y, d = threadIdx.x;
    size_t base = ((size_t)bh * LPAD + n * 32) * DH + d;
    float sq = 0.f, sk = 0.f;
    #pragma unroll
    for (int s = 0; s < 32; ++s) {
        sq += Q[base + (size_t)s * DH];
        sk += K[base + (size_t)s * DH];
    }
    QL[((size_t)bh * NLM + n) * DH + d] = sq * (1.f / 32.f);
    KL[((size_t)bh * NLM + n) * DH + d] = sk * (1.f / 32.f);
}

// ---------------------------------------------------------------------------
// S = QL @ B^T  (128 x 128, inner 64).
// mode 0: B = KL (128 rows), row-softmax, out K2 (ld 128).
// mode 1: B = K tile (128 rows at n0), out raw scores - 1e9*(1-mask) (ld 4096).
// ---------------------------------------------------------------------------
__global__ __launch_bounds__(256) void k_qlk(const float* __restrict__ QLb,
                                             const float* __restrict__ Bsrc,
                                             const float* __restrict__ mask,
                                             float* __restrict__ out,
                                             int ld_out, int mode) {
    __shared__ float Qt[64][132];
    __shared__ float Bt[64][132];
    int tid = threadIdx.x;
    int tx = tid & 15, ty = tid >> 4;
    int bh = blockIdx.y;
    int n0 = blockIdx.x * 128;
    const float* QLp = QLb + (size_t)bh * NLM * DH;
    const float* Bp = Bsrc + ((mode == 0) ? (size_t)bh * NLM * DH
                                          : (size_t)bh * LPAD * DH + (size_t)n0 * DH);

    #pragma unroll
    for (int q = 0; q < 8; ++q) {
        int idx = tid + q * 256;
        int r = idx >> 4, d4 = idx & 15;
        float4 v = *(const float4*)(QLp + (size_t)r * DH + d4 * 4);
        Qt[d4 * 4 + 0][r] = v.x; Qt[d4 * 4 + 1][r] = v.y;
        Qt[d4 * 4 + 2][r] = v.z; Qt[d4 * 4 + 3][r] = v.w;
        float4 w = *(const float4*)(Bp + (size_t)r * DH + d4 * 4);
        Bt[d4 * 4 + 0][r] = w.x; Bt[d4 * 4 + 1][r] = w.y;
        Bt[d4 * 4 + 2][r] = w.z; Bt[d4 * 4 + 3][r] = w.w;
    }
    __syncthreads();

    float acc[8][8];
    #pragma unroll
    for (int i = 0; i < 8; ++i)
        #pragma unroll
        for (int j = 0; j < 8; ++j) acc[i][j] = 0.f;

    #pragma unroll
    for (int k = 0; k < 64; ++k) {
        float av[8], bv[8];
        float4 t0 = *(const float4*)&Qt[k][ty * 4];
        float4 t1 = *(const float4*)&Qt[k][64 + ty * 4];
        float4 t2 = *(const float4*)&Bt[k][tx * 4];
        float4 t3 = *(const float4*)&Bt[k][64 + tx * 4];
        av[0]=t0.x; av[1]=t0.y; av[2]=t0.z; av[3]=t0.w;
        av[4]=t1.x; av[5]=t1.y; av[6]=t1.z; av[7]=t1.w;
        bv[0]=t2.x; bv[1]=t2.y; bv[2]=t2.z; bv[3]=t2.w;
        bv[4]=t3.x; bv[5]=t3.y; bv[6]=t3.z; bv[7]=t3.w;
        #pragma unroll
        for (int i = 0; i < 8; ++i)
            #pragma unroll
            for (int j = 0; j < 8; ++j)
                acc[i][j] = fmaf(av[i], bv[j], acc[i][j]);
    }

    if (mode == 1) {
        int b = bh >> 4;
        #pragma unroll
        for (int i = 0; i < 8; ++i) {
            int r = (i >> 2) * 64 + ty * 4 + (i & 3);
            #pragma unroll
            for (int jh = 0; jh < 2; ++jh) {
                int c = n0 + jh * 64 + tx * 4;
                float4 m4 = *(const float4*)(mask + (size_t)b * LPAD + c);
                float4 res;
                res.x = acc[i][jh * 4 + 0] - 1e9f * (1.f - m4.x);
                res.y = acc[i][jh * 4 + 1] - 1e9f * (1.f - m4.y);
                res.z = acc[i][jh * 4 + 2] - 1e9f * (1.f - m4.z);
                res.w = acc[i][jh * 4 + 3] - 1e9f * (1.f - m4.w);
                *(float4*)(out + ((size_t)bh * NLM + r) * ld_out + c) = res;
            }
        }
    } else {
        float m[8], s[8];
        #pragma unroll
        for (int i = 0; i < 8; ++i) {
            m[i] = acc[i][0];
            #pragma unroll
            for (int j = 1; j < 8; ++j) m[i] = fmaxf(m[i], acc[i][j]);
        }
        #pragma unroll
        for (int o = 8; o >= 1; o >>= 1)
            #pragma unroll
            for (int i = 0; i < 8; ++i) m[i] = fmaxf(m[i], __shfl_xor(m[i], o));
        #pragma unroll
        for (int i = 0; i < 8; ++i) {
            s[i] = 0.f;
            #pragma unroll
            for (int j = 0; j < 8; ++j) {
                acc[i][j] = expf(acc[i][j] - m[i]);
                s[i] += acc[i][j];
            }
        }
        #pragma unroll
        for (int o = 8; o >= 1; o >>= 1)
            #pragma unroll
            for (int i = 0; i < 8; ++i) s[i] += __shfl_xor(s[i], o);
        #pragma unroll
        for (int i = 0; i < 8; ++i) {
            int r = (i >> 2) * 64 + ty * 4 + (i & 3);
            float inv = 1.f / s[i];
            #pragma unroll
            for (int jh = 0; jh < 2; ++jh) {
                int c = jh * 64 + tx * 4;
                float4 res;
                res.x = acc[i][jh * 4 + 0] * inv;
                res.y = acc[i][jh * 4 + 1] * inv;
                res.z = acc[i][jh * 4 + 2] * inv;
                res.w = acc[i][jh * 4 + 3] * inv;
                *(float4*)(out + ((size_t)bh * NLM + r) * ld_out + c) = res;
            }
        }
    }
}

// ---------------------------------------------------------------------------
// denom + V0 = K2^T / denom. grid 32, 128 threads.
// ---------------------------------------------------------------------------
__global__ void k_v0denom(const float* __restrict__ K2b, float* __restrict__ V0b) {
    int bh = blockIdx.x, t = threadIdx.x;
    const float* K2 = K2b + (size_t)bh * NLM * NLM;
    float* V0 = V0b + (size_t)bh * NLM * NLM;
    float cs = 0.f, rs = 0.f;
    for (int r = 0; r < NLM; ++r) cs += fabsf(K2[r * NLM + t]);
    for (int c = 0; c < NLM; ++c) rs += fabsf(K2[t * NLM + c]);
    __shared__ float sc[128], sr[128];
    sc[t] = cs; sr[t] = rs;
    __syncthreads();
    for (int s = 64; s > 0; s >>= 1) {
        if (t < s) {
            sc[t] = fmaxf(sc[t], sc[t + s]);
            sr[t] = fmaxf(sr[t], sr[t + s]);
        }
        __syncthreads();
    }
    float invden = 1.f / (sc[0] * sr[0]);
    for (int idx = t; idx < NLM * NLM; idx += 128) {
        int i = idx >> 7, j = idx & 127;
        V0[idx] = K2[j * NLM + i] * invden;
    }
}

// ---------------------------------------------------------------------------
// Batched matmul: C = alpha*(A@B) + sI  (A 128x128, B 128xN). fp32 VALU.
// Optional second output C2 = alpha2*(A@B) + s2I.
// ---------------------------------------------------------------------------
__global__ __launch_bounds__(256) void k_bmm(const float* __restrict__ Ab,
                                             const float* __restrict__ Bb,
                                             float* __restrict__ Cb,
                                             float* __restrict__ C2b,
                                             int N, float alpha, float sI,
                                             float alpha2, float sI2) {
    __shared__ float At[128][68];
    __shared__ float Bs[128][68];
    int tid = threadIdx.x;
    int tx = tid & 15, ty = tid >> 4;
    int bh = blockIdx.z;
    int r0 = blockIdx.y * 64, c0 = blockIdx.x * 64;
    const float* A = Ab + (size_t)bh * NLM * NLM;
    const float* Bm = Bb + (size_t)bh * NLM * N;

    #pragma unroll
    for (int q = 0; q < 8; ++q) {
        int idx = tid + q * 256;
        int r = idx >> 5, k4 = idx & 31;
        float4 v = *(const float4*)(A + (size_t)(r0 + r) * NLM + k4 * 4);
        At[k4 * 4 + 0][r] = v.x; At[k4 * 4 + 1][r] = v.y;
        At[k4 * 4 + 2][r] = v.z; At[k4 * 4 + 3][r] = v.w;
        int bk = idx >> 4, c4 = idx & 15;
        float4 w = *(const float4*)(Bm + (size_t)bk * N + c0 + c4 * 4);
        *(float4*)&Bs[bk][c4 * 4] = w;
    }
    __syncthreads();

    float acc[4][4];
    #pragma unroll
    for (int i = 0; i < 4; ++i)
        #pragma unroll
        for (int j = 0; j < 4; ++j) acc[i][j] = 0.f;

    #pragma unroll 4
    for (int k = 0; k < 128; ++k) {
        float4 a = *(const float4*)&At[k][ty * 4];
        float4 b = *(const float4*)&Bs[k][tx * 4];
        float av[4] = {a.x, a.y, a.z, a.w};
        float bv[4] = {b.x, b.y, b.z, b.w};
        #pragma unroll
        for (int i = 0; i < 4; ++i)
            #pragma unroll
            for (int j = 0; j < 4; ++j)
                acc[i][j] = fmaf(av[i], bv[j], acc[i][j]);
    }

    float* C = Cb + (size_t)bh * NLM * N;
    float* C2 = C2b ? (C2b + (size_t)bh * NLM * N) : nullptr;
    #pragma unroll
    for (int i = 0; i < 4; ++i) {
        int gr = r0 + ty * 4 + i;
        int gc0 = c0 + tx * 4;
        float4 res, res2;
        float* rp = &res.x; float* rp2 = &res2.x;
        #pragma unroll
        for (int j = 0; j < 4; ++j) {
            float idadd = (gr == gc0 + j) ? 1.f : 0.f;
            rp[j] = alpha * acc[i][j] + sI * idadd;
            rp2[j] = alpha2 * acc[i][j] + sI2 * idadd;
        }
        *(float4*)(C + (size_t)gr * N + gc0) = res;
        if (C2) *(float4*)(C2 + (size_t)gr * N + gc0) = res2;
    }
}

// ---------------------------------------------------------------------------
// Row softmax over 4096-long rows of SC (in place). grid 4096, 256 threads.
// ---------------------------------------------------------------------------
__global__ __launch_bounds__(256) void k_softmax4096(float* __restrict__ SC) {
    float* p = SC + (size_t)blockIdx.x * LPAD;
    int tid = threadIdx.x;
    float4 v[4];
    #pragma unroll
    for (int q = 0; q < 4; ++q) v[q] = *(float4*)(p + tid * 16 + q * 4);

    float m = -1e30f;
    #pragma unroll
    for (int q = 0; q < 4; ++q) {
        m = fmaxf(m, fmaxf(fmaxf(v[q].x, v[q].y), fmaxf(v[q].z, v[q].w)));
    }
    __shared__ float red[4], red2[4];
    for (int o = 32; o >= 1; o >>= 1) m = fmaxf(m, __shfl_xor(m, o));
    int wid = tid >> 6;
    if ((tid & 63) == 0) red[wid] = m;
    __syncthreads();
    m = fmaxf(fmaxf(red[0], red[1]), fmaxf(red[2], red[3]));

    float s = 0.f;
    #pragma unroll
    for (int q = 0; q < 4; ++q) {
        v[q].x = expf(v[q].x - m); v[q].y = expf(v[q].y - m);
        v[q].z = expf(v[q].z - m); v[q].w = expf(v[q].w - m);
        s += v[q].x + v[q].y + v[q].z + v[q].w;
    }
    for (int o = 32; o >= 1; o >>= 1) s += __shfl_xor(s, o);
    if ((tid & 63) == 0) red2[wid] = s;
    __syncthreads();
    s = red2[0] + red2[1] + red2[2] + red2[3];
    float inv = 1.f / s;
    #pragma unroll
    for (int q = 0; q < 4; ++q) {
        v[q].x *= inv; v[q].y *= inv; v[q].z *= inv; v[q].w *= inv;
        *(float4*)(p + tid * 16 + q * 4) = v[q];
    }
}

// ---------------------------------------------------------------------------
// Partial kernel_3 @ V over a 256-wide n chunk. grid (16, 32), 256 threads.
// ---------------------------------------------------------------------------
__global__ __launch_bounds__(256) void k_k3v_partial(const float* __restrict__ SC,
                                                     const float* __restrict__ V,
                                                     float* __restrict__ P) {
    __shared__ float Pt[64][132];
    __shared__ float Vs[64][68];
    int tid = threadIdx.x;
    int tx = tid & 7, ty = tid >> 3;
    int sp = blockIdx.x, bh = blockIdx.y;
    int n0 = sp * 256;

    float acc[4][8];
    #pragma unroll
    for (int i = 0; i < 4; ++i)
        #pragma unroll
        for (int j = 0; j < 8; ++j) acc[i][j] = 0.f;

    for (int ns = 0; ns < 4; ++ns) {
        int nb = n0 + ns * 64;
        #pragma unroll
        for (int q = 0; q < 8; ++q) {
            int idx = tid + q * 256;
            int r = idx >> 4, n4 = idx & 15;
            float4 v = *(const float4*)(SC + ((size_t)bh * NLM + r) * LPAD + nb + n4 * 4);
            Pt[n4 * 4 + 0][r] = v.x; Pt[n4 * 4 + 1][r] = v.y;
            Pt[n4 * 4 + 2][r] = v.z; Pt[n4 * 4 + 3][r] = v.w;
        }
        #pragma unroll
        for (int q = 0; q < 4; ++q) {
            int idx = tid + q * 256;
            int vr = idx >> 4, d4 = idx & 15;
            float4 w = *(const float4*)(V + ((size_t)bh * LPAD + nb + vr) * DH + d4 * 4);
            *(float4*)&Vs[vr][d4 * 4] = w;
        }
        __syncthreads();
        #pragma unroll 4
        for (int nn = 0; nn < 64; ++nn) {
            float4 a4 = *(const float4*)&Pt[nn][ty * 4];
            float4 b0 = *(const float4*)&Vs[nn][tx * 8];
            float4 b1 = *(const float4*)&Vs[nn][tx * 8 + 4];
            float a[4] = {a4.x, a4.y, a4.z, a4.w};
            float b[8] = {b0.x, b0.y, b0.z, b0.w, b1.x, b1.y, b1.z, b1.w};
            #pragma unroll
            for (int i = 0; i < 4; ++i)
                #pragma unroll
                for (int j = 0; j < 8; ++j)
                    acc[i][j] = fmaf(a[i], b[j], acc[i][j]);
        }
        __syncthreads();
    }
    #pragma unroll
    for (int i = 0; i < 4; ++i) {
        int r = ty * 4 + i, d = tx * 8;
        *(float4*)(P + (((size_t)bh * 16 + sp) * NLM + r) * DH + d) =
            make_float4(acc[i][0], acc[i][1], acc[i][2], acc[i][3]);
        *(float4*)(P + (((size_t)bh * 16 + sp) * NLM + r) * DH + d + 4) =
            make_float4(acc[i][4], acc[i][5], acc[i][6], acc[i][7]);
    }
}

__global__ void k_k3v_combine(const float* __restrict__ P, float* __restrict__ O) {
    int idx = blockIdx.x * 256 + threadIdx.x;
    int bh = idx >> 13, rem = idx & 8191;
    float s = 0.f;
    for (int sp = 0; sp < 16; ++sp)
        s += P[((size_t)bh * 16 + sp) * 8192 + rem];
    O[idx] = s;
}

// ---------------------------------------------------------------------------
// kernel_1 fused via split-bf16 MFMA: ATTN = softmax(Q_tile @ KL^T) @ MM.
// grid (32 l-tiles, 32 bh), 256 threads (4 waves). Each wave owns 32 FULL
// rows (all 128 cols) in BOTH matmuls, so the row-softmax reduces entirely
// within the wave's 16-lane groups (R7 bug fix: no cross-wave row split).
// LDS 96 KB: [Qh Ql KLh KLl] (64KB, IDX64) -> later [Ph Pl] (64KB, IDX128);
//            [Mth Mtl] (32KB, MM transposed [d][n], IDX128).
// ---------------------------------------------------------------------------
__global__ __launch_bounds__(256) void k_attn(const float* __restrict__ Q,
                                              const float* __restrict__ KLb,
                                              const float* __restrict__ MMb,
                                              u16* __restrict__ ATH,
                                              u16* __restrict__ ATL) {
    __shared__ u16 lds[49152];
    u16* Qh  = lds;               // 8192 (128x64)
    u16* Ql  = lds + 8192;
    u16* KLh = lds + 16384;
    u16* KLl = lds + 24576;
    u16* Ph  = lds;               // 16384 (128x128), overwrites Q/KL
    u16* Pl  = lds + 16384;
    u16* Mth = lds + 32768;       // 8192 (64x128)
    u16* Mtl = lds + 40960;

    int tid = threadIdx.x;
    int lane = tid & 63, wv = tid >> 6;
    int lr = lane & 15, lk = lane >> 4;
    int l0 = blockIdx.x * 128, bh = blockIdx.y;
    int b = bh >> 4, hh = bh & 15;
    int wrA = wv * 32;            // wave's 32 rows (both matmuls)

    // ---- stage Q, KL (split, IDX64) ----
    #pragma unroll
    for (int q = 0; q < 4; ++q) {
        int idx = tid + q * 256;
        int r = idx >> 3, c8 = (idx & 7) * 8;
        float4 v0 = *(const float4*)(Q + ((size_t)bh * LPAD + l0 + r) * DH + c8);
        float4 v1 = *(const float4*)(Q + ((size_t)bh * LPAD + l0 + r) * DH + c8 + 4);
        float xs[8] = {v0.x, v0.y, v0.z, v0.w, v1.x, v1.y, v1.z, v1.w};
        s16x8 h8, l8;
        #pragma unroll
        for (int e = 0; e < 8; ++e) {
            u16 hh2, ll2; split2(xs[e], hh2, ll2);
            h8[e] = (short)hh2; l8[e] = (short)ll2;
        }
        *(s16x8*)&Qh[IDX64(r, c8)] = h8;
        *(s16x8*)&Ql[IDX64(r, c8)] = l8;

        float4 w0 = *(const float4*)(KLb + ((size_t)bh * NLM + r) * DH + c8);
        float4 w1 = *(const float4*)(KLb + ((size_t)bh * NLM + r) * DH + c8 + 4);
        float ys[8] = {w0.x, w0.y, w0.z, w0.w, w1.x, w1.y, w1.z, w1.w};
        #pragma unroll
        for (int e = 0; e < 8; ++e) {
            u16 hh2, ll2; split2(ys[e], hh2, ll2);
            h8[e] = (short)hh2; l8[e] = (short)ll2;
        }
        *(s16x8*)&KLh[IDX64(r, c8)] = h8;
        *(s16x8*)&KLl[IDX64(r, c8)] = l8;
    }
    // ---- stage MM transposed (split, IDX128) ----
    #pragma unroll
    for (int q = 0; q < 8; ++q) {
        int idx = tid + q * 256;
        int n = idx >> 4, d4 = (idx & 15) * 4;
        float4 v = *(const float4*)(MMb + ((size_t)bh * NLM + n) * DH + d4);
        float xs[4] = {v.x, v.y, v.z, v.w};
        #pragma unroll
        for (int e = 0; e < 4; ++e) {
            u16 hh2, ll2; split2(xs[e], hh2, ll2);
            Mth[IDX128(d4 + e, n)] = hh2;
            Mtl[IDX128(d4 + e, n)] = ll2;
        }
    }
    __syncthreads();

    // ---- S = Q @ KL^T : wave owns 32 rows x 128 cols (t4[2][8]) ----
    f32x4 t4[2][8] = {};
    #pragma unroll
    for (int t = 0; t < 3; ++t) {
        const u16* Xs = (t == 2) ? Ql : Qh;
        const u16* Ys = (t == 1) ? KLl : KLh;
        #pragma unroll
        for (int kc = 0; kc < 2; ++kc) {
            s16x8 a[2], bfr[8];
            #pragma unroll
            for (int i = 0; i < 2; ++i)
                a[i] = *(const s16x8*)&Xs[IDX64(wrA + i * 16 + lr, kc * 32 + lk * 8)];
            #pragma unroll
            for (int j = 0; j < 8; ++j)
                bfr[j] = *(const s16x8*)&Ys[IDX64(j * 16 + lr, kc * 32 + lk * 8)];
            #pragma unroll
            for (int i = 0; i < 2; ++i)
                #pragma unroll
                for (int j = 0; j < 8; ++j)
                    t4[i][j] = __builtin_amdgcn_mfma_f32_16x16x32_bf16(a[i], bfr[j], t4[i][j], 0, 0, 0);
        }
    }

    // ---- row softmax: row = wrA+i*16+lk*4+q; its 128 cols = {j*16+lr} all
    //      in this wave (8 j-frags x 16 lr lanes) ----
    #pragma unroll
    for (int i = 0; i < 2; ++i)
        #pragma unroll
        for (int q = 0; q < 4; ++q) {
            float m = t4[i][0][q];
            #pragma unroll
            for (int j = 1; j < 8; ++j) m = fmaxf(m, t4[i][j][q]);
            m = fmaxf(m, __shfl_xor(m, 1));
            m = fmaxf(m, __shfl_xor(m, 2));
            m = fmaxf(m, __shfl_xor(m, 4));
            m = fmaxf(m, __shfl_xor(m, 8));
            float s = 0.f;
            #pragma unroll
            for (int j = 0; j < 8; ++j) {
                t4[i][j][q] = expf(t4[i][j][q] - m);
                s += t4[i][j][q];
            }
            s += __shfl_xor(s, 1);
            s += __shfl_xor(s, 2);
            s += __shfl_xor(s, 4);
            s += __shfl_xor(s, 8);
            float inv = 1.f / s;
            #pragma unroll
            for (int j = 0; j < 8; ++j) t4[i][j][q] *= inv;
        }

    __syncthreads();   // Q/KL reads done; safe to overwrite with P
    #pragma unroll
    for (int i = 0; i < 2; ++i)
        #pragma unroll
        for (int j = 0; j < 8; ++j) {
            int col = j * 16 + lr;
            #pragma unroll
            for (int q = 0; q < 4; ++q) {
                int row = wrA + i * 16 + lk * 4 + q;
                u16 hh2, ll2; split2(t4[i][j][q], hh2, ll2);
                Ph[IDX128(row, col)] = hh2;
                Pl[IDX128(row, col)] = ll2;
            }
        }
    __syncthreads();

    // ---- O = P @ MM (K=128, 3 split terms); wave computes 32 rows x 64 cols ----
    f32x4 t5[2][4] = {};
    #pragma unroll
    for (int t = 0; t < 3; ++t) {
        const u16* Xs = (t == 2) ? Pl : Ph;
        const u16* Ys = (t == 1) ? Mtl : Mth;
        #pragma unroll
        for (int kc = 0; kc < 4; ++kc) {
            s16x8 a[2], bfr[4];
            #pragma unroll
            for (int i = 0; i < 2; ++i)
                a[i] = *(const s16x8*)&Xs[IDX128(wrA + i * 16 + lr, kc * 32 + lk * 8)];
            #pragma unroll
            for (int j = 0; j < 4; ++j)
                bfr[j] = *(const s16x8*)&Ys[IDX128(j * 16 + lr, kc * 32 + lk * 8)];
            #pragma unroll
            for (int i = 0; i < 2; ++i)
                #pragma unroll
                for (int j = 0; j < 4; ++j)
                    t5[i][j] = __builtin_amdgcn_mfma_f32_16x16x32_bf16(a[i], bfr[j], t5[i][j], 0, 0, 0);
        }
    }

    // ---- epilogue: split O -> ATH/ATL ----
    #pragma unroll
    for (int i = 0; i < 2; ++i)
        #pragma unroll
        for (int j = 0; j < 4; ++j) {
            int d = j * 16 + lr;
            #pragma unroll
            for (int q = 0; q < 4; ++q) {
                int l = l0 + wrA + i * 16 + lk * 4 + q;
                size_t base = ((size_t)b * LPAD + l) * HIDDEN + hh * DH + d;
                u16 hh2, ll2; split2(t5[i][j][q], hh2, ll2);
                ATH[base] = hh2;
                ATL[base] = ll2;
            }
        }
}

// ---------------------------------------------------------------------------
extern "C" void kernel_launch(void* const* d_in, const int* in_sizes, int n_in,
                              void* d_out, int out_size, void* d_ws, size_t ws_size,
                              hipStream_t stream) {
    (void)in_sizes; (void)n_in; (void)out_size; (void)ws_size;
    const float* X    = (const float*)d_in[0];
    const float* mask = (const float*)d_in[1];
    const float* Wq   = (const float*)d_in[2];
    const float* bq   = (const float*)d_in[3];
    const float* Wk   = (const float*)d_in[4];
    const float* bk   = (const float*)d_in[5];
    const float* Wv   = (const float*)d_in[6];
    const float* bv   = (const float*)d_in[7];
    const float* Wo   = (const float*)d_in[8];
    const float* bo   = (const float*)d_in[9];
    float* out = (float*)d_out;
    float* w = (float*)d_ws;

    size_t o = 0;
    u16* WQH = (u16*)(w + o); o += (size_t)HIDDEN * HIDDEN / 2;
    u16* WQL = (u16*)(w + o); o += (size_t)HIDDEN * HIDDEN / 2;
    u16* WKH = (u16*)(w + o); o += (size_t)HIDDEN * HIDDEN / 2;
    u16* WKL = (u16*)(w + o); o += (size_t)HIDDEN * HIDDEN / 2;
    u16* WVH = (u16*)(w + o); o += (size_t)HIDDEN * HIDDEN / 2;
    u16* WVL = (u16*)(w + o); o += (size_t)HIDDEN * HIDDEN / 2;
    u16* WOH = (u16*)(w + o); o += (size_t)HIDDEN * HIDDEN / 2;
    u16* WOL = (u16*)(w + o); o += (size_t)HIDDEN * HIDDEN / 2;
    float* Q   = w + o; o += (size_t)BHT * LPAD * DH;
    float* K   = w + o; o += (size_t)BHT * LPAD * DH;
    float* V   = w + o; o += (size_t)BHT * LPAD * DH;
    float* QL  = w + o; o += (size_t)BHT * NLM * DH;
    float* KL  = w + o; o += (size_t)BHT * NLM * DH;
    float* K2  = w + o; o += (size_t)BHT * NLM * NLM;
    float* VA  = w + o; o += (size_t)BHT * NLM * NLM;
    float* VB  = w + o; o += (size_t)BHT * NLM * NLM;
    float* KV  = w + o; o += (size_t)BHT * NLM * NLM;
    float* P1  = w + o; o += (size_t)BHT * NLM * NLM;
    float* T3  = w + o; o += (size_t)BHT * NLM * NLM;
    float* PK  = w + o; o += (size_t)BHT * 16 * NLM * DH;
    float* K3V = w + o; o += (size_t)BHT * NLM * DH;
    float* MM  = w + o; o += (size_t)BHT * NLM * DH;
    float* SC  = w + o; o += (size_t)BHT * NLM * LPAD;

    // Time-shared aliases of the SC region (disjoint live windows):
    u16* XH  = (u16*)SC;
    u16* XL  = XH + (size_t)2 * LPAD * HIDDEN;
    u16* ATH = (u16*)SC;
    u16* ATL = ATH + (size_t)2 * LPAD * HIDDEN;

    k_split_x<<<8192, 256, 0, stream>>>(X, XH, XL);
    k_split_w<<<1024, 256, 0, stream>>>(Wq, WQH, WQL);
    k_split_w<<<1024, 256, 0, stream>>>(Wk, WKH, WKL);
    k_split_w<<<1024, 256, 0, stream>>>(Wv, WVH, WVL);
    k_split_w<<<1024, 256, 0, stream>>>(Wo, WOH, WOL);

    dim3 gg(64, 8);
    k_gemm_bf16<<<gg, 256, 0, stream>>>(XH, XL, WQH, WQL, bq, mask, Q, 0);
    k_gemm_bf16<<<gg, 256, 0, stream>>>(XH, XL, WKH, WKL, bk, mask, K, 0);
    k_gemm_bf16<<<gg, 256, 0, stream>>>(XH, XL, WVH, WVL, bv, nullptr, V, 0);

    k_landmarks<<<dim3(NLM, BHT), 64, 0, stream>>>(Q, K, QL, KL);

    k_qlk<<<dim3(1, BHT), 256, 0, stream>>>(QL, KL, nullptr, K2, NLM, 0);
    k_qlk<<<dim3(32, BHT), 256, 0, stream>>>(QL, K, mask, SC, LPAD, 1);

    k_v0denom<<<BHT, 128, 0, stream>>>(K2, VA);
    float* cur = VA;
    float* nxt = VB;
    for (int it = 0; it < 6; ++it) {
        k_bmm<<<dim3(2, 2, BHT), 256, 0, stream>>>(K2, cur, KV, P1, NLM, 1.f, 0.f, -1.f, 7.f);
        k_bmm<<<dim3(2, 2, BHT), 256, 0, stream>>>(KV, P1, T3, nullptr, NLM, -1.f, 15.f, 0.f, 0.f);
        k_bmm<<<dim3(2, 2, BHT), 256, 0, stream>>>(KV, T3, P1, nullptr, NLM, -1.f, 13.f, 0.f, 0.f);
        k_bmm<<<dim3(2, 2, BHT), 256, 0, stream>>>(cur, P1, nxt, nullptr, NLM, 0.25f, 0.f, 0.f, 0.f);
        float* t = cur; cur = nxt; nxt = t;
    }

    k_softmax4096<<<BHT * NLM, 256, 0, stream>>>(SC);
    k_k3v_partial<<<dim3(16, BHT), 256, 0, stream>>>(SC, V, PK);
    k_k3v_combine<<<(BHT * NLM * DH) / 256, 256, 0, stream>>>(PK, K3V);
    k_bmm<<<dim3(1, 2, BHT), 256, 0, stream>>>(cur, K3V, MM, nullptr, DH, 1.f, 0.f, 0.f, 0.f);

    k_attn<<<dim3(32, BHT), 256, 0, stream>>>(Q, KL, MM, ATH, ATL);
    k_gemm_bf16<<<gg, 256, 0, stream>>>(ATH, ATL, WOH, WOL, bo, nullptr, out, 1);
}

// Round 9
// 692.250 us; speedup vs baseline: 1.2793x; 1.0922x over previous
//
#include <hip/hip_runtime.h>
#include <hip/hip_bf16.h>
#include <math.h>

#define S_ORIG 4095
#define LPAD   4096
#define NHEADS 16
#define DH     64
#define NLM    128
#define BHT    32        // B * NHEADS
#define HIDDEN 1024
#define QKSCALE 0.35355339059327373f   // 1 / 64^0.25

typedef unsigned short u16;
typedef short s16x8 __attribute__((ext_vector_type(8)));
typedef float f32x4 __attribute__((ext_vector_type(4)));

// XOR-swizzled LDS indices (spread row-stride power-of-2 across banks)
#define IDX64(r, c)  ((r) * 64 + ((c) ^ (((r) & 7) << 3)))
#define IDX128(r, c) ((r) * 128 + ((c) ^ (((r) & 7) << 3)))

// ---------------------------------------------------------------------------
// fp32 -> (hi, lo) bf16 split
// ---------------------------------------------------------------------------
__device__ inline void split2(float x, u16& h, u16& l) {
    __hip_bfloat16 bh = __float2bfloat16(x);
    float fh = __bfloat162float(bh);
    __hip_bfloat16 bl = __float2bfloat16(x - fh);
    h = *(u16*)&bh;
    l = *(u16*)&bl;
}

// X (B,4095,1024) fp32 -> XH, XL (8192,1024) bf16-bits, pad row (l==4095) zero.
__global__ __launch_bounds__(256) void k_split_x(const float* __restrict__ X,
                                                 u16* __restrict__ XH,
                                                 u16* __restrict__ XL) {
    int idx = blockIdx.x * 256 + threadIdx.x;      // one thread = 4 elems
    int gr = idx >> 8;                             // row 0..8191
    int c4 = (idx & 255) * 4;
    int b = gr >> 12, l = gr & (LPAD - 1);
    float4 v = make_float4(0.f, 0.f, 0.f, 0.f);
    if (l < S_ORIG) v = *(const float4*)(X + ((size_t)b * S_ORIG + l) * HIDDEN + c4);
    ushort4 h4, l4;
    split2(v.x, h4.x, l4.x); split2(v.y, h4.y, l4.y);
    split2(v.z, h4.z, l4.z); split2(v.w, h4.w, l4.w);
    size_t o = (size_t)gr * HIDDEN + c4;
    *(ushort4*)(XH + o) = h4;
    *(ushort4*)(XL + o) = l4;
}

// W (1024,1024) fp32 -> WH, WL bf16-bits (native [n][k] layout).
__global__ __launch_bounds__(256) void k_split_w(const float* __restrict__ W,
                                                 u16* __restrict__ WH,
                                                 u16* __restrict__ WL) {
    int idx = blockIdx.x * 256 + threadIdx.x;
    size_t o = (size_t)idx * 4;
    float4 v = *(const float4*)(W + o);
    ushort4 h4, l4;
    split2(v.x, h4.x, l4.x); split2(v.y, h4.y, l4.y);
    split2(v.z, h4.z, l4.z); split2(v.w, h4.w, l4.w);
    *(ushort4*)(WH + o) = h4;
    *(ushort4*)(WL + o) = l4;
}

// ---------------------------------------------------------------------------
// Split-bf16 MFMA GEMM:  C = A @ B^T + bias, A 8192x1024 (hi/lo), B 1024x1024
// [n][k] (hi/lo). SINGLE pass over K=1024: per 32-K step all four tiles
// (AH, AL, BH, BL) are resident in LDS and 48 MFMAs cover the 3 split terms
// AH*BH + AH*BL + AL*BH.  Bank-conflict fix per rule #21: LDS dest stays
// linear (global_load_lds lane-stride), the global SOURCE column is
// inverse-swizzled (chunk ^ (row>>1)&3), and fragment reads apply the same
// XOR -> 8 distinct 16B slots per 8 lanes (2-way aliasing, free).
// ---------------------------------------------------------------------------
__global__ __launch_bounds__(256) void k_gemm_bf16(
    const u16* __restrict__ AH, const u16* __restrict__ AL,
    const u16* __restrict__ BH, const u16* __restrict__ BL,
    const float* __restrict__ bias, const float* __restrict__ mask,
    float* __restrict__ out, int mode)
{
    __shared__ u16 Ah_lds[128 * 32];
    __shared__ u16 Al_lds[128 * 32];
    __shared__ u16 Bh_lds[128 * 32];
    __shared__ u16 Bl_lds[128 * 32];
    int tid = threadIdx.x;
    int row0 = blockIdx.x * 128, col0 = blockIdx.y * 128;
    int lane = tid & 63, wv = tid >> 6;
    int wr = (wv >> 1) * 64, wc = (wv & 1) * 64;
    int lr = lane & 15, lk = lane >> 4;
    int sr = tid >> 2, sc = tid & 3;               // staging row (0..63), chunk (0..3)

    f32x4 acc[4][4] = {};

    for (int kt = 0; kt < 1024; kt += 32) {
        #pragma unroll
        for (int h = 0; h < 2; ++h) {
            int r = sr + h * 64;
            int csrc = (sc ^ ((r >> 1) & 3)) * 8;  // inverse-swizzled source col
            size_t ga = (size_t)(row0 + r) * HIDDEN + kt + csrc;
            size_t gb = (size_t)(col0 + r) * HIDDEN + kt + csrc;
            int ldst = r * 32 + sc * 8;            // linear dest (lane*16B)
            __builtin_amdgcn_global_load_lds(
                (const __attribute__((address_space(1))) void*)(AH + ga),
                (__attribute__((address_space(3))) void*)(&Ah_lds[ldst]), 16, 0, 0);
            __builtin_amdgcn_global_load_lds(
                (const __attribute__((address_space(1))) void*)(AL + ga),
                (__attribute__((address_space(3))) void*)(&Al_lds[ldst]), 16, 0, 0);
            __builtin_amdgcn_global_load_lds(
                (const __attribute__((address_space(1))) void*)(BH + gb),
                (__attribute__((address_space(3))) void*)(&Bh_lds[ldst]), 16, 0, 0);
            __builtin_amdgcn_global_load_lds(
                (const __attribute__((address_space(1))) void*)(BL + gb),
                (__attribute__((address_space(3))) void*)(&Bl_lds[ldst]), 16, 0, 0);
        }
        __syncthreads();
        s16x8 ah[4], al[4], bh[4], bl[4];
        #pragma unroll
        for (int i = 0; i < 4; ++i) {
            int ra = wr + i * 16 + lr;
            int rb = wc + i * 16 + lr;
            int ca = (lk ^ ((ra >> 1) & 3)) * 8;   // swizzled read col
            int cb = (lk ^ ((rb >> 1) & 3)) * 8;
            ah[i] = *(const s16x8*)&Ah_lds[ra * 32 + ca];
            al[i] = *(const s16x8*)&Al_lds[ra * 32 + ca];
            bh[i] = *(const s16x8*)&Bh_lds[rb * 32 + cb];
            bl[i] = *(const s16x8*)&Bl_lds[rb * 32 + cb];
        }
        #pragma unroll
        for (int i = 0; i < 4; ++i)
            #pragma unroll
            for (int j = 0; j < 4; ++j)
                acc[i][j] = __builtin_amdgcn_mfma_f32_16x16x32_bf16(ah[i], bh[j], acc[i][j], 0, 0, 0);
        #pragma unroll
        for (int i = 0; i < 4; ++i)
            #pragma unroll
            for (int j = 0; j < 4; ++j)
                acc[i][j] = __builtin_amdgcn_mfma_f32_16x16x32_bf16(ah[i], bl[j], acc[i][j], 0, 0, 0);
        #pragma unroll
        for (int i = 0; i < 4; ++i)
            #pragma unroll
            for (int j = 0; j < 4; ++j)
                acc[i][j] = __builtin_amdgcn_mfma_f32_16x16x32_bf16(al[i], bh[j], acc[i][j], 0, 0, 0);
        __syncthreads();
    }

    #pragma unroll
    for (int i = 0; i < 4; ++i) {
        #pragma unroll
        for (int j = 0; j < 4; ++j) {
            int cc = col0 + wc + j * 16 + lr;
            float bval = bias[cc];
            #pragma unroll
            for (int q = 0; q < 4; ++q) {
                int rr = row0 + wr + i * 16 + lk * 4 + q;
                int bb = rr >> 12, l = rr & (LPAD - 1);
                float val = acc[i][j][q] + bval;
                if (mode == 0) {
                    if (mask) val *= mask[(size_t)bb * LPAD + l] * QKSCALE;
                    out[(((size_t)bb * NHEADS + (cc >> 6)) * LPAD + l) * DH + (cc & 63)] = val;
                } else {
                    if (l < S_ORIG)
                        out[((size_t)bb * S_ORIG + l) * HIDDEN + cc] = val;
                }
            }
        }
    }
}

// ---------------------------------------------------------------------------
// Landmarks: mean over 32 consecutive rows of Q and K. grid (128, 32), 64 thr.
// ---------------------------------------------------------------------------
__global__ void k_landmarks(const float* __restrict__ Q, const float* __restrict__ K,
                            float* __restrict__ QL, float* __restrict__ KL) {
    int n = blockIdx.x, bh = blockIdx.y, d = threadIdx.x;
    size_t base = ((size_t)bh * LPAD + n * 32) * DH + d;
    float sq = 0.f, sk = 0.f;
    #pragma unroll
    for (int s = 0; s < 32; ++s) {
        sq += Q[base + (size_t)s * DH];
        sk += K[base + (size_t)s * DH];
    }
    QL[((size_t)bh * NLM + n) * DH + d] = sq * (1.f / 32.f);
    KL[((size_t)bh * NLM + n) * DH + d] = sk * (1.f / 32.f);
}

// ---------------------------------------------------------------------------
// S = QL @ B^T  (128 x 128, inner 64).
// mode 0: B = KL (128 rows), row-softmax, out K2 (ld 128).
// mode 1: B = K tile (128 rows at n0), out raw scores - 1e9*(1-mask) (ld 4096).
// ---------------------------------------------------------------------------
__global__ __launch_bounds__(256) void k_qlk(const float* __restrict__ QLb,
                                             const float* __restrict__ Bsrc,
                                             const float* __restrict__ mask,
                                             float* __restrict__ out,
                                             int ld_out, int mode) {
    __shared__ float Qt[64][132];
    __shared__ float Bt[64][132];
    int tid = threadIdx.x;
    int tx = tid & 15, ty = tid >> 4;
    int bh = blockIdx.y;
    int n0 = blockIdx.x * 128;
    const float* QLp = QLb + (size_t)bh * NLM * DH;
    const float* Bp = Bsrc + ((mode == 0) ? (size_t)bh * NLM * DH
                                          : (size_t)bh * LPAD * DH + (size_t)n0 * DH);

    #pragma unroll
    for (int q = 0; q < 8; ++q) {
        int idx = tid + q * 256;
        int r = idx >> 4, d4 = idx & 15;
        float4 v = *(const float4*)(QLp + (size_t)r * DH + d4 * 4);
        Qt[d4 * 4 + 0][r] = v.x; Qt[d4 * 4 + 1][r] = v.y;
        Qt[d4 * 4 + 2][r] = v.z; Qt[d4 * 4 + 3][r] = v.w;
        float4 w = *(const float4*)(Bp + (size_t)r * DH + d4 * 4);
        Bt[d4 * 4 + 0][r] = w.x; Bt[d4 * 4 + 1][r] = w.y;
        Bt[d4 * 4 + 2][r] = w.z; Bt[d4 * 4 + 3][r] = w.w;
    }
    __syncthreads();

    float acc[8][8];
    #pragma unroll
    for (int i = 0; i < 8; ++i)
        #pragma unroll
        for (int j = 0; j < 8; ++j) acc[i][j] = 0.f;

    #pragma unroll
    for (int k = 0; k < 64; ++k) {
        float av[8], bv[8];
        float4 t0 = *(const float4*)&Qt[k][ty * 4];
        float4 t1 = *(const float4*)&Qt[k][64 + ty * 4];
        float4 t2 = *(const float4*)&Bt[k][tx * 4];
        float4 t3 = *(const float4*)&Bt[k][64 + tx * 4];
        av[0]=t0.x; av[1]=t0.y; av[2]=t0.z; av[3]=t0.w;
        av[4]=t1.x; av[5]=t1.y; av[6]=t1.z; av[7]=t1.w;
        bv[0]=t2.x; bv[1]=t2.y; bv[2]=t2.z; bv[3]=t2.w;
        bv[4]=t3.x; bv[5]=t3.y; bv[6]=t3.z; bv[7]=t3.w;
        #pragma unroll
        for (int i = 0; i < 8; ++i)
            #pragma unroll
            for (int j = 0; j < 8; ++j)
                acc[i][j] = fmaf(av[i], bv[j], acc[i][j]);
    }

    if (mode == 1) {
        int b = bh >> 4;
        #pragma unroll
        for (int i = 0; i < 8; ++i) {
            int r = (i >> 2) * 64 + ty * 4 + (i & 3);
            #pragma unroll
            for (int jh = 0; jh < 2; ++jh) {
                int c = n0 + jh * 64 + tx * 4;
                float4 m4 = *(const float4*)(mask + (size_t)b * LPAD + c);
                float4 res;
                res.x = acc[i][jh * 4 + 0] - 1e9f * (1.f - m4.x);
                res.y = acc[i][jh * 4 + 1] - 1e9f * (1.f - m4.y);
                res.z = acc[i][jh * 4 + 2] - 1e9f * (1.f - m4.z);
                res.w = acc[i][jh * 4 + 3] - 1e9f * (1.f - m4.w);
                *(float4*)(out + ((size_t)bh * NLM + r) * ld_out + c) = res;
            }
        }
    } else {
        float m[8], s[8];
        #pragma unroll
        for (int i = 0; i < 8; ++i) {
            m[i] = acc[i][0];
            #pragma unroll
            for (int j = 1; j < 8; ++j) m[i] = fmaxf(m[i], acc[i][j]);
        }
        #pragma unroll
        for (int o = 8; o >= 1; o >>= 1)
            #pragma unroll
            for (int i = 0; i < 8; ++i) m[i] = fmaxf(m[i], __shfl_xor(m[i], o));
        #pragma unroll
        for (int i = 0; i < 8; ++i) {
            s[i] = 0.f;
            #pragma unroll
            for (int j = 0; j < 8; ++j) {
                acc[i][j] = expf(acc[i][j] - m[i]);
                s[i] += acc[i][j];
            }
        }
        #pragma unroll
        for (int o = 8; o >= 1; o >>= 1)
            #pragma unroll
            for (int i = 0; i < 8; ++i) s[i] += __shfl_xor(s[i], o);
        #pragma unroll
        for (int i = 0; i < 8; ++i) {
            int r = (i >> 2) * 64 + ty * 4 + (i & 3);
            float inv = 1.f / s[i];
            #pragma unroll
            for (int jh = 0; jh < 2; ++jh) {
                int c = jh * 64 + tx * 4;
                float4 res;
                res.x = acc[i][jh * 4 + 0] * inv;
                res.y = acc[i][jh * 4 + 1] * inv;
                res.z = acc[i][jh * 4 + 2] * inv;
                res.w = acc[i][jh * 4 + 3] * inv;
                *(float4*)(out + ((size_t)bh * NLM + r) * ld_out + c) = res;
            }
        }
    }
}

// ---------------------------------------------------------------------------
// denom + V0 = K2^T / denom. grid 32, 128 threads.
// ---------------------------------------------------------------------------
__global__ void k_v0denom(const float* __restrict__ K2b, float* __restrict__ V0b) {
    int bh = blockIdx.x, t = threadIdx.x;
    const float* K2 = K2b + (size_t)bh * NLM * NLM;
    float* V0 = V0b + (size_t)bh * NLM * NLM;
    float cs = 0.f, rs = 0.f;
    for (int r = 0; r < NLM; ++r) cs += fabsf(K2[r * NLM + t]);
    for (int c = 0; c < NLM; ++c) rs += fabsf(K2[t * NLM + c]);
    __shared__ float sc[128], sr[128];
    sc[t] = cs; sr[t] = rs;
    __syncthreads();
    for (int s = 64; s > 0; s >>= 1) {
        if (t < s) {
            sc[t] = fmaxf(sc[t], sc[t + s]);
            sr[t] = fmaxf(sr[t], sr[t + s]);
        }
        __syncthreads();
    }
    float invden = 1.f / (sc[0] * sr[0]);
    for (int idx = t; idx < NLM * NLM; idx += 128) {
        int i = idx >> 7, j = idx & 127;
        V0[idx] = K2[j * NLM + i] * invden;
    }
}

// ---------------------------------------------------------------------------
// Batched matmul: C = alpha*(A@B) + sI  (A 128x128, B 128xN). fp32 VALU.
// Optional second output C2 = alpha2*(A@B) + s2I.
// ---------------------------------------------------------------------------
__global__ __launch_bounds__(256) void k_bmm(const float* __restrict__ Ab,
                                             const float* __restrict__ Bb,
                                             float* __restrict__ Cb,
                                             float* __restrict__ C2b,
                                             int N, float alpha, float sI,
                                             float alpha2, float sI2) {
    __shared__ float At[128][68];
    __shared__ float Bs[128][68];
    int tid = threadIdx.x;
    int tx = tid & 15, ty = tid >> 4;
    int bh = blockIdx.z;
    int r0 = blockIdx.y * 64, c0 = blockIdx.x * 64;
    const float* A = Ab + (size_t)bh * NLM * NLM;
    const float* Bm = Bb + (size_t)bh * NLM * N;

    #pragma unroll
    for (int q = 0; q < 8; ++q) {
        int idx = tid + q * 256;
        int r = idx >> 5, k4 = idx & 31;
        float4 v = *(const float4*)(A + (size_t)(r0 + r) * NLM + k4 * 4);
        At[k4 * 4 + 0][r] = v.x; At[k4 * 4 + 1][r] = v.y;
        At[k4 * 4 + 2][r] = v.z; At[k4 * 4 + 3][r] = v.w;
        int bk = idx >> 4, c4 = idx & 15;
        float4 w = *(const float4*)(Bm + (size_t)bk * N + c0 + c4 * 4);
        *(float4*)&Bs[bk][c4 * 4] = w;
    }
    __syncthreads();

    float acc[4][4];
    #pragma unroll
    for (int i = 0; i < 4; ++i)
        #pragma unroll
        for (int j = 0; j < 4; ++j) acc[i][j] = 0.f;

    #pragma unroll 4
    for (int k = 0; k < 128; ++k) {
        float4 a = *(const float4*)&At[k][ty * 4];
        float4 b = *(const float4*)&Bs[k][tx * 4];
        float av[4] = {a.x, a.y, a.z, a.w};
        float bv[4] = {b.x, b.y, b.z, b.w};
        #pragma unroll
        for (int i = 0; i < 4; ++i)
            #pragma unroll
            for (int j = 0; j < 4; ++j)
                acc[i][j] = fmaf(av[i], bv[j], acc[i][j]);
    }

    float* C = Cb + (size_t)bh * NLM * N;
    float* C2 = C2b ? (C2b + (size_t)bh * NLM * N) : nullptr;
    #pragma unroll
    for (int i = 0; i < 4; ++i) {
        int gr = r0 + ty * 4 + i;
        int gc0 = c0 + tx * 4;
        float4 res, res2;
        float* rp = &res.x; float* rp2 = &res2.x;
        #pragma unroll
        for (int j = 0; j < 4; ++j) {
            float idadd = (gr == gc0 + j) ? 1.f : 0.f;
            rp[j] = alpha * acc[i][j] + sI * idadd;
            rp2[j] = alpha2 * acc[i][j] + sI2 * idadd;
        }
        *(float4*)(C + (size_t)gr * N + gc0) = res;
        if (C2) *(float4*)(C2 + (size_t)gr * N + gc0) = res2;
    }
}

// ---------------------------------------------------------------------------
// Row softmax over 4096-long rows of SC (in place). grid 4096, 256 threads.
// ---------------------------------------------------------------------------
__global__ __launch_bounds__(256) void k_softmax4096(float* __restrict__ SC) {
    float* p = SC + (size_t)blockIdx.x * LPAD;
    int tid = threadIdx.x;
    float4 v[4];
    #pragma unroll
    for (int q = 0; q < 4; ++q) v[q] = *(float4*)(p + tid * 16 + q * 4);

    float m = -1e30f;
    #pragma unroll
    for (int q = 0; q < 4; ++q) {
        m = fmaxf(m, fmaxf(fmaxf(v[q].x, v[q].y), fmaxf(v[q].z, v[q].w)));
    }
    __shared__ float red[4], red2[4];
    for (int o = 32; o >= 1; o >>= 1) m = fmaxf(m, __shfl_xor(m, o));
    int wid = tid >> 6;
    if ((tid & 63) == 0) red[wid] = m;
    __syncthreads();
    m = fmaxf(fmaxf(red[0], red[1]), fmaxf(red[2], red[3]));

    float s = 0.f;
    #pragma unroll
    for (int q = 0; q < 4; ++q) {
        v[q].x = expf(v[q].x - m); v[q].y = expf(v[q].y - m);
        v[q].z = expf(v[q].z - m); v[q].w = expf(v[q].w - m);
        s += v[q].x + v[q].y + v[q].z + v[q].w;
    }
    for (int o = 32; o >= 1; o >>= 1) s += __shfl_xor(s, o);
    if ((tid & 63) == 0) red2[wid] = s;
    __syncthreads();
    s = red2[0] + red2[1] + red2[2] + red2[3];
    float inv = 1.f / s;
    #pragma unroll
    for (int q = 0; q < 4; ++q) {
        v[q].x *= inv; v[q].y *= inv; v[q].z *= inv; v[q].w *= inv;
        *(float4*)(p + tid * 16 + q * 4) = v[q];
    }
}

// ---------------------------------------------------------------------------
// Partial kernel_3 @ V over a 256-wide n chunk. grid (16, 32), 256 threads.
// ---------------------------------------------------------------------------
__global__ __launch_bounds__(256) void k_k3v_partial(const float* __restrict__ SC,
                                                     const float* __restrict__ V,
                                                     float* __restrict__ P) {
    __shared__ float Pt[64][132];
    __shared__ float Vs[64][68];
    int tid = threadIdx.x;
    int tx = tid & 7, ty = tid >> 3;
    int sp = blockIdx.x, bh = blockIdx.y;
    int n0 = sp * 256;

    float acc[4][8];
    #pragma unroll
    for (int i = 0; i < 4; ++i)
        #pragma unroll
        for (int j = 0; j < 8; ++j) acc[i][j] = 0.f;

    for (int ns = 0; ns < 4; ++ns) {
        int nb = n0 + ns * 64;
        #pragma unroll
        for (int q = 0; q < 8; ++q) {
            int idx = tid + q * 256;
            int r = idx >> 4, n4 = idx & 15;
            float4 v = *(const float4*)(SC + ((size_t)bh * NLM + r) * LPAD + nb + n4 * 4);
            Pt[n4 * 4 + 0][r] = v.x; Pt[n4 * 4 + 1][r] = v.y;
            Pt[n4 * 4 + 2][r] = v.z; Pt[n4 * 4 + 3][r] = v.w;
        }
        #pragma unroll
        for (int q = 0; q < 4; ++q) {
            int idx = tid + q * 256;
            int vr = idx >> 4, d4 = idx & 15;
            float4 w = *(const float4*)(V + ((size_t)bh * LPAD + nb + vr) * DH + d4 * 4);
            *(float4*)&Vs[vr][d4 * 4] = w;
        }
        __syncthreads();
        #pragma unroll 4
        for (int nn = 0; nn < 64; ++nn) {
            float4 a4 = *(const float4*)&Pt[nn][ty * 4];
            float4 b0 = *(const float4*)&Vs[nn][tx * 8];
            float4 b1 = *(const float4*)&Vs[nn][tx * 8 + 4];
            float a[4] = {a4.x, a4.y, a4.z, a4.w};
            float b[8] = {b0.x, b0.y, b0.z, b0.w, b1.x, b1.y, b1.z, b1.w};
            #pragma unroll
            for (int i = 0; i < 4; ++i)
                #pragma unroll
                for (int j = 0; j < 8; ++j)
                    acc[i][j] = fmaf(a[i], b[j], acc[i][j]);
        }
        __syncthreads();
    }
    #pragma unroll
    for (int i = 0; i < 4; ++i) {
        int r = ty * 4 + i, d = tx * 8;
        *(float4*)(P + (((size_t)bh * 16 + sp) * NLM + r) * DH + d) =
            make_float4(acc[i][0], acc[i][1], acc[i][2], acc[i][3]);
        *(float4*)(P + (((size_t)bh * 16 + sp) * NLM + r) * DH + d + 4) =
            make_float4(acc[i][4], acc[i][5], acc[i][6], acc[i][7]);
    }
}

__global__ void k_k3v_combine(const float* __restrict__ P, float* __restrict__ O) {
    int idx = blockIdx.x * 256 + threadIdx.x;
    int bh = idx >> 13, rem = idx & 8191;
    float s = 0.f;
    for (int sp = 0; sp < 16; ++sp)
        s += P[((size_t)bh * 16 + sp) * 8192 + rem];
    O[idx] = s;
}

// ---------------------------------------------------------------------------
// kernel_1 fused via split-bf16 MFMA: ATTN = softmax(Q_tile @ KL^T) @ MM.
// grid (32 l-tiles, 32 bh), 256 threads (4 waves). Each wave owns 32 FULL
// rows (all 128 cols) in BOTH matmuls, so the row-softmax reduces entirely
// within the wave's 16-lane groups.
// ---------------------------------------------------------------------------
__global__ __launch_bounds__(256) void k_attn(const float* __restrict__ Q,
                                              const float* __restrict__ KLb,
                                              const float* __restrict__ MMb,
                                              u16* __restrict__ ATH,
                                              u16* __restrict__ ATL) {
    __shared__ u16 lds[49152];
    u16* Qh  = lds;               // 8192 (128x64)
    u16* Ql  = lds + 8192;
    u16* KLh = lds + 16384;
    u16* KLl = lds + 24576;
    u16* Ph  = lds;               // 16384 (128x128), overwrites Q/KL
    u16* Pl  = lds + 16384;
    u16* Mth = lds + 32768;       // 8192 (64x128)
    u16* Mtl = lds + 40960;

    int tid = threadIdx.x;
    int lane = tid & 63, wv = tid >> 6;
    int lr = lane & 15, lk = lane >> 4;
    int l0 = blockIdx.x * 128, bh = blockIdx.y;
    int b = bh >> 4, hh = bh & 15;
    int wrA = wv * 32;            // wave's 32 rows (both matmuls)

    // ---- stage Q, KL (split, IDX64) ----
    #pragma unroll
    for (int q = 0; q < 4; ++q) {
        int idx = tid + q * 256;
        int r = idx >> 3, c8 = (idx & 7) * 8;
        float4 v0 = *(const float4*)(Q + ((size_t)bh * LPAD + l0 + r) * DH + c8);
        float4 v1 = *(const float4*)(Q + ((size_t)bh * LPAD + l0 + r) * DH + c8 + 4);
        float xs[8] = {v0.x, v0.y, v0.z, v0.w, v1.x, v1.y, v1.z, v1.w};
        s16x8 h8, l8;
        #pragma unroll
        for (int e = 0; e < 8; ++e) {
            u16 hh2, ll2; split2(xs[e], hh2, ll2);
            h8[e] = (short)hh2; l8[e] = (short)ll2;
        }
        *(s16x8*)&Qh[IDX64(r, c8)] = h8;
        *(s16x8*)&Ql[IDX64(r, c8)] = l8;

        float4 w0 = *(const float4*)(KLb + ((size_t)bh * NLM + r) * DH + c8);
        float4 w1 = *(const float4*)(KLb + ((size_t)bh * NLM + r) * DH + c8 + 4);
        float ys[8] = {w0.x, w0.y, w0.z, w0.w, w1.x, w1.y, w1.z, w1.w};
        #pragma unroll
        for (int e = 0; e < 8; ++e) {
            u16 hh2, ll2; split2(ys[e], hh2, ll2);
            h8[e] = (short)hh2; l8[e] = (short)ll2;
        }
        *(s16x8*)&KLh[IDX64(r, c8)] = h8;
        *(s16x8*)&KLl[IDX64(r, c8)] = l8;
    }
    // ---- stage MM transposed (split, IDX128) ----
    #pragma unroll
    for (int q = 0; q < 8; ++q) {
        int idx = tid + q * 256;
        int n = idx >> 4, d4 = (idx & 15) * 4;
        float4 v = *(const float4*)(MMb + ((size_t)bh * NLM + n) * DH + d4);
        float xs[4] = {v.x, v.y, v.z, v.w};
        #pragma unroll
        for (int e = 0; e < 4; ++e) {
            u16 hh2, ll2; split2(xs[e], hh2, ll2);
            Mth[IDX128(d4 + e, n)] = hh2;
            Mtl[IDX128(d4 + e, n)] = ll2;
        }
    }
    __syncthreads();

    // ---- S = Q @ KL^T : wave owns 32 rows x 128 cols (t4[2][8]) ----
    f32x4 t4[2][8] = {};
    #pragma unroll
    for (int t = 0; t < 3; ++t) {
        const u16* Xs = (t == 2) ? Ql : Qh;
        const u16* Ys = (t == 1) ? KLl : KLh;
        #pragma unroll
        for (int kc = 0; kc < 2; ++kc) {
            s16x8 a[2], bfr[8];
            #pragma unroll
            for (int i = 0; i < 2; ++i)
                a[i] = *(const s16x8*)&Xs[IDX64(wrA + i * 16 + lr, kc * 32 + lk * 8)];
            #pragma unroll
            for (int j = 0; j < 8; ++j)
                bfr[j] = *(const s16x8*)&Ys[IDX64(j * 16 + lr, kc * 32 + lk * 8)];
            #pragma unroll
            for (int i = 0; i < 2; ++i)
                #pragma unroll
                for (int j = 0; j < 8; ++j)
                    t4[i][j] = __builtin_amdgcn_mfma_f32_16x16x32_bf16(a[i], bfr[j], t4[i][j], 0, 0, 0);
        }
    }

    // ---- row softmax: row = wrA+i*16+lk*4+q; its 128 cols = {j*16+lr} all
    //      in this wave (8 j-frags x 16 lr lanes) ----
    #pragma unroll
    for (int i = 0; i < 2; ++i)
        #pragma unroll
        for (int q = 0; q < 4; ++q) {
            float m = t4[i][0][q];
            #pragma unroll
            for (int j = 1; j < 8; ++j) m = fmaxf(m, t4[i][j][q]);
            m = fmaxf(m, __shfl_xor(m, 1));
            m = fmaxf(m, __shfl_xor(m, 2));
            m = fmaxf(m, __shfl_xor(m, 4));
            m = fmaxf(m, __shfl_xor(m, 8));
            float s = 0.f;
            #pragma unroll
            for (int j = 0; j < 8; ++j) {
                t4[i][j][q] = expf(t4[i][j][q] - m);
                s += t4[i][j][q];
            }
            s += __shfl_xor(s, 1);
            s += __shfl_xor(s, 2);
            s += __shfl_xor(s, 4);
            s += __shfl_xor(s, 8);
            float inv = 1.f / s;
            #pragma unroll
            for (int j = 0; j < 8; ++j) t4[i][j][q] *= inv;
        }

    __syncthreads();   // Q/KL reads done; safe to overwrite with P
    #pragma unroll
    for (int i = 0; i < 2; ++i)
        #pragma unroll
        for (int j = 0; j < 8; ++j) {
            int col = j * 16 + lr;
            #pragma unroll
            for (int q = 0; q < 4; ++q) {
                int row = wrA + i * 16 + lk * 4 + q;
                u16 hh2, ll2; split2(t4[i][j][q], hh2, ll2);
                Ph[IDX128(row, col)] = hh2;
                Pl[IDX128(row, col)] = ll2;
            }
        }
    __syncthreads();

    // ---- O = P @ MM (K=128, 3 split terms); wave computes 32 rows x 64 cols ----
    f32x4 t5[2][4] = {};
    #pragma unroll
    for (int t = 0; t < 3; ++t) {
        const u16* Xs = (t == 2) ? Pl : Ph;
        const u16* Ys = (t == 1) ? Mtl : Mth;
        #pragma unroll
        for (int kc = 0; kc < 4; ++kc) {
            s16x8 a[2], bfr[4];
            #pragma unroll
            for (int i = 0; i < 2; ++i)
                a[i] = *(const s16x8*)&Xs[IDX128(wrA + i * 16 + lr, kc * 32 + lk * 8)];
            #pragma unroll
            for (int j = 0; j < 4; ++j)
                bfr[j] = *(const s16x8*)&Ys[IDX128(j * 16 + lr, kc * 32 + lk * 8)];
            #pragma unroll
            for (int i = 0; i < 2; ++i)
                #pragma unroll
                for (int j = 0; j < 4; ++j)
                    t5[i][j] = __builtin_amdgcn_mfma_f32_16x16x32_bf16(a[i], bfr[j], t5[i][j], 0, 0, 0);
        }
    }

    // ---- epilogue: split O -> ATH/ATL ----
    #pragma unroll
    for (int i = 0; i < 2; ++i)
        #pragma unroll
        for (int j = 0; j < 4; ++j) {
            int d = j * 16 + lr;
            #pragma unroll
            for (int q = 0; q < 4; ++q) {
                int l = l0 + wrA + i * 16 + lk * 4 + q;
                size_t base = ((size_t)b * LPAD + l) * HIDDEN + hh * DH + d;
                u16 hh2, ll2; split2(t5[i][j][q], hh2, ll2);
                ATH[base] = hh2;
                ATL[base] = ll2;
            }
        }
}

// ---------------------------------------------------------------------------
extern "C" void kernel_launch(void* const* d_in, const int* in_sizes, int n_in,
                              void* d_out, int out_size, void* d_ws, size_t ws_size,
                              hipStream_t stream) {
    (void)in_sizes; (void)n_in; (void)out_size; (void)ws_size;
    const float* X    = (const float*)d_in[0];
    const float* mask = (const float*)d_in[1];
    const float* Wq   = (const float*)d_in[2];
    const float* bq   = (const float*)d_in[3];
    const float* Wk   = (const float*)d_in[4];
    const float* bk   = (const float*)d_in[5];
    const float* Wv   = (const float*)d_in[6];
    const float* bv   = (const float*)d_in[7];
    const float* Wo   = (const float*)d_in[8];
    const float* bo   = (const float*)d_in[9];
    float* out = (float*)d_out;
    float* w = (float*)d_ws;

    size_t o = 0;
    u16* WQH = (u16*)(w + o); o += (size_t)HIDDEN * HIDDEN / 2;
    u16* WQL = (u16*)(w + o); o += (size_t)HIDDEN * HIDDEN / 2;
    u16* WKH = (u16*)(w + o); o += (size_t)HIDDEN * HIDDEN / 2;
    u16* WKL = (u16*)(w + o); o += (size_t)HIDDEN * HIDDEN / 2;
    u16* WVH = (u16*)(w + o); o += (size_t)HIDDEN * HIDDEN / 2;
    u16* WVL = (u16*)(w + o); o += (size_t)HIDDEN * HIDDEN / 2;
    u16* WOH = (u16*)(w + o); o += (size_t)HIDDEN * HIDDEN / 2;
    u16* WOL = (u16*)(w + o); o += (size_t)HIDDEN * HIDDEN / 2;
    float* Q   = w + o; o += (size_t)BHT * LPAD * DH;
    float* K   = w + o; o += (size_t)BHT * LPAD * DH;
    float* V   = w + o; o += (size_t)BHT * LPAD * DH;
    float* QL  = w + o; o += (size_t)BHT * NLM * DH;
    float* KL  = w + o; o += (size_t)BHT * NLM * DH;
    float* K2  = w + o; o += (size_t)BHT * NLM * NLM;
    float* VA  = w + o; o += (size_t)BHT * NLM * NLM;
    float* VB  = w + o; o += (size_t)BHT * NLM * NLM;
    float* KV  = w + o; o += (size_t)BHT * NLM * NLM;
    float* P1  = w + o; o += (size_t)BHT * NLM * NLM;
    float* T3  = w + o; o += (size_t)BHT * NLM * NLM;
    float* PK  = w + o; o += (size_t)BHT * 16 * NLM * DH;
    float* K3V = w + o; o += (size_t)BHT * NLM * DH;
    float* MM  = w + o; o += (size_t)BHT * NLM * DH;
    float* SC  = w + o; o += (size_t)BHT * NLM * LPAD;

    // Time-shared aliases of the SC region (disjoint live windows):
    u16* XH  = (u16*)SC;
    u16* XL  = XH + (size_t)2 * LPAD * HIDDEN;
    u16* ATH = (u16*)SC;
    u16* ATL = ATH + (size_t)2 * LPAD * HIDDEN;

    k_split_x<<<8192, 256, 0, stream>>>(X, XH, XL);
    k_split_w<<<1024, 256, 0, stream>>>(Wq, WQH, WQL);
    k_split_w<<<1024, 256, 0, stream>>>(Wk, WKH, WKL);
    k_split_w<<<1024, 256, 0, stream>>>(Wv, WVH, WVL);
    k_split_w<<<1024, 256, 0, stream>>>(Wo, WOH, WOL);

    dim3 gg(64, 8);
    k_gemm_bf16<<<gg, 256, 0, stream>>>(XH, XL, WQH, WQL, bq, mask, Q, 0);
    k_gemm_bf16<<<gg, 256, 0, stream>>>(XH, XL, WKH, WKL, bk, mask, K, 0);
    k_gemm_bf16<<<gg, 256, 0, stream>>>(XH, XL, WVH, WVL, bv, nullptr, V, 0);

    k_landmarks<<<dim3(NLM, BHT), 64, 0, stream>>>(Q, K, QL, KL);

    k_qlk<<<dim3(1, BHT), 256, 0, stream>>>(QL, KL, nullptr, K2, NLM, 0);
    k_qlk<<<dim3(32, BHT), 256, 0, stream>>>(QL, K, mask, SC, LPAD, 1);

    k_v0denom<<<BHT, 128, 0, stream>>>(K2, VA);
    float* cur = VA;
    float* nxt = VB;
    for (int it = 0; it < 6; ++it) {
        k_bmm<<<dim3(2, 2, BHT), 256, 0, stream>>>(K2, cur, KV, P1, NLM, 1.f, 0.f, -1.f, 7.f);
        k_bmm<<<dim3(2, 2, BHT), 256, 0, stream>>>(KV, P1, T3, nullptr, NLM, -1.f, 15.f, 0.f, 0.f);
        k_bmm<<<dim3(2, 2, BHT), 256, 0, stream>>>(KV, T3, P1, nullptr, NLM, -1.f, 13.f, 0.f, 0.f);
        k_bmm<<<dim3(2, 2, BHT), 256, 0, stream>>>(cur, P1, nxt, nullptr, NLM, 0.25f, 0.f, 0.f, 0.f);
        float* t = cur; cur = nxt; nxt = t;
    }

    k_softmax4096<<<BHT * NLM, 256, 0, stream>>>(SC);
    k_k3v_partial<<<dim3(16, BHT), 256, 0, stream>>>(SC, V, PK);
    k_k3v_combine<<<(BHT * NLM * DH) / 256, 256, 0, stream>>>(PK, K3V);
    k_bmm<<<dim3(1, 2, BHT), 256, 0, stream>>>(cur, K3V, MM, nullptr, DH, 1.f, 0.f, 0.f, 0.f);

    k_attn<<<dim3(32, BHT), 256, 0, stream>>>(Q, KL, MM, ATH, ATL);
    k_gemm_bf16<<<gg, 256, 0, stream>>>(ATH, ATL, WOH, WOL, bo, nullptr, out, 1);
}

// Round 10
// 692.152 us; speedup vs baseline: 1.2795x; 1.0001x over previous
//
#include <hip/hip_runtime.h>
#include <hip/hip_bf16.h>
#include <math.h>

#define S_ORIG 4095
#define LPAD   4096
#define NHEADS 16
#define DH     64
#define NLM    128
#define BHT    32        // B * NHEADS
#define HIDDEN 1024
#define QKSCALE 0.35355339059327373f   // 1 / 64^0.25

typedef unsigned short u16;
typedef short s16x8 __attribute__((ext_vector_type(8)));
typedef float f32x4 __attribute__((ext_vector_type(4)));

// XOR-swizzled LDS indices (spread row-stride power-of-2 across banks)
#define IDX64(r, c)  ((r) * 64 + ((c) ^ (((r) & 7) << 3)))
#define IDX128(r, c) ((r) * 128 + ((c) ^ (((r) & 7) << 3)))

// ---------------------------------------------------------------------------
// fp32 -> (hi, lo) bf16 split
// ---------------------------------------------------------------------------
__device__ inline void split2(float x, u16& h, u16& l) {
    __hip_bfloat16 bh = __float2bfloat16(x);
    float fh = __bfloat162float(bh);
    __hip_bfloat16 bl = __float2bfloat16(x - fh);
    h = *(u16*)&bh;
    l = *(u16*)&bl;
}

// X (B,4095,1024) fp32 -> XH, XL (8192,1024) bf16-bits, pad row (l==4095) zero.
__global__ __launch_bounds__(256) void k_split_x(const float* __restrict__ X,
                                                 u16* __restrict__ XH,
                                                 u16* __restrict__ XL) {
    int idx = blockIdx.x * 256 + threadIdx.x;      // one thread = 4 elems
    int gr = idx >> 8;                             // row 0..8191
    int c4 = (idx & 255) * 4;
    int b = gr >> 12, l = gr & (LPAD - 1);
    float4 v = make_float4(0.f, 0.f, 0.f, 0.f);
    if (l < S_ORIG) v = *(const float4*)(X + ((size_t)b * S_ORIG + l) * HIDDEN + c4);
    ushort4 h4, l4;
    split2(v.x, h4.x, l4.x); split2(v.y, h4.y, l4.y);
    split2(v.z, h4.z, l4.z); split2(v.w, h4.w, l4.w);
    size_t o = (size_t)gr * HIDDEN + c4;
    *(ushort4*)(XH + o) = h4;
    *(ushort4*)(XL + o) = l4;
}

// W (1024,1024) fp32 -> WH, WL bf16-bits (native [n][k] layout).
__global__ __launch_bounds__(256) void k_split_w(const float* __restrict__ W,
                                                 u16* __restrict__ WH,
                                                 u16* __restrict__ WL) {
    int idx = blockIdx.x * 256 + threadIdx.x;
    size_t o = (size_t)idx * 4;
    float4 v = *(const float4*)(W + o);
    ushort4 h4, l4;
    split2(v.x, h4.x, l4.x); split2(v.y, h4.y, l4.y);
    split2(v.z, h4.z, l4.z); split2(v.w, h4.w, l4.w);
    *(ushort4*)(WH + o) = h4;
    *(ushort4*)(WL + o) = l4;
}

// ---------------------------------------------------------------------------
// Split-bf16 MFMA GEMM:  C = A @ B^T + bias, A 8192x1024 (hi/lo), B 1024x1024
// [n][k] (hi/lo). SINGLE pass over K=1024: per 32-K step all four tiles
// (AH, AL, BH, BL) are resident in LDS and 48 MFMAs cover the 3 split terms
// AH*BH + AH*BL + AL*BH.  Bank-conflict fix per rule #21: LDS dest stays
// linear (global_load_lds lane-stride), the global SOURCE column is
// inverse-swizzled (chunk ^ (row>>1)&3), and fragment reads apply the same
// XOR -> 8 distinct 16B slots per 8 lanes (2-way aliasing, free).
// ---------------------------------------------------------------------------
__global__ __launch_bounds__(256) void k_gemm_bf16(
    const u16* __restrict__ AH, const u16* __restrict__ AL,
    const u16* __restrict__ BH, const u16* __restrict__ BL,
    const float* __restrict__ bias, const float* __restrict__ mask,
    float* __restrict__ out, int mode)
{
    __shared__ u16 Ah_lds[128 * 32];
    __shared__ u16 Al_lds[128 * 32];
    __shared__ u16 Bh_lds[128 * 32];
    __shared__ u16 Bl_lds[128 * 32];
    int tid = threadIdx.x;
    int row0 = blockIdx.x * 128, col0 = blockIdx.y * 128;
    int lane = tid & 63, wv = tid >> 6;
    int wr = (wv >> 1) * 64, wc = (wv & 1) * 64;
    int lr = lane & 15, lk = lane >> 4;
    int sr = tid >> 2, sc = tid & 3;               // staging row (0..63), chunk (0..3)

    f32x4 acc[4][4] = {};

    for (int kt = 0; kt < 1024; kt += 32) {
        #pragma unroll
        for (int h = 0; h < 2; ++h) {
            int r = sr + h * 64;
            int csrc = (sc ^ ((r >> 1) & 3)) * 8;  // inverse-swizzled source col
            size_t ga = (size_t)(row0 + r) * HIDDEN + kt + csrc;
            size_t gb = (size_t)(col0 + r) * HIDDEN + kt + csrc;
            int ldst = r * 32 + sc * 8;            // linear dest (lane*16B)
            __builtin_amdgcn_global_load_lds(
                (const __attribute__((address_space(1))) void*)(AH + ga),
                (__attribute__((address_space(3))) void*)(&Ah_lds[ldst]), 16, 0, 0);
            __builtin_amdgcn_global_load_lds(
                (const __attribute__((address_space(1))) void*)(AL + ga),
                (__attribute__((address_space(3))) void*)(&Al_lds[ldst]), 16, 0, 0);
            __builtin_amdgcn_global_load_lds(
                (const __attribute__((address_space(1))) void*)(BH + gb),
                (__attribute__((address_space(3))) void*)(&Bh_lds[ldst]), 16, 0, 0);
            __builtin_amdgcn_global_load_lds(
                (const __attribute__((address_space(1))) void*)(BL + gb),
                (__attribute__((address_space(3))) void*)(&Bl_lds[ldst]), 16, 0, 0);
        }
        __syncthreads();
        s16x8 ah[4], al[4], bh[4], bl[4];
        #pragma unroll
        for (int i = 0; i < 4; ++i) {
            int ra = wr + i * 16 + lr;
            int rb = wc + i * 16 + lr;
            int ca = (lk ^ ((ra >> 1) & 3)) * 8;   // swizzled read col
            int cb = (lk ^ ((rb >> 1) & 3)) * 8;
            ah[i] = *(const s16x8*)&Ah_lds[ra * 32 + ca];
            al[i] = *(const s16x8*)&Al_lds[ra * 32 + ca];
            bh[i] = *(const s16x8*)&Bh_lds[rb * 32 + cb];
            bl[i] = *(const s16x8*)&Bl_lds[rb * 32 + cb];
        }
        #pragma unroll
        for (int i = 0; i < 4; ++i)
            #pragma unroll
            for (int j = 0; j < 4; ++j)
                acc[i][j] = __builtin_amdgcn_mfma_f32_16x16x32_bf16(ah[i], bh[j], acc[i][j], 0, 0, 0);
        #pragma unroll
        for (int i = 0; i < 4; ++i)
            #pragma unroll
            for (int j = 0; j < 4; ++j)
                acc[i][j] = __builtin_amdgcn_mfma_f32_16x16x32_bf16(ah[i], bl[j], acc[i][j], 0, 0, 0);
        #pragma unroll
        for (int i = 0; i < 4; ++i)
            #pragma unroll
            for (int j = 0; j < 4; ++j)
                acc[i][j] = __builtin_amdgcn_mfma_f32_16x16x32_bf16(al[i], bh[j], acc[i][j], 0, 0, 0);
        __syncthreads();
    }

    #pragma unroll
    for (int i = 0; i < 4; ++i) {
        #pragma unroll
        for (int j = 0; j < 4; ++j) {
            int cc = col0 + wc + j * 16 + lr;
            float bval = bias[cc];
            #pragma unroll
            for (int q = 0; q < 4; ++q) {
                int rr = row0 + wr + i * 16 + lk * 4 + q;
                int bb = rr >> 12, l = rr & (LPAD - 1);
                float val = acc[i][j][q] + bval;
                if (mode == 0) {
                    if (mask) val *= mask[(size_t)bb * LPAD + l] * QKSCALE;
                    out[(((size_t)bb * NHEADS + (cc >> 6)) * LPAD + l) * DH + (cc & 63)] = val;
                } else {
                    if (l < S_ORIG)
                        out[((size_t)bb * S_ORIG + l) * HIDDEN + cc] = val;
                }
            }
        }
    }
}

// ---------------------------------------------------------------------------
// Landmarks: mean over 32 consecutive rows of Q and K. grid (128, 32), 64 thr.
// ---------------------------------------------------------------------------
__global__ void k_landmarks(const float* __restrict__ Q, const float* __restrict__ K,
                            float* __restrict__ QL, float* __restrict__ KL) {
    int n = blockIdx.x, bh = blockIdx.y, d = threadIdx.x;
    size_t base = ((size_t)bh * LPAD + n * 32) * DH + d;
    float sq = 0.f, sk = 0.f;
    #pragma unroll
    for (int s = 0; s < 32; ++s) {
        sq += Q[base + (size_t)s * DH];
        sk += K[base + (size_t)s * DH];
    }
    QL[((size_t)bh * NLM + n) * DH + d] = sq * (1.f / 32.f);
    KL[((size_t)bh * NLM + n) * DH + d] = sk * (1.f / 32.f);
}

// ---------------------------------------------------------------------------
// S = QL @ B^T  (128 x 128, inner 64).
// mode 0: B = KL (128 rows), row-softmax, out K2 (ld 128).
// mode 1: B = K tile (128 rows at n0), out raw scores - 1e9*(1-mask) (ld 4096).
// ---------------------------------------------------------------------------
__global__ __launch_bounds__(256) void k_qlk(const float* __restrict__ QLb,
                                             const float* __restrict__ Bsrc,
                                             const float* __restrict__ mask,
                                             float* __restrict__ out,
                                             int ld_out, int mode) {
    __shared__ float Qt[64][132];
    __shared__ float Bt[64][132];
    int tid = threadIdx.x;
    int tx = tid & 15, ty = tid >> 4;
    int bh = blockIdx.y;
    int n0 = blockIdx.x * 128;
    const float* QLp = QLb + (size_t)bh * NLM * DH;
    const float* Bp = Bsrc + ((mode == 0) ? (size_t)bh * NLM * DH
                                          : (size_t)bh * LPAD * DH + (size_t)n0 * DH);

    #pragma unroll
    for (int q = 0; q < 8; ++q) {
        int idx = tid + q * 256;
        int r = idx >> 4, d4 = idx & 15;
        float4 v = *(const float4*)(QLp + (size_t)r * DH + d4 * 4);
        Qt[d4 * 4 + 0][r] = v.x; Qt[d4 * 4 + 1][r] = v.y;
        Qt[d4 * 4 + 2][r] = v.z; Qt[d4 * 4 + 3][r] = v.w;
        float4 w = *(const float4*)(Bp + (size_t)r * DH + d4 * 4);
        Bt[d4 * 4 + 0][r] = w.x; Bt[d4 * 4 + 1][r] = w.y;
        Bt[d4 * 4 + 2][r] = w.z; Bt[d4 * 4 + 3][r] = w.w;
    }
    __syncthreads();

    float acc[8][8];
    #pragma unroll
    for (int i = 0; i < 8; ++i)
        #pragma unroll
        for (int j = 0; j < 8; ++j) acc[i][j] = 0.f;

    #pragma unroll
    for (int k = 0; k < 64; ++k) {
        float av[8], bv[8];
        float4 t0 = *(const float4*)&Qt[k][ty * 4];
        float4 t1 = *(const float4*)&Qt[k][64 + ty * 4];
        float4 t2 = *(const float4*)&Bt[k][tx * 4];
        float4 t3 = *(const float4*)&Bt[k][64 + tx * 4];
        av[0]=t0.x; av[1]=t0.y; av[2]=t0.z; av[3]=t0.w;
        av[4]=t1.x; av[5]=t1.y; av[6]=t1.z; av[7]=t1.w;
        bv[0]=t2.x; bv[1]=t2.y; bv[2]=t2.z; bv[3]=t2.w;
        bv[4]=t3.x; bv[5]=t3.y; bv[6]=t3.z; bv[7]=t3.w;
        #pragma unroll
        for (int i = 0; i < 8; ++i)
            #pragma unroll
            for (int j = 0; j < 8; ++j)
                acc[i][j] = fmaf(av[i], bv[j], acc[i][j]);
    }

    if (mode == 1) {
        int b = bh >> 4;
        #pragma unroll
        for (int i = 0; i < 8; ++i) {
            int r = (i >> 2) * 64 + ty * 4 + (i & 3);
            #pragma unroll
            for (int jh = 0; jh < 2; ++jh) {
                int c = n0 + jh * 64 + tx * 4;
                float4 m4 = *(const float4*)(mask + (size_t)b * LPAD + c);
                float4 res;
                res.x = acc[i][jh * 4 + 0] - 1e9f * (1.f - m4.x);
                res.y = acc[i][jh * 4 + 1] - 1e9f * (1.f - m4.y);
                res.z = acc[i][jh * 4 + 2] - 1e9f * (1.f - m4.z);
                res.w = acc[i][jh * 4 + 3] - 1e9f * (1.f - m4.w);
                *(float4*)(out + ((size_t)bh * NLM + r) * ld_out + c) = res;
            }
        }
    } else {
        float m[8], s[8];
        #pragma unroll
        for (int i = 0; i < 8; ++i) {
            m[i] = acc[i][0];
            #pragma unroll
            for (int j = 1; j < 8; ++j) m[i] = fmaxf(m[i], acc[i][j]);
        }
        #pragma unroll
        for (int o = 8; o >= 1; o >>= 1)
            #pragma unroll
            for (int i = 0; i < 8; ++i) m[i] = fmaxf(m[i], __shfl_xor(m[i], o));
        #pragma unroll
        for (int i = 0; i < 8; ++i) {
            s[i] = 0.f;
            #pragma unroll
            for (int j = 0; j < 8; ++j) {
                acc[i][j] = expf(acc[i][j] - m[i]);
                s[i] += acc[i][j];
            }
        }
        #pragma unroll
        for (int o = 8; o >= 1; o >>= 1)
            #pragma unroll
            for (int i = 0; i < 8; ++i) s[i] += __shfl_xor(s[i], o);
        #pragma unroll
        for (int i = 0; i < 8; ++i) {
            int r = (i >> 2) * 64 + ty * 4 + (i & 3);
            float inv = 1.f / s[i];
            #pragma unroll
            for (int jh = 0; jh < 2; ++jh) {
                int c = jh * 64 + tx * 4;
                float4 res;
                res.x = acc[i][jh * 4 + 0] * inv;
                res.y = acc[i][jh * 4 + 1] * inv;
                res.z = acc[i][jh * 4 + 2] * inv;
                res.w = acc[i][jh * 4 + 3] * inv;
                *(float4*)(out + ((size_t)bh * NLM + r) * ld_out + c) = res;
            }
        }
    }
}

// ---------------------------------------------------------------------------
// denom + V0 = K2^T / denom. grid 32, 128 threads.
// ---------------------------------------------------------------------------
__global__ void k_v0denom(const float* __restrict__ K2b, float* __restrict__ V0b) {
    int bh = blockIdx.x, t = threadIdx.x;
    const float* K2 = K2b + (size_t)bh * NLM * NLM;
    float* V0 = V0b + (size_t)bh * NLM * NLM;
    float cs = 0.f, rs = 0.f;
    for (int r = 0; r < NLM; ++r) cs += fabsf(K2[r * NLM + t]);
    for (int c = 0; c < NLM; ++c) rs += fabsf(K2[t * NLM + c]);
    __shared__ float sc[128], sr[128];
    sc[t] = cs; sr[t] = rs;
    __syncthreads();
    for (int s = 64; s > 0; s >>= 1) {
        if (t < s) {
            sc[t] = fmaxf(sc[t], sc[t + s]);
            sr[t] = fmaxf(sr[t], sr[t + s]);
        }
        __syncthreads();
    }
    float invden = 1.f / (sc[0] * sr[0]);
    for (int idx = t; idx < NLM * NLM; idx += 128) {
        int i = idx >> 7, j = idx & 127;
        V0[idx] = K2[j * NLM + i] * invden;
    }
}

// ---------------------------------------------------------------------------
// Batched matmul: C = alpha*(A@B) + sI  (A 128x128, B 128xN). fp32 VALU.
// Optional second output C2 = alpha2*(A@B) + s2I.
// ---------------------------------------------------------------------------
__global__ __launch_bounds__(256) void k_bmm(const float* __restrict__ Ab,
                                             const float* __restrict__ Bb,
                                             float* __restrict__ Cb,
                                             float* __restrict__ C2b,
                                             int N, float alpha, float sI,
                                             float alpha2, float sI2) {
    __shared__ float At[128][68];
    __shared__ float Bs[128][68];
    int tid = threadIdx.x;
    int tx = tid & 15, ty = tid >> 4;
    int bh = blockIdx.z;
    int r0 = blockIdx.y * 64, c0 = blockIdx.x * 64;
    const float* A = Ab + (size_t)bh * NLM * NLM;
    const float* Bm = Bb + (size_t)bh * NLM * N;

    #pragma unroll
    for (int q = 0; q < 8; ++q) {
        int idx = tid + q * 256;
        int r = idx >> 5, k4 = idx & 31;
        float4 v = *(const float4*)(A + (size_t)(r0 + r) * NLM + k4 * 4);
        At[k4 * 4 + 0][r] = v.x; At[k4 * 4 + 1][r] = v.y;
        At[k4 * 4 + 2][r] = v.z; At[k4 * 4 + 3][r] = v.w;
        int bk = idx >> 4, c4 = idx & 15;
        float4 w = *(const float4*)(Bm + (size_t)bk * N + c0 + c4 * 4);
        *(float4*)&Bs[bk][c4 * 4] = w;
    }
    __syncthreads();

    float acc[4][4];
    #pragma unroll
    for (int i = 0; i < 4; ++i)
        #pragma unroll
        for (int j = 0; j < 4; ++j) acc[i][j] = 0.f;

    #pragma unroll 4
    for (int k = 0; k < 128; ++k) {
        float4 a = *(const float4*)&At[k][ty * 4];
        float4 b = *(const float4*)&Bs[k][tx * 4];
        float av[4] = {a.x, a.y, a.z, a.w};
        float bv[4] = {b.x, b.y, b.z, b.w};
        #pragma unroll
        for (int i = 0; i < 4; ++i)
            #pragma unroll
            for (int j = 0; j < 4; ++j)
                acc[i][j] = fmaf(av[i], bv[j], acc[i][j]);
    }

    float* C = Cb + (size_t)bh * NLM * N;
    float* C2 = C2b ? (C2b + (size_t)bh * NLM * N) : nullptr;
    #pragma unroll
    for (int i = 0; i < 4; ++i) {
        int gr = r0 + ty * 4 + i;
        int gc0 = c0 + tx * 4;
        float4 res, res2;
        float* rp = &res.x; float* rp2 = &res2.x;
        #pragma unroll
        for (int j = 0; j < 4; ++j) {
            float idadd = (gr == gc0 + j) ? 1.f : 0.f;
            rp[j] = alpha * acc[i][j] + sI * idadd;
            rp2[j] = alpha2 * acc[i][j] + sI2 * idadd;
        }
        *(float4*)(C + (size_t)gr * N + gc0) = res;
        if (C2) *(float4*)(C2 + (size_t)gr * N + gc0) = res2;
    }
}

// ---------------------------------------------------------------------------
// Row softmax over 4096-long rows of SC (in place). grid 4096, 256 threads.
// ---------------------------------------------------------------------------
__global__ __launch_bounds__(256) void k_softmax4096(float* __restrict__ SC) {
    float* p = SC + (size_t)blockIdx.x * LPAD;
    int tid = threadIdx.x;
    float4 v[4];
    #pragma unroll
    for (int q = 0; q < 4; ++q) v[q] = *(float4*)(p + tid * 16 + q * 4);

    float m = -1e30f;
    #pragma unroll
    for (int q = 0; q < 4; ++q) {
        m = fmaxf(m, fmaxf(fmaxf(v[q].x, v[q].y), fmaxf(v[q].z, v[q].w)));
    }
    __shared__ float red[4], red2[4];
    for (int o = 32; o >= 1; o >>= 1) m = fmaxf(m, __shfl_xor(m, o));
    int wid = tid >> 6;
    if ((tid & 63) == 0) red[wid] = m;
    __syncthreads();
    m = fmaxf(fmaxf(red[0], red[1]), fmaxf(red[2], red[3]));

    float s = 0.f;
    #pragma unroll
    for (int q = 0; q < 4; ++q) {
        v[q].x = expf(v[q].x - m); v[q].y = expf(v[q].y - m);
        v[q].z = expf(v[q].z - m); v[q].w = expf(v[q].w - m);
        s += v[q].x + v[q].y + v[q].z + v[q].w;
    }
    for (int o = 32; o >= 1; o >>= 1) s += __shfl_xor(s, o);
    if ((tid & 63) == 0) red2[wid] = s;
    __syncthreads();
    s = red2[0] + red2[1] + red2[2] + red2[3];
    float inv = 1.f / s;
    #pragma unroll
    for (int q = 0; q < 4; ++q) {
        v[q].x *= inv; v[q].y *= inv; v[q].z *= inv; v[q].w *= inv;
        *(float4*)(p + tid * 16 + q * 4) = v[q];
    }
}

// ---------------------------------------------------------------------------
// Partial kernel_3 @ V over a 256-wide n chunk. grid (16, 32), 256 threads.
// ---------------------------------------------------------------------------
__global__ __launch_bounds__(256) void k_k3v_partial(const float* __restrict__ SC,
                                                     const float* __restrict__ V,
                                                     float* __restrict__ P) {
    __shared__ float Pt[64][132];
    __shared__ float Vs[64][68];
    int tid = threadIdx.x;
    int tx = tid & 7, ty = tid >> 3;
    int sp = blockIdx.x, bh = blockIdx.y;
    int n0 = sp * 256;

    float acc[4][8];
    #pragma unroll
    for (int i = 0; i < 4; ++i)
        #pragma unroll
        for (int j = 0; j < 8; ++j) acc[i][j] = 0.f;

    for (int ns = 0; ns < 4; ++ns) {
        int nb = n0 + ns * 64;
        #pragma unroll
        for (int q = 0; q < 8; ++q) {
            int idx = tid + q * 256;
            int r = idx >> 4, n4 = idx & 15;
            float4 v = *(const float4*)(SC + ((size_t)bh * NLM + r) * LPAD + nb + n4 * 4);
            Pt[n4 * 4 + 0][r] = v.x; Pt[n4 * 4 + 1][r] = v.y;
            Pt[n4 * 4 + 2][r] = v.z; Pt[n4 * 4 + 3][r] = v.w;
        }
        #pragma unroll
        for (int q = 0; q < 4; ++q) {
            int idx = tid + q * 256;
            int vr = idx >> 4, d4 = idx & 15;
            float4 w = *(const float4*)(V + ((size_t)bh * LPAD + nb + vr) * DH + d4 * 4);
            *(float4*)&Vs[vr][d4 * 4] = w;
        }
        __syncthreads();
        #pragma unroll 4
        for (int nn = 0; nn < 64; ++nn) {
            float4 a4 = *(const float4*)&Pt[nn][ty * 4];
            float4 b0 = *(const float4*)&Vs[nn][tx * 8];
            float4 b1 = *(const float4*)&Vs[nn][tx * 8 + 4];
            float a[4] = {a4.x, a4.y, a4.z, a4.w};
            float b[8] = {b0.x, b0.y, b0.z, b0.w, b1.x, b1.y, b1.z, b1.w};
            #pragma unroll
            for (int i = 0; i < 4; ++i)
                #pragma unroll
                for (int j = 0; j < 8; ++j)
                    acc[i][j] = fmaf(a[i], b[j], acc[i][j]);
        }
        __syncthreads();
    }
    #pragma unroll
    for (int i = 0; i < 4; ++i) {
        int r = ty * 4 + i, d = tx * 8;
        *(float4*)(P + (((size_t)bh * 16 + sp) * NLM + r) * DH + d) =
            make_float4(acc[i][0], acc[i][1], acc[i][2], acc[i][3]);
        *(float4*)(P + (((size_t)bh * 16 + sp) * NLM + r) * DH + d + 4) =
            make_float4(acc[i][4], acc[i][5], acc[i][6], acc[i][7]);
    }
}

__global__ void k_k3v_combine(const float* __restrict__ P, float* __restrict__ O) {
    int idx = blockIdx.x * 256 + threadIdx.x;
    int bh = idx >> 13, rem = idx & 8191;
    float s = 0.f;
    for (int sp = 0; sp < 16; ++sp)
        s += P[((size_t)bh * 16 + sp) * 8192 + rem];
    O[idx] = s;
}

// ---------------------------------------------------------------------------
// kernel_1 fused via split-bf16 MFMA: ATTN = softmax(Q_tile @ KL^T) @ MM.
// grid (32 l-tiles, 32 bh), 256 threads (4 waves). Each wave owns 32 FULL
// rows (all 128 cols) in BOTH matmuls, so the row-softmax reduces entirely
// within the wave's 16-lane groups.
// ---------------------------------------------------------------------------
__global__ __launch_bounds__(256) void k_attn(const float* __restrict__ Q,
                                              const float* __restrict__ KLb,
                                              const float* __restrict__ MMb,
                                              u16* __restrict__ ATH,
                                              u16* __restrict__ ATL) {
    __shared__ u16 lds[49152];
    u16* Qh  = lds;               // 8192 (128x64)
    u16* Ql  = lds + 8192;
    u16* KLh = lds + 16384;
    u16* KLl = lds + 24576;
    u16* Ph  = lds;               // 16384 (128x128), overwrites Q/KL
    u16* Pl  = lds + 16384;
    u16* Mth = lds + 32768;       // 8192 (64x128)
    u16* Mtl = lds + 40960;

    int tid = threadIdx.x;
    int lane = tid & 63, wv = tid >> 6;
    int lr = lane & 15, lk = lane >> 4;
    int l0 = blockIdx.x * 128, bh = blockIdx.y;
    int b = bh >> 4, hh = bh & 15;
    int wrA = wv * 32;            // wave's 32 rows (both matmuls)

    // ---- stage Q, KL (split, IDX64) ----
    #pragma unroll
    for (int q = 0; q < 4; ++q) {
        int idx = tid + q * 256;
        int r = idx >> 3, c8 = (idx & 7) * 8;
        float4 v0 = *(const float4*)(Q + ((size_t)bh * LPAD + l0 + r) * DH + c8);
        float4 v1 = *(const float4*)(Q + ((size_t)bh * LPAD + l0 + r) * DH + c8 + 4);
        float xs[8] = {v0.x, v0.y, v0.z, v0.w, v1.x, v1.y, v1.z, v1.w};
        s16x8 h8, l8;
        #pragma unroll
        for (int e = 0; e < 8; ++e) {
            u16 hh2, ll2; split2(xs[e], hh2, ll2);
            h8[e] = (short)hh2; l8[e] = (short)ll2;
        }
        *(s16x8*)&Qh[IDX64(r, c8)] = h8;
        *(s16x8*)&Ql[IDX64(r, c8)] = l8;

        float4 w0 = *(const float4*)(KLb + ((size_t)bh * NLM + r) * DH + c8);
        float4 w1 = *(const float4*)(KLb + ((size_t)bh * NLM + r) * DH + c8 + 4);
        float ys[8] = {w0.x, w0.y, w0.z, w0.w, w1.x, w1.y, w1.z, w1.w};
        #pragma unroll
        for (int e = 0; e < 8; ++e) {
            u16 hh2, ll2; split2(ys[e], hh2, ll2);
            h8[e] = (short)hh2; l8[e] = (short)ll2;
        }
        *(s16x8*)&KLh[IDX64(r, c8)] = h8;
        *(s16x8*)&KLl[IDX64(r, c8)] = l8;
    }
    // ---- stage MM transposed (split, IDX128) ----
    #pragma unroll
    for (int q = 0; q < 8; ++q) {
        int idx = tid + q * 256;
        int n = idx >> 4, d4 = (idx & 15) * 4;
        float4 v = *(const float4*)(MMb + ((size_t)bh * NLM + n) * DH + d4);
        float xs[4] = {v.x, v.y, v.z, v.w};
        #pragma unroll
        for (int e = 0; e < 4; ++e) {
            u16 hh2, ll2; split2(xs[e], hh2, ll2);
            Mth[IDX128(d4 + e, n)] = hh2;
            Mtl[IDX128(d4 + e, n)] = ll2;
        }
    }
    __syncthreads();

    // ---- S = Q @ KL^T : wave owns 32 rows x 128 cols (t4[2][8]) ----
    f32x4 t4[2][8] = {};
    #pragma unroll
    for (int t = 0; t < 3; ++t) {
        const u16* Xs = (t == 2) ? Ql : Qh;
        const u16* Ys = (t == 1) ? KLl : KLh;
        #pragma unroll
        for (int kc = 0; kc < 2; ++kc) {
            s16x8 a[2], bfr[8];
            #pragma unroll
            for (int i = 0; i < 2; ++i)
                a[i] = *(const s16x8*)&Xs[IDX64(wrA + i * 16 + lr, kc * 32 + lk * 8)];
            #pragma unroll
            for (int j = 0; j < 8; ++j)
                bfr[j] = *(const s16x8*)&Ys[IDX64(j * 16 + lr, kc * 32 + lk * 8)];
            #pragma unroll
            for (int i = 0; i < 2; ++i)
                #pragma unroll
                for (int j = 0; j < 8; ++j)
                    t4[i][j] = __builtin_amdgcn_mfma_f32_16x16x32_bf16(a[i], bfr[j], t4[i][j], 0, 0, 0);
        }
    }

    // ---- row softmax: row = wrA+i*16+lk*4+q; its 128 cols = {j*16+lr} all
    //      in this wave (8 j-frags x 16 lr lanes) ----
    #pragma unroll
    for (int i = 0; i < 2; ++i)
        #pragma unroll
        for (int q = 0; q < 4; ++q) {
            float m = t4[i][0][q];
            #pragma unroll
            for (int j = 1; j < 8; ++j) m = fmaxf(m, t4[i][j][q]);
            m = fmaxf(m, __shfl_xor(m, 1));
            m = fmaxf(m, __shfl_xor(m, 2));
            m = fmaxf(m, __shfl_xor(m, 4));
            m = fmaxf(m, __shfl_xor(m, 8));
            float s = 0.f;
            #pragma unroll
            for (int j = 0; j < 8; ++j) {
                t4[i][j][q] = expf(t4[i][j][q] - m);
                s += t4[i][j][q];
            }
            s += __shfl_xor(s, 1);
            s += __shfl_xor(s, 2);
            s += __shfl_xor(s, 4);
            s += __shfl_xor(s, 8);
            float inv = 1.f / s;
            #pragma unroll
            for (int j = 0; j < 8; ++j) t4[i][j][q] *= inv;
        }

    __syncthreads();   // Q/KL reads done; safe to overwrite with P
    #pragma unroll
    for (int i = 0; i < 2; ++i)
        #pragma unroll
        for (int j = 0; j < 8; ++j) {
            int col = j * 16 + lr;
            #pragma unroll
            for (int q = 0; q < 4; ++q) {
                int row = wrA + i * 16 + lk * 4 + q;
                u16 hh2, ll2; split2(t4[i][j][q], hh2, ll2);
                Ph[IDX128(row, col)] = hh2;
                Pl[IDX128(row, col)] = ll2;
            }
        }
    __syncthreads();

    // ---- O = P @ MM (K=128, 3 split terms); wave computes 32 rows x 64 cols ----
    f32x4 t5[2][4] = {};
    #pragma unroll
    for (int t = 0; t < 3; ++t) {
        const u16* Xs = (t == 2) ? Pl : Ph;
        const u16* Ys = (t == 1) ? Mtl : Mth;
        #pragma unroll
        for (int kc = 0; kc < 4; ++kc) {
            s16x8 a[2], bfr[4];
            #pragma unroll
            for (int i = 0; i < 2; ++i)
                a[i] = *(const s16x8*)&Xs[IDX128(wrA + i * 16 + lr, kc * 32 + lk * 8)];
            #pragma unroll
            for (int j = 0; j < 4; ++j)
                bfr[j] = *(const s16x8*)&Ys[IDX128(j * 16 + lr, kc * 32 + lk * 8)];
            #pragma unroll
            for (int i = 0; i < 2; ++i)
                #pragma unroll
                for (int j = 0; j < 4; ++j)
                    t5[i][j] = __builtin_amdgcn_mfma_f32_16x16x32_bf16(a[i], bfr[j], t5[i][j], 0, 0, 0);
        }
    }

    // ---- epilogue: split O -> ATH/ATL ----
    #pragma unroll
    for (int i = 0; i < 2; ++i)
        #pragma unroll
        for (int j = 0; j < 4; ++j) {
            int d = j * 16 + lr;
            #pragma unroll
            for (int q = 0; q < 4; ++q) {
                int l = l0 + wrA + i * 16 + lk * 4 + q;
                size_t base = ((size_t)b * LPAD + l) * HIDDEN + hh * DH + d;
                u16 hh2, ll2; split2(t5[i][j][q], hh2, ll2);
                ATH[base] = hh2;
                ATL[base] = ll2;
            }
        }
}

// ---------------------------------------------------------------------------
extern "C" void kernel_launch(void* const* d_in, const int* in_sizes, int n_in,
                              void* d_out, int out_size, void* d_ws, size_t ws_size,
                              hipStream_t stream) {
    (void)in_sizes; (void)n_in; (void)out_size; (void)ws_size;
    const float* X    = (const float*)d_in[0];
    const float* mask = (const float*)d_in[1];
    const float* Wq   = (const float*)d_in[2];
    const float* bq   = (const float*)d_in[3];
    const float* Wk   = (const float*)d_in[4];
    const float* bk   = (const float*)d_in[5];
    const float* Wv   = (const float*)d_in[6];
    const float* bv   = (const float*)d_in[7];
    const float* Wo   = (const float*)d_in[8];
    const float* bo   = (const float*)d_in[9];
    float* out = (float*)d_out;
    float* w = (float*)d_ws;

    size_t o = 0;
    u16* WQH = (u16*)(w + o); o += (size_t)HIDDEN * HIDDEN / 2;
    u16* WQL = (u16*)(w + o); o += (size_t)HIDDEN * HIDDEN / 2;
    u16* WKH = (u16*)(w + o); o += (size_t)HIDDEN * HIDDEN / 2;
    u16* WKL = (u16*)(w + o); o += (size_t)HIDDEN * HIDDEN / 2;
    u16* WVH = (u16*)(w + o); o += (size_t)HIDDEN * HIDDEN / 2;
    u16* WVL = (u16*)(w + o); o += (size_t)HIDDEN * HIDDEN / 2;
    u16* WOH = (u16*)(w + o); o += (size_t)HIDDEN * HIDDEN / 2;
    u16* WOL = (u16*)(w + o); o += (size_t)HIDDEN * HIDDEN / 2;
    float* Q   = w + o; o += (size_t)BHT * LPAD * DH;
    float* K   = w + o; o += (size_t)BHT * LPAD * DH;
    float* V   = w + o; o += (size_t)BHT * LPAD * DH;
    float* QL  = w + o; o += (size_t)BHT * NLM * DH;
    float* KL  = w + o; o += (size_t)BHT * NLM * DH;
    float* K2  = w + o; o += (size_t)BHT * NLM * NLM;
    float* VA  = w + o; o += (size_t)BHT * NLM * NLM;
    float* VB  = w + o; o += (size_t)BHT * NLM * NLM;
    float* KV  = w + o; o += (size_t)BHT * NLM * NLM;
    float* P1  = w + o; o += (size_t)BHT * NLM * NLM;
    float* T3  = w + o; o += (size_t)BHT * NLM * NLM;
    float* PK  = w + o; o += (size_t)BHT * 16 * NLM * DH;
    float* K3V = w + o; o += (size_t)BHT * NLM * DH;
    float* MM  = w + o; o += (size_t)BHT * NLM * DH;
    float* SC  = w + o; o += (size_t)BHT * NLM * LPAD;

    // Time-shared aliases of the SC region (disjoint live windows):
    u16* XH  = (u16*)SC;
    u16* XL  = XH + (size_t)2 * LPAD * HIDDEN;
    u16* ATH = (u16*)SC;
    u16* ATL = ATH + (size_t)2 * LPAD * HIDDEN;

    k_split_x<<<8192, 256, 0, stream>>>(X, XH, XL);
    k_split_w<<<1024, 256, 0, stream>>>(Wq, WQH, WQL);
    k_split_w<<<1024, 256, 0, stream>>>(Wk, WKH, WKL);
    k_split_w<<<1024, 256, 0, stream>>>(Wv, WVH, WVL);
    k_split_w<<<1024, 256, 0, stream>>>(Wo, WOH, WOL);

    dim3 gg(64, 8);
    k_gemm_bf16<<<gg, 256, 0, stream>>>(XH, XL, WQH, WQL, bq, mask, Q, 0);
    k_gemm_bf16<<<gg, 256, 0, stream>>>(XH, XL, WKH, WKL, bk, mask, K, 0);
    k_gemm_bf16<<<gg, 256, 0, stream>>>(XH, XL, WVH, WVL, bv, nullptr, V, 0);

    k_landmarks<<<dim3(NLM, BHT), 64, 0, stream>>>(Q, K, QL, KL);

    k_qlk<<<dim3(1, BHT), 256, 0, stream>>>(QL, KL, nullptr, K2, NLM, 0);
    k_qlk<<<dim3(32, BHT), 256, 0, stream>>>(QL, K, mask, SC, LPAD, 1);

    k_v0denom<<<BHT, 128, 0, stream>>>(K2, VA);
    float* cur = VA;
    float* nxt = VB;
    for (int it = 0; it < 6; ++it) {
        k_bmm<<<dim3(2, 2, BHT), 256, 0, stream>>>(K2, cur, KV, P1, NLM, 1.f, 0.f, -1.f, 7.f);
        k_bmm<<<dim3(2, 2, BHT), 256, 0, stream>>>(KV, P1, T3, nullptr, NLM, -1.f, 15.f, 0.f, 0.f);
        k_bmm<<<dim3(2, 2, BHT), 256, 0, stream>>>(KV, T3, P1, nullptr, NLM, -1.f, 13.f, 0.f, 0.f);
        k_bmm<<<dim3(2, 2, BHT), 256, 0, stream>>>(cur, P1, nxt, nullptr, NLM, 0.25f, 0.f, 0.f, 0.f);
        float* t = cur; cur = nxt; nxt = t;
    }

    k_softmax4096<<<BHT * NLM, 256, 0, stream>>>(SC);
    k_k3v_partial<<<dim3(16, BHT), 256, 0, stream>>>(SC, V, PK);
    k_k3v_combine<<<(BHT * NLM * DH) / 256, 256, 0, stream>>>(PK, K3V);
    k_bmm<<<dim3(1, 2, BHT), 256, 0, stream>>>(cur, K3V, MM, nullptr, DH, 1.f, 0.f, 0.f, 0.f);

    k_attn<<<dim3(32, BHT), 256, 0, stream>>>(Q, KL, MM, ATH, ATL);
    k_gemm_bf16<<<gg, 256, 0, stream>>>(ATH, ATL, WOH, WOL, bo, nullptr, out, 1);
}